// Round 1
// baseline (2505.630 us; speedup 1.0000x reference)
//
#include <hip/hip_runtime.h>
#include <hip/hip_bf16.h>
#include <math.h>

// Problem constants
#define BB 8
#define TT 704
#define DD 1024
#define RR 16
#define KK 4
#define HDH 64
#define BT (BB*TT)   // 5632

// ---------------------------------------------------------------- LayerNorm
__global__ __launch_bounds__(256)
void ln_kernel(const float* __restrict__ x, const float* __restrict__ g,
               const float* __restrict__ be, float* __restrict__ y)
{
    const int row = blockIdx.x;
    const int tid = threadIdx.x;
    __shared__ float sbuf[4];
    const size_t off = (size_t)row * DD + tid * 4;
    float4 v = *(const float4*)(x + off);
    float s = v.x + v.y + v.z + v.w;
#pragma unroll
    for (int o = 32; o; o >>= 1) s += __shfl_xor(s, o);
    if ((tid & 63) == 0) sbuf[tid >> 6] = s;
    __syncthreads();
    float mean = (sbuf[0] + sbuf[1] + sbuf[2] + sbuf[3]) * (1.f / 1024.f);
    float dx = v.x - mean, dy = v.y - mean, dz = v.z - mean, dw = v.w - mean;
    float q = dx*dx + dy*dy + dz*dz + dw*dw;
    __syncthreads();
#pragma unroll
    for (int o = 32; o; o >>= 1) q += __shfl_xor(q, o);
    if ((tid & 63) == 0) sbuf[tid >> 6] = q;
    __syncthreads();
    float var = (sbuf[0] + sbuf[1] + sbuf[2] + sbuf[3]) * (1.f / 1024.f);
    float rstd = rsqrtf(var + 1e-5f);
    float4 gg = *(const float4*)(g + tid * 4);
    float4 bb4 = *(const float4*)(be + tid * 4);
    float4 o4;
    o4.x = dx * rstd * gg.x + bb4.x;
    o4.y = dy * rstd * gg.y + bb4.y;
    o4.z = dz * rstd * gg.z + bb4.z;
    o4.w = dw * rstd * gg.w + bb4.w;
    *(float4*)(y + off) = o4;
}

// ------------------------------------------------- entity pooling + W_ent
__global__ __launch_bounds__(256)
void pool_entities_kernel(const float* __restrict__ h, const float* __restrict__ W_ent,
                          const float* __restrict__ b_ent, float* __restrict__ entities)
{
    const int b = blockIdx.x / 3, e = blockIdx.x % 3;
    const int t0 = (e == 0) ? 0 : (e == 1) ? 128 : 192;
    const int t1 = (e == 0) ? 128 : (e == 1) ? 192 : 704;
    const float invlen = (e == 0) ? (1.f/128.f) : (e == 1) ? (1.f/64.f) : (1.f/512.f);
    __shared__ float pooled[DD];
    const int tid = threadIdx.x;
    for (int d = tid; d < DD; d += 256) {
        float s = 0.f;
        for (int t = t0; t < t1; ++t) s += h[((size_t)b * TT + t) * DD + d];
        pooled[d] = s * invlen;
    }
    __syncthreads();
    if (tid < 32) {
        float s = b_ent[tid];
        for (int d = 0; d < DD; ++d) s = fmaf(pooled[d], W_ent[d * 32 + tid], s);
        entities[(b * 3 + e) * 32 + tid] = s;
    }
}

// ----------------------------------------------------- rule/entity selection
__global__ __launch_bounds__(256)
void select_kernel(const float* __restrict__ entities, const float* __restrict__ rules,
                   const float* __restrict__ Wq_er, const float* __restrict__ Wk_er,
                   const float* __restrict__ Wq_es, const float* __restrict__ Wk_es,
                   int* __restrict__ slot_rule, float* __restrict__ gate)
{
    __shared__ float q_er_s[2048];   // [k][r][d]  4*16*32
    __shared__ float k_er_s[768];    // [b][e][d]  8*3*32
    __shared__ float k_es_s[384];    // [b][e][i]  8*3*16
    __shared__ int   sel_e[32];
    const int tid = threadIdx.x;
    for (int idx = tid; idx < 2048; idx += 256) {
        int k = idx >> 9, rem = idx & 511, r = rem >> 5, d = rem & 31;
        float s = 0.f;
        for (int hh = 0; hh < 64; ++hh)
            s = fmaf(rules[(k * 16 + r) * 64 + hh], Wq_er[hh * 32 + d], s);
        q_er_s[idx] = s;
    }
    for (int idx = tid; idx < 768; idx += 256) {
        int be = idx >> 5, d = idx & 31;
        float s = 0.f;
        for (int ss = 0; ss < 32; ++ss)
            s = fmaf(entities[be * 32 + ss], Wk_er[ss * 32 + d], s);
        k_er_s[idx] = s;
    }
    for (int idx = tid; idx < 384; idx += 256) {
        int be = idx >> 4, i = idx & 15;
        float s = 0.f;
        for (int ss = 0; ss < 32; ++ss)
            s = fmaf(entities[be * 32 + ss], Wk_es[ss * 16 + i], s);
        k_es_s[idx] = s;
    }
    __syncthreads();
    if (tid < 32) {
        const int b = tid >> 2, k = tid & 3;
        float best = -1e30f; int bi = 0;
        for (int r = 0; r < 16; ++r)
            for (int e = 0; e < 3; ++e) {
                const float* qp = &q_er_s[(k * 16 + r) * 32];
                const float* kp = &k_er_s[(b * 3 + e) * 32];
                float s = 0.f;
                for (int d = 0; d < 32; ++d) s = fmaf(qp[d], kp[d], s);
                s *= 0.17677669529663687f;   // 1/sqrt(32)
                int idx = r * 3 + e;
                if (s > best) { best = s; bi = idx; }   // first-wins tie => matches lax.top_k
            }
        const int rstar = bi / 3;
        slot_rule[b * 4 + k] = rstar;
        float qes[16];
        for (int i = 0; i < 16; ++i) {
            float s = 0.f;
            for (int hh = 0; hh < 64; ++hh)
                s = fmaf(rules[(k * 16 + rstar) * 64 + hh], Wq_es[(k * 64 + hh) * 16 + i], s);
            qes[i] = s;
        }
        float best2 = -1e30f; int ei = 0;
        for (int e = 0; e < 3; ++e) {
            float s = 0.f;
            for (int i = 0; i < 16; ++i) s = fmaf(qes[i], k_es_s[(b * 3 + e) * 16 + i], s);
            s *= 0.25f;   // 1/sqrt(16)
            if (s > best2) { best2 = s; ei = e; }
        }
        sel_e[tid] = ei;
    }
    __syncthreads();
    if (tid < 24) {
        const int b = tid / 3, e = tid % 3;
        float g = 0.f;
        for (int k = 0; k < 4; ++k) g += (sel_e[b * 4 + k] == e) ? 1.f : 0.f;
        gate[b * 3 + e] = g;
    }
}

// ------------------------------------------- QKV projection (selected heads)
__device__ __forceinline__ int seg_of(int t) { return (t < 128) ? 0 : (t < 192) ? 1 : 2; }

__global__ __launch_bounds__(256)
void qkv_kernel(const float* __restrict__ h, const float* __restrict__ gate,
                const int* __restrict__ slot_rule,
                const float* __restrict__ Wq, const float* __restrict__ bq,
                const float* __restrict__ Wk, const float* __restrict__ bk,
                const float* __restrict__ Wv, const float* __restrict__ bv,
                float* __restrict__ Qb, float* __restrict__ Kb, float* __restrict__ Vb)
{
    const int tt = blockIdx.x, slot = blockIdx.y, b = blockIdx.z;
    const int r = slot_rule[b * 4 + slot];
    const int col0 = r * 64;
    __shared__ __align__(16) float As[32][68];    // [k][token]
    __shared__ __align__(16) float Bqs[32][68], Bks[32][68], Bvs[32][68];
    const int tid = threadIdx.x;
    const int tx = tid & 15, ty = tid >> 4;
    // loaders
    const int tok = tid >> 2, kc8 = (tid & 3) * 8;       // A: 64 tok x 32 k
    const int krow = tid >> 3, cc = (tid & 7) * 8;       // B: 32 k x 64 col
    const int tglob = tt * 64 + tok;
    const float gatef = gate[b * 3 + seg_of(tglob)];
    float accq[4][4] = {}, acck[4][4] = {}, accv[4][4] = {};
    const size_t hrow = ((size_t)b * TT + tglob) * DD;
    for (int k0 = 0; k0 < DD; k0 += 32) {
        float4 a0 = *(const float4*)(h + hrow + k0 + kc8);
        float4 a1 = *(const float4*)(h + hrow + k0 + kc8 + 4);
        float4 q0 = *(const float4*)(Wq + (size_t)(k0 + krow) * DD + col0 + cc);
        float4 q1 = *(const float4*)(Wq + (size_t)(k0 + krow) * DD + col0 + cc + 4);
        float4 kk0v = *(const float4*)(Wk + (size_t)(k0 + krow) * DD + col0 + cc);
        float4 kk1v = *(const float4*)(Wk + (size_t)(k0 + krow) * DD + col0 + cc + 4);
        float4 v0 = *(const float4*)(Wv + (size_t)(k0 + krow) * DD + col0 + cc);
        float4 v1 = *(const float4*)(Wv + (size_t)(k0 + krow) * DD + col0 + cc + 4);
        __syncthreads();
        As[kc8+0][tok] = a0.x * gatef; As[kc8+1][tok] = a0.y * gatef;
        As[kc8+2][tok] = a0.z * gatef; As[kc8+3][tok] = a0.w * gatef;
        As[kc8+4][tok] = a1.x * gatef; As[kc8+5][tok] = a1.y * gatef;
        As[kc8+6][tok] = a1.z * gatef; As[kc8+7][tok] = a1.w * gatef;
        *(float4*)&Bqs[krow][cc] = q0;  *(float4*)&Bqs[krow][cc+4] = q1;
        *(float4*)&Bks[krow][cc] = kk0v; *(float4*)&Bks[krow][cc+4] = kk1v;
        *(float4*)&Bvs[krow][cc] = v0;  *(float4*)&Bvs[krow][cc+4] = v1;
        __syncthreads();
#pragma unroll
        for (int kk = 0; kk < 32; ++kk) {
            float4 a4 = *(float4*)&As[kk][ty * 4];
            float4 bq4 = *(float4*)&Bqs[kk][tx * 4];
            float4 bk4 = *(float4*)&Bks[kk][tx * 4];
            float4 bv4 = *(float4*)&Bvs[kk][tx * 4];
            const float a[4] = {a4.x, a4.y, a4.z, a4.w};
            const float wq4[4] = {bq4.x, bq4.y, bq4.z, bq4.w};
            const float wk4[4] = {bk4.x, bk4.y, bk4.z, bk4.w};
            const float wv4[4] = {bv4.x, bv4.y, bv4.z, bv4.w};
#pragma unroll
            for (int i = 0; i < 4; ++i)
#pragma unroll
                for (int j = 0; j < 4; ++j) {
                    accq[i][j] = fmaf(a[i], wq4[j], accq[i][j]);
                    acck[i][j] = fmaf(a[i], wk4[j], acck[i][j]);
                    accv[i][j] = fmaf(a[i], wv4[j], accv[i][j]);
                }
        }
    }
    const size_t bs = (size_t)(b * 4 + slot) * TT;
#pragma unroll
    for (int i = 0; i < 4; ++i) {
        const int t = tt * 64 + ty * 4 + i;
        const int c = tx * 4;
        float4 qo, ko, vo;
        qo.x = (accq[i][0] + bq[col0 + c + 0]) * 0.125f;
        qo.y = (accq[i][1] + bq[col0 + c + 1]) * 0.125f;
        qo.z = (accq[i][2] + bq[col0 + c + 2]) * 0.125f;
        qo.w = (accq[i][3] + bq[col0 + c + 3]) * 0.125f;
        ko.x = acck[i][0] + bk[col0 + c + 0];
        ko.y = acck[i][1] + bk[col0 + c + 1];
        ko.z = acck[i][2] + bk[col0 + c + 2];
        ko.w = acck[i][3] + bk[col0 + c + 3];
        vo.x = accv[i][0] + bv[col0 + c + 0];
        vo.y = accv[i][1] + bv[col0 + c + 1];
        vo.z = accv[i][2] + bv[col0 + c + 2];
        vo.w = accv[i][3] + bv[col0 + c + 3];
        *(float4*)(Qb + (bs + t) * 64 + c) = qo;
        *(float4*)(Kb + (bs + t) * 64 + c) = ko;
        *(float4*)(Vb + (bs + t) * 64 + c) = vo;
    }
}

// --------------------------------------------------- flash attention / slot
__global__ __launch_bounds__(256)
void attn_kernel(const float* __restrict__ Qb, const float* __restrict__ Kb,
                 const float* __restrict__ Vb, const float* __restrict__ amask,
                 float* __restrict__ AO)
{
    const int qt = blockIdx.x, slot = blockIdx.y, b = blockIdx.z;
    const int tid = threadIdx.x;
    const int row = tid >> 3, sub = tid & 7;
    const int t = qt * 32 + row;
    const size_t bs = (size_t)(b * 4 + slot) * TT;
    __shared__ float Ks[64][65];
    __shared__ float Vs[64][65];
    __shared__ float Sp[64][33];
    __shared__ __align__(16) float Qs[32][64];
    for (int i = tid; i < 512; i += 256) {
        int rr = i >> 4, cc = (i & 15) << 2;
        *(float4*)&Qs[rr][cc] = *(const float4*)(Qb + (bs + qt * 32 + rr) * 64 + cc);
    }
    __syncthreads();
    float qreg[64];
#pragma unroll
    for (int hh = 0; hh < 64; ++hh) qreg[hh] = Qs[row][hh];
    float m_run = -1e30f, l_run = 0.f;
    float acc[8] = {};
    for (int kc = 0; kc < 11; ++kc) {
        __syncthreads();
        for (int i = tid; i < 1024; i += 256) {
            int rr = i >> 4, cc = (i & 15) << 2;
            float4 kv = *(const float4*)(Kb + (bs + kc * 64 + rr) * 64 + cc);
            Ks[rr][cc] = kv.x; Ks[rr][cc+1] = kv.y; Ks[rr][cc+2] = kv.z; Ks[rr][cc+3] = kv.w;
            float4 vv = *(const float4*)(Vb + (bs + kc * 64 + rr) * 64 + cc);
            Vs[rr][cc] = vv.x; Vs[rr][cc+1] = vv.y; Vs[rr][cc+2] = vv.z; Vs[rr][cc+3] = vv.w;
        }
        __syncthreads();
        float sc[8], mloc = -1e30f;
#pragma unroll
        for (int j = 0; j < 8; ++j) {
            const int key = sub * 8 + j;
            float s = 0.f;
#pragma unroll
            for (int hh = 0; hh < 64; ++hh) s = fmaf(qreg[hh], Ks[key][hh], s);
            s += amask[((size_t)b * TT + t) * TT + kc * 64 + key];
            sc[j] = s; mloc = fmaxf(mloc, s);
        }
        mloc = fmaxf(mloc, __shfl_xor(mloc, 1));
        mloc = fmaxf(mloc, __shfl_xor(mloc, 2));
        mloc = fmaxf(mloc, __shfl_xor(mloc, 4));
        const float m_new = fmaxf(m_run, mloc);
        const float fac = __expf(m_run - m_new);
        float lsum = 0.f;
#pragma unroll
        for (int j = 0; j < 8; ++j) {
            float p = __expf(sc[j] - m_new);
            Sp[sub * 8 + j][row] = p;
            lsum += p;
        }
        lsum += __shfl_xor(lsum, 1);
        lsum += __shfl_xor(lsum, 2);
        lsum += __shfl_xor(lsum, 4);
        l_run = l_run * fac + lsum;
        m_run = m_new;
#pragma unroll
        for (int c = 0; c < 8; ++c) acc[c] *= fac;
        __syncthreads();
#pragma unroll
        for (int k2 = 0; k2 < 64; ++k2) {
            const float p = Sp[k2][row];
#pragma unroll
            for (int c = 0; c < 8; ++c)
                acc[c] = fmaf(p, Vs[k2][sub * 8 + c], acc[c]);
        }
    }
    const float inv = 1.f / l_run;
#pragma unroll
    for (int c = 0; c < 8; ++c)
        AO[(bs + t) * 64 + sub * 8 + c] = acc[c] * inv;
}

// ------------------------------------- slot-sum + Wo projection + residual
__global__ __launch_bounds__(256)
void combine_kernel(const float* __restrict__ AO, const float* __restrict__ hidden,
                    const float* __restrict__ Wo, const float* __restrict__ bo,
                    float* __restrict__ hmid)
{
    const int blk = blockIdx.x;
    const int b = blk / TT, t = blk % TT;
    __shared__ float comb[64];
    const int tid = threadIdx.x;
    if (tid < 64) {
        float s = 0.f;
        for (int slot = 0; slot < 4; ++slot)
            s += AO[((size_t)(b * 4 + slot) * TT + t) * 64 + tid];
        comb[tid] = s;
    }
    __syncthreads();
    const size_t rowoff = ((size_t)b * TT + t) * DD;
    for (int c = tid; c < DD; c += 256) {
        float s = 0.f;
#pragma unroll
        for (int hh = 0; hh < 64; ++hh) s = fmaf(comb[hh], Wo[hh * DD + c], s);
        hmid[rowoff + c] = hidden[rowoff + c] + s + 4.f * bo[c];
    }
}

// ----------------------------------------------------------- tiled fp32 GEMM
// C = act(A[M,K] @ B[K,N] (+ C if beta)) (+ resid)
template<int ACT>   // 0 none, 1 relu, 2 gelu(exact)
__global__ __launch_bounds__(256)
void gemm128_kernel(const float* __restrict__ A, int lda,
                    const float* __restrict__ B, int ldb,
                    float* __restrict__ C, int ldc,
                    int M, int N, int Kd, int beta,
                    const float* __restrict__ resid)
{
    __shared__ __align__(16) float As[8][132];   // [k][row] (transposed)
    __shared__ __align__(16) float Bs[8][132];   // [k][col]
    const int tid = threadIdx.x;
    const int tx = tid & 15, ty = tid >> 4;
    const int row0 = blockIdx.y * 128, col0 = blockIdx.x * 128;
    const int arow = tid >> 1, ac4 = (tid & 1) * 4;
    const int brow = tid >> 5, bc4 = (tid & 31) * 4;
    float acc[8][8] = {};
    for (int k0 = 0; k0 < Kd; k0 += 8) {
        float4 av = *(const float4*)(A + (size_t)(row0 + arow) * lda + k0 + ac4);
        float4 bv = *(const float4*)(B + (size_t)(k0 + brow) * ldb + col0 + bc4);
        __syncthreads();
        As[ac4+0][arow] = av.x; As[ac4+1][arow] = av.y;
        As[ac4+2][arow] = av.z; As[ac4+3][arow] = av.w;
        *(float4*)&Bs[brow][bc4] = bv;
        __syncthreads();
#pragma unroll
        for (int kk = 0; kk < 8; ++kk) {
            float a[8], bb[8];
            *(float4*)&a[0] = *(float4*)&As[kk][ty * 8];
            *(float4*)&a[4] = *(float4*)&As[kk][ty * 8 + 4];
            *(float4*)&bb[0] = *(float4*)&Bs[kk][tx * 8];
            *(float4*)&bb[4] = *(float4*)&Bs[kk][tx * 8 + 4];
#pragma unroll
            for (int i = 0; i < 8; ++i)
#pragma unroll
                for (int j = 0; j < 8; ++j)
                    acc[i][j] = fmaf(a[i], bb[j], acc[i][j]);
        }
    }
#pragma unroll
    for (int i = 0; i < 8; ++i) {
        const size_t r = row0 + ty * 8 + i;
        float* cp = C + r * ldc + col0 + tx * 8;
        float v[8];
#pragma unroll
        for (int j = 0; j < 8; ++j) v[j] = acc[i][j];
        if (beta) {
            float4 c0 = *(float4*)cp, c1 = *(float4*)(cp + 4);
            v[0]+=c0.x; v[1]+=c0.y; v[2]+=c0.z; v[3]+=c0.w;
            v[4]+=c1.x; v[5]+=c1.y; v[6]+=c1.z; v[7]+=c1.w;
        }
#pragma unroll
        for (int j = 0; j < 8; ++j) {
            if (ACT == 1) v[j] = fmaxf(v[j], 0.f);
            else if (ACT == 2) v[j] = 0.5f * v[j] * (1.f + erff(v[j] * 0.70710678118654752f));
        }
        if (resid) {
            const float* rp = resid + r * ldc + col0 + tx * 8;
            float4 r0 = *(const float4*)rp, r1 = *(const float4*)(rp + 4);
            v[0]+=r0.x; v[1]+=r0.y; v[2]+=r0.z; v[3]+=r0.w;
            v[4]+=r1.x; v[5]+=r1.y; v[6]+=r1.z; v[7]+=r1.w;
        }
        float4 o0 = {v[0], v[1], v[2], v[3]}, o1 = {v[4], v[5], v[6], v[7]};
        *(float4*)cp = o0;
        *(float4*)(cp + 4) = o1;
    }
}

__global__ void relu_kernel(float* __restrict__ x, int n)
{
    int i = blockIdx.x * 256 + threadIdx.x;
    if (i < n) x[i] = fmaxf(x[i], 0.f);
}

// ---------------------------------------------------------------- launcher
extern "C" void kernel_launch(void* const* d_in, const int* in_sizes, int n_in,
                              void* d_out, int out_size, void* d_ws, size_t ws_size,
                              hipStream_t stream)
{
    const float* hidden = (const float*)d_in[0];
    const float* amask  = (const float*)d_in[1];
    const float* rules  = (const float*)d_in[2];
    const float* W_ent  = (const float*)d_in[3];
    const float* b_ent  = (const float*)d_in[4];
    const float* Wq_er  = (const float*)d_in[5];
    const float* Wk_er  = (const float*)d_in[6];
    const float* Wq_es  = (const float*)d_in[7];
    const float* Wk_es  = (const float*)d_in[8];
    const float* Wq     = (const float*)d_in[9];
    const float* bq     = (const float*)d_in[10];
    const float* Wk     = (const float*)d_in[11];
    const float* bk     = (const float*)d_in[12];
    const float* Wv     = (const float*)d_in[13];
    const float* bv     = (const float*)d_in[14];
    const float* Wo     = (const float*)d_in[15];
    const float* bo     = (const float*)d_in[16];
    const float* ln1_g  = (const float*)d_in[17];
    const float* ln1_b  = (const float*)d_in[18];
    const float* ln2_g  = (const float*)d_in[19];
    const float* ln2_b  = (const float*)d_in[20];
    const float* fc1_w1 = (const float*)d_in[21];
    const float* fc1_w2 = (const float*)d_in[22];
    const float* fc2_w1 = (const float*)d_in[23];
    const float* fc2_w2 = (const float*)d_in[24];

    float* ws = (float*)d_ws;
    // workspace layout (floats); aliases noted. total = 23,069,504 floats (~88 MB)
    float* h    = ws + 0;          // 5,767,168   (later reused as x_ln2)
    float* hmid = ws + 5767168;    // 5,767,168
    float* Qb   = ws + 11534336;   // 1,441,792   (Q+K region later reused as x1)
    float* Kb   = ws + 12976128;   // 1,441,792
    float* Vb   = ws + 14417920;   // 1,441,792   (V+AO region later reused as acc3)
    float* AO   = ws + 15859712;   // 1,441,792
    float* x2   = ws + 17301504;   // 5,767,168
    float* ent  = ws + 23068672;   // 768
    float* gate = ws + 23069440;   // 24
    int*   srule = (int*)(ws + 23069472); // 32
    float* xln2 = h;
    float* x1   = Qb;
    float* acc3 = Vb;
    float* out  = (float*)d_out;

    ln_kernel<<<BT, 256, 0, stream>>>(hidden, ln1_g, ln1_b, h);
    pool_entities_kernel<<<24, 256, 0, stream>>>(h, W_ent, b_ent, ent);
    select_kernel<<<1, 256, 0, stream>>>(ent, rules, Wq_er, Wk_er, Wq_es, Wk_es, srule, gate);
    qkv_kernel<<<dim3(11, 4, 8), 256, 0, stream>>>(h, gate, srule, Wq, bq, Wk, bk, Wv, bv,
                                                   Qb, Kb, Vb);
    attn_kernel<<<dim3(22, 4, 8), 256, 0, stream>>>(Qb, Kb, Vb, amask, AO);
    combine_kernel<<<BT, 256, 0, stream>>>(AO, hidden, Wo, bo, hmid);
    ln_kernel<<<BT, 256, 0, stream>>>(hmid, ln2_g, ln2_b, xln2);

    // MLP: x1 = relu(xln2 @ fc1_w1)
    gemm128_kernel<1><<<dim3(4, 44), 256, 0, stream>>>(xln2, 1024, fc1_w1, 512,
                                                       x1, 512, BT, 512, 1024, 0, nullptr);
    // x2(chunk) = gelu(x1 @ fc1_w2[:, c]);  acc3 += x2 @ fc2_w1[c, :]
    for (int c = 0; c < 4; ++c) {
        gemm128_kernel<2><<<dim3(8, 44), 256, 0, stream>>>(x1, 512, fc1_w2 + c * 1024, 4096,
                                                           x2, 1024, BT, 1024, 512, 0, nullptr);
        gemm128_kernel<0><<<dim3(4, 44), 256, 0, stream>>>(x2, 1024, fc2_w1 + (size_t)c * 1024 * 512, 512,
                                                           acc3, 512, BT, 512, 1024, (c > 0) ? 1 : 0,
                                                           nullptr);
    }
    relu_kernel<<<(BT * 512 + 255) / 256, 256, 0, stream>>>(acc3, BT * 512);
    // out = hmid + acc3 @ fc2_w2
    gemm128_kernel<0><<<dim3(8, 44), 256, 0, stream>>>(acc3, 512, fc2_w2, 1024,
                                                       out, 1024, BT, 1024, 512, 0, hmid);
}

// Round 3
// 807.905 us; speedup vs baseline: 3.1014x; 3.1014x over previous
//
#include <hip/hip_runtime.h>
#include <hip/hip_bf16.h>
#include <math.h>

// Problem constants
#define BB 8
#define TT 704
#define DD 1024
#define RR 16
#define KK 4
#define HDH 64
#define BT (BB*TT)   // 5632

typedef unsigned short u16;
typedef __attribute__((ext_vector_type(4))) float f32x4;
typedef __attribute__((ext_vector_type(8))) short bf16x8;
typedef __attribute__((ext_vector_type(4))) unsigned short u16x4;

__device__ __forceinline__ u16 f2bf(float f) {
    union { float f; unsigned int u; } cv; cv.f = f;
    unsigned int u = cv.u;
    unsigned int r = (u + 0x7fffu + ((u >> 16) & 1u)) >> 16;
    return (u16)r;
}

__device__ __forceinline__ void gl2lds(const u16* g, u16* l) {
    __builtin_amdgcn_global_load_lds(
        (const __attribute__((address_space(1))) void*)g,
        (__attribute__((address_space(3))) void*)l, 16, 0, 0);
}

// ---------------------------------------------------------------- LayerNorm
template<int OBF16>
__global__ __launch_bounds__(256)
void ln_kernel(const float* __restrict__ x, const float* __restrict__ g,
               const float* __restrict__ be, void* __restrict__ yv)
{
    const int row = blockIdx.x;
    const int tid = threadIdx.x;
    __shared__ float sbuf[4];
    const size_t off = (size_t)row * DD + tid * 4;
    float4 v = *(const float4*)(x + off);
    float s = v.x + v.y + v.z + v.w;
#pragma unroll
    for (int o = 32; o; o >>= 1) s += __shfl_xor(s, o);
    if ((tid & 63) == 0) sbuf[tid >> 6] = s;
    __syncthreads();
    float mean = (sbuf[0] + sbuf[1] + sbuf[2] + sbuf[3]) * (1.f / 1024.f);
    float dx = v.x - mean, dy = v.y - mean, dz = v.z - mean, dw = v.w - mean;
    float q = dx*dx + dy*dy + dz*dz + dw*dw;
    __syncthreads();
#pragma unroll
    for (int o = 32; o; o >>= 1) q += __shfl_xor(q, o);
    if ((tid & 63) == 0) sbuf[tid >> 6] = q;
    __syncthreads();
    float var = (sbuf[0] + sbuf[1] + sbuf[2] + sbuf[3]) * (1.f / 1024.f);
    float rstd = rsqrtf(var + 1e-5f);
    float4 gg = *(const float4*)(g + tid * 4);
    float4 bb4 = *(const float4*)(be + tid * 4);
    float o0 = dx * rstd * gg.x + bb4.x;
    float o1 = dy * rstd * gg.y + bb4.y;
    float o2 = dz * rstd * gg.z + bb4.z;
    float o3 = dw * rstd * gg.w + bb4.w;
    if (OBF16) {
        u16x4 o4 = {f2bf(o0), f2bf(o1), f2bf(o2), f2bf(o3)};
        *(u16x4*)((u16*)yv + off) = o4;
    } else {
        float4 o4 = {o0, o1, o2, o3};
        *(float4*)((float*)yv + off) = o4;
    }
}

// -------------------------------------------------- entity pooling (2-phase)
__global__ __launch_bounds__(256)
void pool_partial_kernel(const float* __restrict__ h, float* __restrict__ partial)
{
    const int chunk = blockIdx.x, b = blockIdx.y;   // 11 chunks of 64 tokens
    const int d = threadIdx.x * 4;
    const float* p = h + ((size_t)b * TT + chunk * 64) * DD + d;
    float4 s = {0.f, 0.f, 0.f, 0.f};
    for (int t = 0; t < 64; ++t) {
        float4 v = *(const float4*)(p + (size_t)t * DD);
        s.x += v.x; s.y += v.y; s.z += v.z; s.w += v.w;
    }
    *(float4*)(partial + ((size_t)(b * 11 + chunk)) * 1024 + d) = s;
}

__global__ __launch_bounds__(256)
void pool_finish_kernel(const float* __restrict__ partial, const float* __restrict__ W_ent,
                        const float* __restrict__ b_ent, float* __restrict__ entities)
{
    const int b = blockIdx.x / 3, e = blockIdx.x % 3;
    const int c0 = (e == 0) ? 0 : (e == 1) ? 2 : 3;
    const int c1 = (e == 0) ? 2 : (e == 1) ? 3 : 11;
    const float invlen = (e == 0) ? (1.f/128.f) : (e == 1) ? (1.f/64.f) : (1.f/512.f);
    __shared__ float pooled[1024];
    __shared__ float part[8][32];
    const int tid = threadIdx.x;
    {
        const int d = tid * 4;
        float4 s = {0.f, 0.f, 0.f, 0.f};
        for (int c = c0; c < c1; ++c) {
            float4 v = *(const float4*)(partial + ((size_t)(b * 11 + c)) * 1024 + d);
            s.x += v.x; s.y += v.y; s.z += v.z; s.w += v.w;
        }
        pooled[d+0] = s.x * invlen; pooled[d+1] = s.y * invlen;
        pooled[d+2] = s.z * invlen; pooled[d+3] = s.w * invlen;
    }
    __syncthreads();
    const int g = tid >> 5, j = tid & 31;
    float s = 0.f;
    for (int d = g * 128; d < g * 128 + 128; ++d) s = fmaf(pooled[d], W_ent[d * 32 + j], s);
    part[g][j] = s;
    __syncthreads();
    if (tid < 32) {
        float s2 = b_ent[tid];
        for (int g2 = 0; g2 < 8; ++g2) s2 += part[g2][tid];
        entities[blockIdx.x * 32 + tid] = s2;
    }
}

// ----------------------------------------------------- rule/entity selection
__global__ __launch_bounds__(256)
void select_kernel(const float* __restrict__ entities, const float* __restrict__ rules,
                   const float* __restrict__ Wq_er, const float* __restrict__ Wk_er,
                   const float* __restrict__ Wq_es, const float* __restrict__ Wk_es,
                   int* __restrict__ slot_rule, float* __restrict__ gate)
{
    __shared__ float q_er_s[2048];   // [k][r][d]  4*16*32
    __shared__ float k_er_s[768];    // [b][e][d]  8*3*32
    __shared__ float k_es_s[384];    // [b][e][i]  8*3*16
    __shared__ int   sel_e[32];
    const int tid = threadIdx.x;
    for (int idx = tid; idx < 2048; idx += 256) {
        int k = idx >> 9, rem = idx & 511, r = rem >> 5, d = rem & 31;
        float s = 0.f;
        for (int hh = 0; hh < 64; ++hh)
            s = fmaf(rules[(k * 16 + r) * 64 + hh], Wq_er[hh * 32 + d], s);
        q_er_s[idx] = s;
    }
    for (int idx = tid; idx < 768; idx += 256) {
        int be = idx >> 5, d = idx & 31;
        float s = 0.f;
        for (int ss = 0; ss < 32; ++ss)
            s = fmaf(entities[be * 32 + ss], Wk_er[ss * 32 + d], s);
        k_er_s[idx] = s;
    }
    for (int idx = tid; idx < 384; idx += 256) {
        int be = idx >> 4, i = idx & 15;
        float s = 0.f;
        for (int ss = 0; ss < 32; ++ss)
            s = fmaf(entities[be * 32 + ss], Wk_es[ss * 16 + i], s);
        k_es_s[idx] = s;
    }
    __syncthreads();
    if (tid < 32) {
        const int b = tid >> 2, k = tid & 3;
        float best = -1e30f; int bi = 0;
        for (int r = 0; r < 16; ++r)
            for (int e = 0; e < 3; ++e) {
                const float* qp = &q_er_s[(k * 16 + r) * 32];
                const float* kp = &k_er_s[(b * 3 + e) * 32];
                float s = 0.f;
                for (int d = 0; d < 32; ++d) s = fmaf(qp[d], kp[d], s);
                s *= 0.17677669529663687f;   // 1/sqrt(32)
                int idx = r * 3 + e;
                if (s > best) { best = s; bi = idx; }   // first-wins tie => matches lax.top_k
            }
        const int rstar = bi / 3;
        slot_rule[b * 4 + k] = rstar;
        float qes[16];
        for (int i = 0; i < 16; ++i) {
            float s = 0.f;
            for (int hh = 0; hh < 64; ++hh)
                s = fmaf(rules[(k * 16 + rstar) * 64 + hh], Wq_es[(k * 64 + hh) * 16 + i], s);
            qes[i] = s;
        }
        float best2 = -1e30f; int ei = 0;
        for (int e = 0; e < 3; ++e) {
            float s = 0.f;
            for (int i = 0; i < 16; ++i) s = fmaf(qes[i], k_es_s[(b * 3 + e) * 16 + i], s);
            s *= 0.25f;   // 1/sqrt(16)
            if (s > best2) { best2 = s; ei = e; }
        }
        sel_e[tid] = ei;
    }
    __syncthreads();
    if (tid < 24) {
        const int b = tid / 3, e = tid % 3;
        float g = 0.f;
        for (int k = 0; k < 4; ++k) g += (sel_e[b * 4 + k] == e) ? 1.f : 0.f;
        gate[b * 3 + e] = g;
    }
}

// ---------------------------------------------- gated hidden -> bf16 staging
__global__ __launch_bounds__(256)
void hg_kernel(const float* __restrict__ h, const float* __restrict__ gate,
               u16* __restrict__ hgb)
{
    const int row = blockIdx.x;   // b*T + t
    const int b = row / TT, t = row - b * TT;
    const float g = gate[b * 3 + ((t < 128) ? 0 : (t < 192) ? 1 : 2)];
    const size_t off = (size_t)row * DD + threadIdx.x * 4;
    float4 v = *(const float4*)(h + off);
    u16x4 o = {f2bf(v.x * g), f2bf(v.y * g), f2bf(v.z * g), f2bf(v.w * g)};
    *(u16x4*)(hgb + off) = o;
}

// --------------------------------------- fp32 [R][C] -> bf16 [C][R] transpose
__global__ __launch_bounds__(256)
void transpose_bf16_kernel(const float* __restrict__ in, u16* __restrict__ out,
                           int R, int C)
{
    __shared__ float tile[32][33];
    const int tx = threadIdx.x & 31, ty = threadIdx.x >> 5;
    const int c0 = blockIdx.x * 32, r0 = blockIdx.y * 32;
#pragma unroll
    for (int j = 0; j < 4; ++j)
        tile[ty + j * 8][tx] = in[(size_t)(r0 + ty + j * 8) * C + c0 + tx];
    __syncthreads();
#pragma unroll
    for (int j = 0; j < 4; ++j)
        out[(size_t)(c0 + ty + j * 8) * R + r0 + tx] = f2bf(tile[tx][ty + j * 8]);
}

// --------------------------------------------- MFMA bf16 GEMM, 128x128 tile
// C = act(A[M,K]bf16 @ Bt[N,K]bf16^T) with optional beta(fp32 C in), bias, resid
template<int ACT, int OBF16>   // ACT: 0 none, 1 relu, 2 gelu(exact)
__global__ __launch_bounds__(256)
void gemm_bt(const u16* __restrict__ A, int lda,
             const u16* __restrict__ Bt, int ldb,
             void* __restrict__ Cp, int ldc, int M, int Kt,
             int beta, const float* __restrict__ resid,
             const float* __restrict__ bias, float bscale)
{
    __shared__ u16 As[128 * 32];
    __shared__ u16 Bs[128 * 32];
    const int tid = threadIdx.x;
    const int wid = tid >> 6, lane = tid & 63;
    const int wr = wid >> 1, wc = wid & 1;
    const int row0 = blockIdx.y * 128, col0 = blockIdx.x * 128;
    // staging: wave w covers tile rows w*32 .. w*32+31 (two 16-row issues).
    // issue i: LDS base = w*1024 + i*512 u16; HW writes base + lane*16B.
    // global source row = w*32 + i*16 + (lane>>2), k-offset (lane&3)*8.
    const int sr = wid * 32 + (lane >> 2);
    const int sc = (lane & 3) * 8;
    const u16* ag = A + (size_t)(row0 + sr) * lda + sc;
    const u16* bg = Bt + (size_t)(col0 + sr) * ldb + sc;
    u16* lA0 = As + wid * 1024;
    u16* lA1 = As + wid * 1024 + 512;
    u16* lB0 = Bs + wid * 1024;
    u16* lB1 = Bs + wid * 1024 + 512;
    f32x4 acc[4][4];
#pragma unroll
    for (int i = 0; i < 4; ++i)
#pragma unroll
        for (int j = 0; j < 4; ++j) acc[i][j] = (f32x4){0.f, 0.f, 0.f, 0.f};
    const int fr = lane & 15, kb8 = (lane >> 4) * 8;
    const u16* pa = As + (wr * 64 + fr) * 32 + kb8;
    const u16* pb = Bs + (wc * 64 + fr) * 32 + kb8;
    for (int k0 = 0; k0 < Kt; k0 += 32) {
        __syncthreads();
        gl2lds(ag, lA0);
        gl2lds(ag + (size_t)16 * lda, lA1);
        gl2lds(bg, lB0);
        gl2lds(bg + (size_t)16 * ldb, lB1);
        ag += 32; bg += 32;
        __syncthreads();
#pragma unroll
        for (int mi = 0; mi < 4; ++mi) {
            bf16x8 af = *(const bf16x8*)(pa + mi * 16 * 32);
#pragma unroll
            for (int ni = 0; ni < 4; ++ni) {
                bf16x8 bfv = *(const bf16x8*)(pb + ni * 16 * 32);
                acc[mi][ni] = __builtin_amdgcn_mfma_f32_16x16x32_bf16(af, bfv, acc[mi][ni], 0, 0, 0);
            }
        }
    }
    const int fq4 = (lane >> 4) * 4;
#pragma unroll
    for (int mi = 0; mi < 4; ++mi) {
#pragma unroll
        for (int j = 0; j < 4; ++j) {
            const int row = row0 + wr * 64 + mi * 16 + fq4 + j;
            if (row >= M) continue;
#pragma unroll
            for (int ni = 0; ni < 4; ++ni) {
                const int col = col0 + wc * 64 + ni * 16 + fr;
                float v = acc[mi][ni][j];
                if (bias) v += bscale * bias[col];
                if (OBF16) {
                    if (ACT == 1) v = fmaxf(v, 0.f);
                    else if (ACT == 2) v = 0.5f * v * (1.f + erff(v * 0.70710678118654752f));
                    ((u16*)Cp)[(size_t)row * ldc + col] = f2bf(v);
                } else {
                    float* Cf = (float*)Cp;
                    const size_t off = (size_t)row * ldc + col;
                    if (beta) v += Cf[off];
                    if (ACT == 1) v = fmaxf(v, 0.f);
                    else if (ACT == 2) v = 0.5f * v * (1.f + erff(v * 0.70710678118654752f));
                    if (resid) v += resid[off];
                    Cf[off] = v;
                }
            }
        }
    }
}

// ------------------------------------- QKV projection via MFMA, 64x64 tiles
__global__ __launch_bounds__(256)
void qkv_mfma_kernel(const u16* __restrict__ hgb, const u16* __restrict__ WqkvT,
                     const float* __restrict__ bq, const float* __restrict__ bk,
                     const float* __restrict__ bv, const int* __restrict__ slot_rule,
                     float* __restrict__ Qb, float* __restrict__ Kb, float* __restrict__ Vb)
{
    const int mt = blockIdx.x, typ = blockIdx.y, z = blockIdx.z;  // z = b*4+slot
    const int b = z >> 2;
    const int r = slot_rule[z];
    const u16* A  = hgb + (size_t)b * TT * DD + (size_t)mt * 64 * DD;
    const u16* Bt = WqkvT + (size_t)typ * DD * DD + (size_t)(r * 64) * DD;
    __shared__ u16 As[64 * 32];
    __shared__ u16 Bs[64 * 32];
    const int tid = threadIdx.x;
    const int wid = tid >> 6, lane = tid & 63;
    const int wr = wid >> 1, wc = wid & 1;
    const u16* ag = A + (size_t)(tid >> 2) * DD + (tid & 3) * 8;
    const u16* bg = Bt + (size_t)(tid >> 2) * DD + (tid & 3) * 8;
    u16* lA = As + wid * 512;
    u16* lB = Bs + wid * 512;
    f32x4 acc[2][2];
#pragma unroll
    for (int i = 0; i < 2; ++i)
#pragma unroll
        for (int j = 0; j < 2; ++j) acc[i][j] = (f32x4){0.f, 0.f, 0.f, 0.f};
    const int fr = lane & 15, kb8 = (lane >> 4) * 8;
    const u16* pa = As + (wr * 32 + fr) * 32 + kb8;
    const u16* pb = Bs + (wc * 32 + fr) * 32 + kb8;
    for (int k0 = 0; k0 < DD; k0 += 32) {
        __syncthreads();
        gl2lds(ag, lA);
        gl2lds(bg, lB);
        ag += 32; bg += 32;
        __syncthreads();
#pragma unroll
        for (int mi = 0; mi < 2; ++mi) {
            bf16x8 af = *(const bf16x8*)(pa + mi * 16 * 32);
#pragma unroll
            for (int ni = 0; ni < 2; ++ni) {
                bf16x8 bfv = *(const bf16x8*)(pb + ni * 16 * 32);
                acc[mi][ni] = __builtin_amdgcn_mfma_f32_16x16x32_bf16(af, bfv, acc[mi][ni], 0, 0, 0);
            }
        }
    }
    const float* bias = (typ == 0) ? bq : (typ == 1) ? bk : bv;
    const float scale = (typ == 0) ? 0.125f : 1.f;
    float* out = ((typ == 0) ? Qb : (typ == 1) ? Kb : Vb) + (size_t)z * TT * 64;
    const int fq4 = (lane >> 4) * 4;
#pragma unroll
    for (int mi = 0; mi < 2; ++mi)
#pragma unroll
        for (int j = 0; j < 4; ++j) {
            const int row = mt * 64 + wr * 32 + mi * 16 + fq4 + j;
#pragma unroll
            for (int ni = 0; ni < 2; ++ni) {
                const int col = wc * 32 + ni * 16 + fr;
                out[(size_t)row * 64 + col] = (acc[mi][ni][j] + bias[r * 64 + col]) * scale;
            }
        }
}

// --------------------------------------------------- flash attention / slot
__global__ __launch_bounds__(256)
void attn_kernel(const float* __restrict__ Qb, const float* __restrict__ Kb,
                 const float* __restrict__ Vb, const float* __restrict__ amask,
                 float* __restrict__ AO)
{
    const int qt = blockIdx.x, slot = blockIdx.y, b = blockIdx.z;
    const int tid = threadIdx.x;
    const int row = tid >> 3, sub = tid & 7;
    const int t = qt * 32 + row;
    const size_t bs = (size_t)(b * 4 + slot) * TT;
    __shared__ float Ks[64][65];
    __shared__ float Vs[64][65];
    __shared__ float Sp[64][33];
    __shared__ __align__(16) float Qs[32][64];
    for (int i = tid; i < 512; i += 256) {
        int rr = i >> 4, cc = (i & 15) << 2;
        *(float4*)&Qs[rr][cc] = *(const float4*)(Qb + (bs + qt * 32 + rr) * 64 + cc);
    }
    __syncthreads();
    float qreg[64];
#pragma unroll
    for (int hh = 0; hh < 64; ++hh) qreg[hh] = Qs[row][hh];
    float m_run = -1e30f, l_run = 0.f;
    float acc[8] = {};
    for (int kc = 0; kc < 11; ++kc) {
        __syncthreads();
        for (int i = tid; i < 1024; i += 256) {
            int rr = i >> 4, cc = (i & 15) << 2;
            float4 kv = *(const float4*)(Kb + (bs + kc * 64 + rr) * 64 + cc);
            Ks[rr][cc] = kv.x; Ks[rr][cc+1] = kv.y; Ks[rr][cc+2] = kv.z; Ks[rr][cc+3] = kv.w;
            float4 vv = *(const float4*)(Vb + (bs + kc * 64 + rr) * 64 + cc);
            Vs[rr][cc] = vv.x; Vs[rr][cc+1] = vv.y; Vs[rr][cc+2] = vv.z; Vs[rr][cc+3] = vv.w;
        }
        __syncthreads();
        float sc[8], mloc = -1e30f;
#pragma unroll
        for (int j = 0; j < 8; ++j) {
            const int key = sub * 8 + j;
            float s = 0.f;
#pragma unroll
            for (int hh = 0; hh < 64; ++hh) s = fmaf(qreg[hh], Ks[key][hh], s);
            s += amask[((size_t)b * TT + t) * TT + kc * 64 + key];
            sc[j] = s; mloc = fmaxf(mloc, s);
        }
        mloc = fmaxf(mloc, __shfl_xor(mloc, 1));
        mloc = fmaxf(mloc, __shfl_xor(mloc, 2));
        mloc = fmaxf(mloc, __shfl_xor(mloc, 4));
        const float m_new = fmaxf(m_run, mloc);
        const float fac = __expf(m_run - m_new);
        float lsum = 0.f;
#pragma unroll
        for (int j = 0; j < 8; ++j) {
            float p = __expf(sc[j] - m_new);
            Sp[sub * 8 + j][row] = p;
            lsum += p;
        }
        lsum += __shfl_xor(lsum, 1);
        lsum += __shfl_xor(lsum, 2);
        lsum += __shfl_xor(lsum, 4);
        l_run = l_run * fac + lsum;
        m_run = m_new;
#pragma unroll
        for (int c = 0; c < 8; ++c) acc[c] *= fac;
        __syncthreads();
#pragma unroll
        for (int k2 = 0; k2 < 64; ++k2) {
            const float p = Sp[k2][row];
#pragma unroll
            for (int c = 0; c < 8; ++c)
                acc[c] = fmaf(p, Vs[k2][sub * 8 + c], acc[c]);
        }
    }
    const float inv = 1.f / l_run;
#pragma unroll
    for (int c = 0; c < 8; ++c)
        AO[(bs + t) * 64 + sub * 8 + c] = acc[c] * inv;
}

// ------------------------------------------------ sum AO over slots -> bf16
__global__ __launch_bounds__(256)
void aosum_kernel(const float* __restrict__ AO, u16* __restrict__ AOs)
{
    const int i = blockIdx.x * 256 + threadIdx.x;   // over BT*64
    const int bt = i >> 6;
    const int b = bt / TT, t = bt - b * TT;
    const int c = i & 63;
    float s = 0.f;
#pragma unroll
    for (int slot = 0; slot < 4; ++slot)
        s += AO[(((size_t)(b * 4 + slot)) * TT + t) * 64 + c];
    AOs[i] = f2bf(s);
}

// --------------------------------------------------- relu + fp32->bf16 conv
__global__ __launch_bounds__(256)
void reluconv_kernel(const float* __restrict__ x, u16* __restrict__ y)
{
    const int i = (blockIdx.x * 256 + threadIdx.x) * 4;
    float4 v = *(const float4*)(x + i);
    u16x4 o = {f2bf(fmaxf(v.x, 0.f)), f2bf(fmaxf(v.y, 0.f)),
               f2bf(fmaxf(v.z, 0.f)), f2bf(fmaxf(v.w, 0.f))};
    *(u16x4*)(y + i) = o;
}

// ---------------------------------------------------------------- launcher
extern "C" void kernel_launch(void* const* d_in, const int* in_sizes, int n_in,
                              void* d_out, int out_size, void* d_ws, size_t ws_size,
                              hipStream_t stream)
{
    const float* hidden = (const float*)d_in[0];
    const float* amask  = (const float*)d_in[1];
    const float* rules  = (const float*)d_in[2];
    const float* W_ent  = (const float*)d_in[3];
    const float* b_ent  = (const float*)d_in[4];
    const float* Wq_er  = (const float*)d_in[5];
    const float* Wk_er  = (const float*)d_in[6];
    const float* Wq_es  = (const float*)d_in[7];
    const float* Wk_es  = (const float*)d_in[8];
    const float* Wq     = (const float*)d_in[9];
    const float* bq     = (const float*)d_in[10];
    const float* Wk     = (const float*)d_in[11];
    const float* bk     = (const float*)d_in[12];
    const float* Wv     = (const float*)d_in[13];
    const float* bv     = (const float*)d_in[14];
    const float* Wo     = (const float*)d_in[15];
    const float* bo     = (const float*)d_in[16];
    const float* ln1_g  = (const float*)d_in[17];
    const float* ln1_b  = (const float*)d_in[18];
    const float* ln2_g  = (const float*)d_in[19];
    const float* ln2_b  = (const float*)d_in[20];
    const float* fc1_w1 = (const float*)d_in[21];
    const float* fc1_w2 = (const float*)d_in[22];
    const float* fc2_w1 = (const float*)d_in[23];
    const float* fc2_w2 = (const float*)d_in[24];

    char* ws = (char*)d_ws;
    // byte offsets (aliasing noted); total 92,078,080 B < proven 92.28 MB
    float* h      = (float*)(ws + 0);              // 23,068,672  [ln1..hg]
    u16*   x1     = (u16*)(ws + 0);                //  5,767,168  [G1..G2]   (in dead h)
    u16*   x2c    = (u16*)(ws + 5767168);          // 11,534,336  [G2..G3]   (in dead h)
    float* hmid   = (float*)(ws + 23068672);       // 23,068,672  [combine..end]
    u16*   hgb    = (u16*)(ws + 46137344);         // 11,534,336  [hg..qkv]
    u16*   xln2   = (u16*)(ws + 46137344);         //   (reuse)   [ln2..G1]
    float* x3f    = (float*)(ws + 46137344);       //   (reuse)   [G3..reluconv]
    float* Qb     = (float*)(ws + 57671680);       //  5,767,168  [qkv..attn]
    u16*   x3b    = (u16*)(ws + 57671680);         //   (reuse)   [reluconv..G4]
    float* Kb     = (float*)(ws + 63438848);       //  5,767,168
    float* Vb     = (float*)(ws + 69206016);       //  5,767,168
    float* AO     = (float*)(ws + 74973184);       //  5,767,168  [attn..aosum]
    float* part   = (float*)(ws + 74973184);       //    360,448  (dead before AO)
    float* ent    = (float*)(ws + 75333632);       //      3,072
    float* gate   = (float*)(ws + 75336704);       //        128
    int*   srule  = (int*)(ws + 75336832);         //        128
    u16*   AOs    = (u16*)(ws + 80740352);         //    720,896
    u16*   WqkvT  = (u16*)(ws + 81461248);         //  6,291,456  [..qkv]
    u16*   fc1w2T = (u16*)(ws + 81461248);         //  4,194,304  (after qkv)
    u16*   fc2w1T = (u16*)(ws + 85655552);         //  4,194,304  (after qkv)
    u16*   WoT    = (u16*)(ws + 89849856);         //    131,072
    u16*   fc1w1T = (u16*)(ws + 89980928);         //  1,048,576
    u16*   fc2w2T = (u16*)(ws + 91029504);         //  1,048,576
    float* out    = (float*)d_out;

    // --- LN1 + selection path (fp32)
    ln_kernel<0><<<BT, 256, 0, stream>>>(hidden, ln1_g, ln1_b, h);
    pool_partial_kernel<<<dim3(11, 8), 256, 0, stream>>>(h, part);
    pool_finish_kernel<<<24, 256, 0, stream>>>(part, W_ent, b_ent, ent);
    select_kernel<<<1, 256, 0, stream>>>(ent, rules, Wq_er, Wk_er, Wq_es, Wk_es, srule, gate);
    hg_kernel<<<BT, 256, 0, stream>>>(h, gate, hgb);

    // --- weight prep (phase 1: needed before/at qkv)
    transpose_bf16_kernel<<<dim3(32, 32), 256, 0, stream>>>(Wq, WqkvT,               1024, 1024);
    transpose_bf16_kernel<<<dim3(32, 32), 256, 0, stream>>>(Wk, WqkvT + 1024*1024,   1024, 1024);
    transpose_bf16_kernel<<<dim3(32, 32), 256, 0, stream>>>(Wv, WqkvT + 2*1024*1024, 1024, 1024);
    transpose_bf16_kernel<<<dim3(32, 2),  256, 0, stream>>>(Wo, WoT, 64, 1024);
    transpose_bf16_kernel<<<dim3(16, 32), 256, 0, stream>>>(fc1_w1, fc1w1T, 1024, 512);
    transpose_bf16_kernel<<<dim3(32, 16), 256, 0, stream>>>(fc2_w2, fc2w2T, 512, 1024);

    // --- QKV (MFMA) + attention (fp32)
    qkv_mfma_kernel<<<dim3(11, 3, 32), 256, 0, stream>>>(hgb, WqkvT, bq, bk, bv, srule,
                                                         Qb, Kb, Vb);
    // weight prep phase 2 (aliases WqkvT region, so must come after qkv)
    transpose_bf16_kernel<<<dim3(128, 16), 256, 0, stream>>>(fc1_w2, fc1w2T, 512, 4096);
    transpose_bf16_kernel<<<dim3(16, 128), 256, 0, stream>>>(fc2_w1, fc2w1T, 4096, 512);

    attn_kernel<<<dim3(22, 4, 8), 256, 0, stream>>>(Qb, Kb, Vb, amask, AO);
    aosum_kernel<<<1408, 256, 0, stream>>>(AO, AOs);

    // --- combine: hmid = hidden + AOs @ WoT^T + 4*bo   (MFMA)
    gemm_bt<0, 0><<<dim3(8, 44), 256, 0, stream>>>(AOs, 64, WoT, 64, hmid, 1024,
                                                   BT, 64, 0, hidden, bo, 4.f);
    // --- LN2 -> bf16
    ln_kernel<1><<<BT, 256, 0, stream>>>(hmid, ln2_g, ln2_b, xln2);

    // --- MLP (all MFMA)
    gemm_bt<1, 1><<<dim3(4, 44), 256, 0, stream>>>(xln2, 1024, fc1w1T, 1024, x1, 512,
                                                   BT, 1024, 0, nullptr, nullptr, 0.f);
    for (int c = 0; c < 4; ++c) {
        gemm_bt<2, 1><<<dim3(8, 44), 256, 0, stream>>>(x1, 512, fc1w2T + (size_t)c * 1024 * 512, 512,
                                                       x2c, 1024, BT, 512, 0, nullptr, nullptr, 0.f);
        gemm_bt<0, 0><<<dim3(4, 44), 256, 0, stream>>>(x2c, 1024, fc2w1T + c * 1024, 4096,
                                                       x3f, 512, BT, 1024, (c > 0) ? 1 : 0,
                                                       nullptr, nullptr, 0.f);
    }
    reluconv_kernel<<<(BT * 512) / 1024, 256, 0, stream>>>(x3f, x3b);
    gemm_bt<0, 0><<<dim3(8, 44), 256, 0, stream>>>(x3b, 512, fc2w2T, 512, out, 1024,
                                                   BT, 512, 0, hmid, nullptr, 0.f);
}

// Round 4
// 501.272 us; speedup vs baseline: 4.9985x; 1.6117x over previous
//
#include <hip/hip_runtime.h>
#include <hip/hip_bf16.h>
#include <math.h>

// Problem constants
#define BB 8
#define TT 704
#define DD 1024
#define RR 16
#define KK 4
#define HDH 64
#define BT (BB*TT)   // 5632

typedef unsigned short u16;
typedef __attribute__((ext_vector_type(4))) float f32x4;
typedef __attribute__((ext_vector_type(8))) short bf16x8;
typedef __attribute__((ext_vector_type(4))) unsigned short u16x4;
typedef __attribute__((ext_vector_type(8))) unsigned short u16x8;

__device__ __forceinline__ u16 f2bf(float f) {
    union { float f; unsigned int u; } cv; cv.f = f;
    unsigned int u = cv.u;
    unsigned int r = (u + 0x7fffu + ((u >> 16) & 1u)) >> 16;
    return (u16)r;
}

__device__ __forceinline__ void gl2lds(const u16* g, u16* l) {
    __builtin_amdgcn_global_load_lds(
        (const __attribute__((address_space(1))) void*)g,
        (__attribute__((address_space(3))) void*)l, 16, 0, 0);
}

// ---------------------------------------------------------------- LayerNorm
template<int OBF16>
__global__ __launch_bounds__(256)
void ln_kernel(const float* __restrict__ x, const float* __restrict__ g,
               const float* __restrict__ be, void* __restrict__ yv)
{
    const int row = blockIdx.x;
    const int tid = threadIdx.x;
    __shared__ float sbuf[4];
    const size_t off = (size_t)row * DD + tid * 4;
    float4 v = *(const float4*)(x + off);
    float s = v.x + v.y + v.z + v.w;
#pragma unroll
    for (int o = 32; o; o >>= 1) s += __shfl_xor(s, o);
    if ((tid & 63) == 0) sbuf[tid >> 6] = s;
    __syncthreads();
    float mean = (sbuf[0] + sbuf[1] + sbuf[2] + sbuf[3]) * (1.f / 1024.f);
    float dx = v.x - mean, dy = v.y - mean, dz = v.z - mean, dw = v.w - mean;
    float q = dx*dx + dy*dy + dz*dz + dw*dw;
    __syncthreads();
#pragma unroll
    for (int o = 32; o; o >>= 1) q += __shfl_xor(q, o);
    if ((tid & 63) == 0) sbuf[tid >> 6] = q;
    __syncthreads();
    float var = (sbuf[0] + sbuf[1] + sbuf[2] + sbuf[3]) * (1.f / 1024.f);
    float rstd = rsqrtf(var + 1e-5f);
    float4 gg = *(const float4*)(g + tid * 4);
    float4 bb4 = *(const float4*)(be + tid * 4);
    float o0 = dx * rstd * gg.x + bb4.x;
    float o1 = dy * rstd * gg.y + bb4.y;
    float o2 = dz * rstd * gg.z + bb4.z;
    float o3 = dw * rstd * gg.w + bb4.w;
    if (OBF16) {
        u16x4 o4 = {f2bf(o0), f2bf(o1), f2bf(o2), f2bf(o3)};
        *(u16x4*)((u16*)yv + off) = o4;
    } else {
        float4 o4 = {o0, o1, o2, o3};
        *(float4*)((float*)yv + off) = o4;
    }
}

// -------------------------------------------------- entity pooling (2-phase)
__global__ __launch_bounds__(256)
void pool_partial_kernel(const float* __restrict__ h, float* __restrict__ partial)
{
    const int chunk = blockIdx.x, b = blockIdx.y;   // 11 chunks of 64 tokens
    const int d = threadIdx.x * 4;
    const float* p = h + ((size_t)b * TT + chunk * 64) * DD + d;
    float4 s = {0.f, 0.f, 0.f, 0.f};
    for (int t = 0; t < 64; ++t) {
        float4 v = *(const float4*)(p + (size_t)t * DD);
        s.x += v.x; s.y += v.y; s.z += v.z; s.w += v.w;
    }
    *(float4*)(partial + ((size_t)(b * 11 + chunk)) * 1024 + d) = s;
}

__global__ __launch_bounds__(256)
void pool_finish_kernel(const float* __restrict__ partial, const float* __restrict__ W_ent,
                        const float* __restrict__ b_ent, float* __restrict__ entities)
{
    const int b = blockIdx.x / 3, e = blockIdx.x % 3;
    const int c0 = (e == 0) ? 0 : (e == 1) ? 2 : 3;
    const int c1 = (e == 0) ? 2 : (e == 1) ? 3 : 11;
    const float invlen = (e == 0) ? (1.f/128.f) : (e == 1) ? (1.f/64.f) : (1.f/512.f);
    __shared__ float pooled[1024];
    __shared__ float part[8][32];
    const int tid = threadIdx.x;
    {
        const int d = tid * 4;
        float4 s = {0.f, 0.f, 0.f, 0.f};
        for (int c = c0; c < c1; ++c) {
            float4 v = *(const float4*)(partial + ((size_t)(b * 11 + c)) * 1024 + d);
            s.x += v.x; s.y += v.y; s.z += v.z; s.w += v.w;
        }
        pooled[d+0] = s.x * invlen; pooled[d+1] = s.y * invlen;
        pooled[d+2] = s.z * invlen; pooled[d+3] = s.w * invlen;
    }
    __syncthreads();
    const int g = tid >> 5, j = tid & 31;
    float s = 0.f;
    for (int d = g * 128; d < g * 128 + 128; ++d) s = fmaf(pooled[d], W_ent[d * 32 + j], s);
    part[g][j] = s;
    __syncthreads();
    if (tid < 32) {
        float s2 = b_ent[tid];
        for (int g2 = 0; g2 < 8; ++g2) s2 += part[g2][tid];
        entities[blockIdx.x * 32 + tid] = s2;
    }
}

// ----------------------------------------------------- rule/entity selection
__global__ __launch_bounds__(256)
void select_kernel(const float* __restrict__ entities, const float* __restrict__ rules,
                   const float* __restrict__ Wq_er, const float* __restrict__ Wk_er,
                   const float* __restrict__ Wq_es, const float* __restrict__ Wk_es,
                   int* __restrict__ slot_rule, float* __restrict__ gate)
{
    __shared__ float q_er_s[2048];   // [k][r][d]  4*16*32
    __shared__ float k_er_s[768];    // [b][e][d]  8*3*32
    __shared__ float k_es_s[384];    // [b][e][i]  8*3*16
    __shared__ int   sel_e[32];
    const int tid = threadIdx.x;
    for (int idx = tid; idx < 2048; idx += 256) {
        int k = idx >> 9, rem = idx & 511, r = rem >> 5, d = rem & 31;
        float s = 0.f;
        for (int hh = 0; hh < 64; ++hh)
            s = fmaf(rules[(k * 16 + r) * 64 + hh], Wq_er[hh * 32 + d], s);
        q_er_s[idx] = s;
    }
    for (int idx = tid; idx < 768; idx += 256) {
        int be = idx >> 5, d = idx & 31;
        float s = 0.f;
        for (int ss = 0; ss < 32; ++ss)
            s = fmaf(entities[be * 32 + ss], Wk_er[ss * 32 + d], s);
        k_er_s[idx] = s;
    }
    for (int idx = tid; idx < 384; idx += 256) {
        int be = idx >> 4, i = idx & 15;
        float s = 0.f;
        for (int ss = 0; ss < 32; ++ss)
            s = fmaf(entities[be * 32 + ss], Wk_es[ss * 16 + i], s);
        k_es_s[idx] = s;
    }
    __syncthreads();
    if (tid < 32) {
        const int b = tid >> 2, k = tid & 3;
        float best = -1e30f; int bi = 0;
        for (int r = 0; r < 16; ++r)
            for (int e = 0; e < 3; ++e) {
                const float* qp = &q_er_s[(k * 16 + r) * 32];
                const float* kp = &k_er_s[(b * 3 + e) * 32];
                float s = 0.f;
                for (int d = 0; d < 32; ++d) s = fmaf(qp[d], kp[d], s);
                s *= 0.17677669529663687f;   // 1/sqrt(32)
                int idx = r * 3 + e;
                if (s > best) { best = s; bi = idx; }   // first-wins tie => matches lax.top_k
            }
        const int rstar = bi / 3;
        slot_rule[b * 4 + k] = rstar;
        float qes[16];
        for (int i = 0; i < 16; ++i) {
            float s = 0.f;
            for (int hh = 0; hh < 64; ++hh)
                s = fmaf(rules[(k * 16 + rstar) * 64 + hh], Wq_es[(k * 64 + hh) * 16 + i], s);
            qes[i] = s;
        }
        float best2 = -1e30f; int ei = 0;
        for (int e = 0; e < 3; ++e) {
            float s = 0.f;
            for (int i = 0; i < 16; ++i) s = fmaf(qes[i], k_es_s[(b * 3 + e) * 16 + i], s);
            s *= 0.25f;   // 1/sqrt(16)
            if (s > best2) { best2 = s; ei = e; }
        }
        sel_e[tid] = ei;
    }
    __syncthreads();
    if (tid < 24) {
        const int b = tid / 3, e = tid % 3;
        float g = 0.f;
        for (int k = 0; k < 4; ++k) g += (sel_e[b * 4 + k] == e) ? 1.f : 0.f;
        gate[b * 3 + e] = g;
    }
}

// ---------------------------------------------- gated hidden -> bf16 staging
__global__ __launch_bounds__(256)
void hg_kernel(const float* __restrict__ h, const float* __restrict__ gate,
               u16* __restrict__ hgb)
{
    const int row = blockIdx.x;   // b*T + t
    const int b = row / TT, t = row - b * TT;
    const float g = gate[b * 3 + ((t < 128) ? 0 : (t < 192) ? 1 : 2)];
    const size_t off = (size_t)row * DD + threadIdx.x * 4;
    float4 v = *(const float4*)(h + off);
    u16x4 o = {f2bf(v.x * g), f2bf(v.y * g), f2bf(v.z * g), f2bf(v.w * g)};
    *(u16x4*)(hgb + off) = o;
}

// --------------------------------------- fp32 [R][C] -> bf16 [C][R] transpose
__global__ __launch_bounds__(256)
void transpose_bf16_kernel(const float* __restrict__ in, u16* __restrict__ out,
                           int R, int C)
{
    __shared__ float tile[32][33];
    const int tx = threadIdx.x & 31, ty = threadIdx.x >> 5;
    const int c0 = blockIdx.x * 32, r0 = blockIdx.y * 32;
#pragma unroll
    for (int j = 0; j < 4; ++j)
        tile[ty + j * 8][tx] = in[(size_t)(r0 + ty + j * 8) * C + c0 + tx];
    __syncthreads();
#pragma unroll
    for (int j = 0; j < 4; ++j)
        out[(size_t)(c0 + ty + j * 8) * R + r0 + tx] = f2bf(tile[tx][ty + j * 8]);
}

// --------------------------------------------- MFMA bf16 GEMM, 128x128 tile
// C = act(A[M,K]bf16 @ Bt[N,K]bf16^T) with optional beta(fp32 C in), bias, resid
template<int ACT, int OBF16>   // ACT: 0 none, 1 relu, 2 gelu(exact)
__global__ __launch_bounds__(256)
void gemm_bt(const u16* __restrict__ A, int lda,
             const u16* __restrict__ Bt, int ldb,
             void* __restrict__ Cp, int ldc, int M, int Kt,
             int beta, const float* __restrict__ resid,
             const float* __restrict__ bias, float bscale)
{
    __shared__ u16 As[128 * 32];
    __shared__ u16 Bs[128 * 32];
    const int tid = threadIdx.x;
    const int wid = tid >> 6, lane = tid & 63;
    const int wr = wid >> 1, wc = wid & 1;
    const int row0 = blockIdx.y * 128, col0 = blockIdx.x * 128;
    // staging: wave w covers tile rows w*32 .. w*32+31 (two 16-row issues).
    const int sr = wid * 32 + (lane >> 2);
    const int sc = (lane & 3) * 8;
    const u16* ag = A + (size_t)(row0 + sr) * lda + sc;
    const u16* bg = Bt + (size_t)(col0 + sr) * ldb + sc;
    u16* lA0 = As + wid * 1024;
    u16* lA1 = As + wid * 1024 + 512;
    u16* lB0 = Bs + wid * 1024;
    u16* lB1 = Bs + wid * 1024 + 512;
    f32x4 acc[4][4];
#pragma unroll
    for (int i = 0; i < 4; ++i)
#pragma unroll
        for (int j = 0; j < 4; ++j) acc[i][j] = (f32x4){0.f, 0.f, 0.f, 0.f};
    const int fr = lane & 15, kb8 = (lane >> 4) * 8;
    const u16* pa = As + (wr * 64 + fr) * 32 + kb8;
    const u16* pb = Bs + (wc * 64 + fr) * 32 + kb8;
    for (int k0 = 0; k0 < Kt; k0 += 32) {
        __syncthreads();
        gl2lds(ag, lA0);
        gl2lds(ag + (size_t)16 * lda, lA1);
        gl2lds(bg, lB0);
        gl2lds(bg + (size_t)16 * ldb, lB1);
        ag += 32; bg += 32;
        __syncthreads();
#pragma unroll
        for (int mi = 0; mi < 4; ++mi) {
            bf16x8 af = *(const bf16x8*)(pa + mi * 16 * 32);
#pragma unroll
            for (int ni = 0; ni < 4; ++ni) {
                bf16x8 bfv = *(const bf16x8*)(pb + ni * 16 * 32);
                acc[mi][ni] = __builtin_amdgcn_mfma_f32_16x16x32_bf16(af, bfv, acc[mi][ni], 0, 0, 0);
            }
        }
    }
    const int fq4 = (lane >> 4) * 4;
#pragma unroll
    for (int mi = 0; mi < 4; ++mi) {
#pragma unroll
        for (int j = 0; j < 4; ++j) {
            const int row = row0 + wr * 64 + mi * 16 + fq4 + j;
            if (row >= M) continue;
#pragma unroll
            for (int ni = 0; ni < 4; ++ni) {
                const int col = col0 + wc * 64 + ni * 16 + fr;
                float v = acc[mi][ni][j];
                if (bias) v += bscale * bias[col];
                if (OBF16) {
                    if (ACT == 1) v = fmaxf(v, 0.f);
                    else if (ACT == 2) v = 0.5f * v * (1.f + erff(v * 0.70710678118654752f));
                    ((u16*)Cp)[(size_t)row * ldc + col] = f2bf(v);
                } else {
                    float* Cf = (float*)Cp;
                    const size_t off = (size_t)row * ldc + col;
                    if (beta) v += Cf[off];
                    if (ACT == 1) v = fmaxf(v, 0.f);
                    else if (ACT == 2) v = 0.5f * v * (1.f + erff(v * 0.70710678118654752f));
                    if (resid) v += resid[off];
                    Cf[off] = v;
                }
            }
        }
    }
}

// ------------------------------------- QKV projection via MFMA, 64x64 tiles
__global__ __launch_bounds__(256)
void qkv_mfma_kernel(const u16* __restrict__ hgb, const u16* __restrict__ WqkvT,
                     const float* __restrict__ bq, const float* __restrict__ bk,
                     const float* __restrict__ bv, const int* __restrict__ slot_rule,
                     u16* __restrict__ Qb, u16* __restrict__ Kb, u16* __restrict__ Vb)
{
    const int mt = blockIdx.x, typ = blockIdx.y, z = blockIdx.z;  // z = b*4+slot
    const int b = z >> 2;
    const int r = slot_rule[z];
    const u16* A  = hgb + (size_t)b * TT * DD + (size_t)mt * 64 * DD;
    const u16* Bt = WqkvT + (size_t)typ * DD * DD + (size_t)(r * 64) * DD;
    __shared__ u16 As[64 * 32];
    __shared__ u16 Bs[64 * 32];
    const int tid = threadIdx.x;
    const int wid = tid >> 6, lane = tid & 63;
    const int wr = wid >> 1, wc = wid & 1;
    const u16* ag = A + (size_t)(tid >> 2) * DD + (tid & 3) * 8;
    const u16* bg = Bt + (size_t)(tid >> 2) * DD + (tid & 3) * 8;
    u16* lA = As + wid * 512;
    u16* lB = Bs + wid * 512;
    f32x4 acc[2][2];
#pragma unroll
    for (int i = 0; i < 2; ++i)
#pragma unroll
        for (int j = 0; j < 2; ++j) acc[i][j] = (f32x4){0.f, 0.f, 0.f, 0.f};
    const int fr = lane & 15, kb8 = (lane >> 4) * 8;
    const u16* pa = As + (wr * 32 + fr) * 32 + kb8;
    const u16* pb = Bs + (wc * 32 + fr) * 32 + kb8;
    for (int k0 = 0; k0 < DD; k0 += 32) {
        __syncthreads();
        gl2lds(ag, lA);
        gl2lds(bg, lB);
        ag += 32; bg += 32;
        __syncthreads();
#pragma unroll
        for (int mi = 0; mi < 2; ++mi) {
            bf16x8 af = *(const bf16x8*)(pa + mi * 16 * 32);
#pragma unroll
            for (int ni = 0; ni < 2; ++ni) {
                bf16x8 bfv = *(const bf16x8*)(pb + ni * 16 * 32);
                acc[mi][ni] = __builtin_amdgcn_mfma_f32_16x16x32_bf16(af, bfv, acc[mi][ni], 0, 0, 0);
            }
        }
    }
    const float* bias = (typ == 0) ? bq : (typ == 1) ? bk : bv;
    const float scale = (typ == 0) ? 0.125f : 1.f;
    u16* out = ((typ == 0) ? Qb : (typ == 1) ? Kb : Vb) + (size_t)z * TT * 64;
    const int fq4 = (lane >> 4) * 4;
#pragma unroll
    for (int mi = 0; mi < 2; ++mi)
#pragma unroll
        for (int j = 0; j < 4; ++j) {
            const int row = mt * 64 + wr * 32 + mi * 16 + fq4 + j;
#pragma unroll
            for (int ni = 0; ni < 2; ++ni) {
                const int col = wc * 32 + ni * 16 + fr;
                out[(size_t)row * 64 + col] = f2bf((acc[mi][ni][j] + bias[r * 64 + col]) * scale);
            }
        }
}

// ---------------------------------- V [z][t][64] -> VT [z][64][704]  (bf16)
__global__ __launch_bounds__(256)
void vtrans_kernel(const u16* __restrict__ Vb, u16* __restrict__ VT)
{
    const int tt = blockIdx.x, z = blockIdx.y;   // 11 x 32
    const int d = threadIdx.x & 63, tc = threadIdx.x >> 6;
    const size_t bs = (size_t)z * TT;
    u16x8 a, b2;
#pragma unroll
    for (int i = 0; i < 8; ++i)
        a[i] = Vb[(bs + tt * 64 + tc * 16 + i) * 64 + d];
#pragma unroll
    for (int i = 0; i < 8; ++i)
        b2[i] = Vb[(bs + tt * 64 + tc * 16 + 8 + i) * 64 + d];
    u16* dst = VT + ((size_t)z * 64 + d) * TT + tt * 64 + tc * 16;
    *(u16x8*)dst = a;
    *(u16x8*)(dst + 8) = b2;
}

// ----------------------------------------- MFMA bf16 flash attention / slot
__global__ __launch_bounds__(256)
void attn_mfma_kernel(const u16* __restrict__ Qb, const u16* __restrict__ Kb,
                      const u16* __restrict__ VT, const float* __restrict__ amask,
                      float* __restrict__ AO)
{
    const int qt = blockIdx.x, slot = blockIdx.y, b = blockIdx.z;
    const int z = b * 4 + slot;
    const size_t bs = (size_t)z * TT;
    const int tid = threadIdx.x;
    const int w = tid >> 6, lane = tid & 63;
    const int fr = lane & 15, g = lane >> 4;
    const int q0 = qt * 64 + w * 16;

    __shared__ u16 Ks[64 * 72];    // [key][d], stride 72 (144B = 9x16B, aligned)
    __shared__ u16 VTs[64 * 72];   // [d][key]
    __shared__ u16 Ps[4][16 * 72]; // per-wave P tile [q][key]

    bf16x8 qa[2];
    qa[0] = *(const bf16x8*)(Qb + (bs + q0 + fr) * 64 + g * 8);
    qa[1] = *(const bf16x8*)(Qb + (bs + q0 + fr) * 64 + 32 + g * 8);

    float m_run[4], l_run[4];
    f32x4 oacc[4];
#pragma unroll
    for (int j = 0; j < 4; ++j) { m_run[j] = -1e30f; l_run[j] = 0.f; }
#pragma unroll
    for (int ni = 0; ni < 4; ++ni) oacc[ni] = (f32x4){0.f, 0.f, 0.f, 0.f};

    const float* mrow = amask + ((size_t)b * TT + q0 + g * 4) * TT;

    for (int kc = 0; kc < 11; ++kc) {
        const int kv0 = kc * 64;
        __syncthreads();
#pragma unroll
        for (int it = 0; it < 2; ++it) {
            const int idx = tid + it * 256;
            const int row = idx >> 3, ch = (idx & 7) * 8;
            *(u16x8*)&Ks[row * 72 + ch]  = *(const u16x8*)(Kb + (bs + kv0 + row) * 64 + ch);
            *(u16x8*)&VTs[row * 72 + ch] = *(const u16x8*)(VT + ((size_t)z * 64 + row) * TT + kv0 + ch);
        }
        __syncthreads();
        // S = Q K^T
        f32x4 sacc[4];
#pragma unroll
        for (int ni = 0; ni < 4; ++ni) sacc[ni] = (f32x4){0.f, 0.f, 0.f, 0.f};
#pragma unroll
        for (int c = 0; c < 2; ++c)
#pragma unroll
            for (int ni = 0; ni < 4; ++ni) {
                bf16x8 bf = *(const bf16x8*)&Ks[(ni * 16 + fr) * 72 + c * 32 + g * 8];
                sacc[ni] = __builtin_amdgcn_mfma_f32_16x16x32_bf16(qa[c], bf, sacc[ni], 0, 0, 0);
            }
        // + mask, row max
        float mloc[4] = {-1e30f, -1e30f, -1e30f, -1e30f};
#pragma unroll
        for (int ni = 0; ni < 4; ++ni)
#pragma unroll
            for (int j = 0; j < 4; ++j) {
                float s = sacc[ni][j] + mrow[(size_t)j * TT + kv0 + ni * 16 + fr];
                sacc[ni][j] = s;
                mloc[j] = fmaxf(mloc[j], s);
            }
#pragma unroll
        for (int o = 1; o < 16; o <<= 1)
#pragma unroll
            for (int j = 0; j < 4; ++j) mloc[j] = fmaxf(mloc[j], __shfl_xor(mloc[j], o));
        float fac[4], lsum[4];
#pragma unroll
        for (int j = 0; j < 4; ++j) {
            const float mn = fmaxf(m_run[j], mloc[j]);
            fac[j] = __expf(m_run[j] - mn);
            m_run[j] = mn;
            lsum[j] = 0.f;
        }
#pragma unroll
        for (int ni = 0; ni < 4; ++ni)
#pragma unroll
            for (int j = 0; j < 4; ++j) {
                const float p = __expf(sacc[ni][j] - m_run[j]);
                lsum[j] += p;
                Ps[w][(g * 4 + j) * 72 + ni * 16 + fr] = f2bf(p);
            }
#pragma unroll
        for (int o = 1; o < 16; o <<= 1)
#pragma unroll
            for (int j = 0; j < 4; ++j) lsum[j] += __shfl_xor(lsum[j], o);
#pragma unroll
        for (int j = 0; j < 4; ++j) l_run[j] = l_run[j] * fac[j] + lsum[j];
#pragma unroll
        for (int ni = 0; ni < 4; ++ni)
#pragma unroll
            for (int j = 0; j < 4; ++j) oacc[ni][j] *= fac[j];
        // O += P V
#pragma unroll
        for (int c = 0; c < 2; ++c) {
            bf16x8 paf = *(const bf16x8*)&Ps[w][fr * 72 + c * 32 + g * 8];
#pragma unroll
            for (int ni = 0; ni < 4; ++ni) {
                bf16x8 vf = *(const bf16x8*)&VTs[(ni * 16 + fr) * 72 + c * 32 + g * 8];
                oacc[ni] = __builtin_amdgcn_mfma_f32_16x16x32_bf16(paf, vf, oacc[ni], 0, 0, 0);
            }
        }
    }
#pragma unroll
    for (int j = 0; j < 4; ++j) {
        const float inv = 1.f / l_run[j];
        const int t = q0 + g * 4 + j;
#pragma unroll
        for (int ni = 0; ni < 4; ++ni)
            AO[(bs + t) * 64 + ni * 16 + fr] = oacc[ni][j] * inv;
    }
}

// ------------------------------------------------ sum AO over slots -> bf16
__global__ __launch_bounds__(256)
void aosum_kernel(const float* __restrict__ AO, u16* __restrict__ AOs)
{
    const int i = blockIdx.x * 256 + threadIdx.x;   // over BT*64
    const int bt = i >> 6;
    const int b = bt / TT, t = bt - b * TT;
    const int c = i & 63;
    float s = 0.f;
#pragma unroll
    for (int slot = 0; slot < 4; ++slot)
        s += AO[(((size_t)(b * 4 + slot)) * TT + t) * 64 + c];
    AOs[i] = f2bf(s);
}

// --------------------------------------------------- relu + fp32->bf16 conv
__global__ __launch_bounds__(256)
void reluconv_kernel(const float* __restrict__ x, u16* __restrict__ y)
{
    const int i = (blockIdx.x * 256 + threadIdx.x) * 4;
    float4 v = *(const float4*)(x + i);
    u16x4 o = {f2bf(fmaxf(v.x, 0.f)), f2bf(fmaxf(v.y, 0.f)),
               f2bf(fmaxf(v.z, 0.f)), f2bf(fmaxf(v.w, 0.f))};
    *(u16x4*)(y + i) = o;
}

// ---------------------------------------------------------------- launcher
extern "C" void kernel_launch(void* const* d_in, const int* in_sizes, int n_in,
                              void* d_out, int out_size, void* d_ws, size_t ws_size,
                              hipStream_t stream)
{
    const float* hidden = (const float*)d_in[0];
    const float* amask  = (const float*)d_in[1];
    const float* rules  = (const float*)d_in[2];
    const float* W_ent  = (const float*)d_in[3];
    const float* b_ent  = (const float*)d_in[4];
    const float* Wq_er  = (const float*)d_in[5];
    const float* Wk_er  = (const float*)d_in[6];
    const float* Wq_es  = (const float*)d_in[7];
    const float* Wk_es  = (const float*)d_in[8];
    const float* Wq     = (const float*)d_in[9];
    const float* bq     = (const float*)d_in[10];
    const float* Wk     = (const float*)d_in[11];
    const float* bk     = (const float*)d_in[12];
    const float* Wv     = (const float*)d_in[13];
    const float* bv     = (const float*)d_in[14];
    const float* Wo     = (const float*)d_in[15];
    const float* bo     = (const float*)d_in[16];
    const float* ln1_g  = (const float*)d_in[17];
    const float* ln1_b  = (const float*)d_in[18];
    const float* ln2_g  = (const float*)d_in[19];
    const float* ln2_b  = (const float*)d_in[20];
    const float* fc1_w1 = (const float*)d_in[21];
    const float* fc1_w2 = (const float*)d_in[22];
    const float* fc2_w1 = (const float*)d_in[23];
    const float* fc2_w2 = (const float*)d_in[24];

    char* ws = (char*)d_ws;
    // byte offsets; total 86,314,240 B
    float* h      = (float*)(ws + 0);              // 23,068,672  [ln1..hg]
    u16*   x1     = (u16*)(ws + 0);                //  5,767,168  [G1..G2]   (dead h)
    u16*   x2c    = (u16*)(ws + 5767168);          // 11,534,336  [G2..G3]   (dead h)
    float* hmid   = (float*)(ws + 23068672);       // 23,068,672  [combine..end]
    u16*   hgb    = (u16*)(ws + 46137344);         // 11,534,336  [hg..qkv]
    u16*   xln2   = (u16*)(ws + 46137344);         //   (reuse)   [ln2..G1]
    float* x3f    = (float*)(ws + 46137344);       //   (reuse)   [G3..reluconv]
    u16*   Qb     = (u16*)(ws + 57671680);         //  2,883,584  [qkv..attn]
    u16*   x3b    = (u16*)(ws + 57671680);         //   (reuse, 5.7MB over Qb+Kb) [reluconv..G4]
    u16*   Kb     = (u16*)(ws + 60555264);         //  2,883,584
    u16*   Vb     = (u16*)(ws + 63438848);         //  2,883,584
    u16*   VT     = (u16*)(ws + 66322432);         //  2,883,584
    float* AO     = (float*)(ws + 69206016);       //  5,767,168  [attn..aosum]
    float* part   = (float*)(ws + 69206016);       //    360,448  (dead before AO)
    float* ent    = (float*)(ws + 74973184);       //      3,072
    float* gate   = (float*)(ws + 74976256);       //        128
    int*   srule  = (int*)(ws + 74976384);         //        128
    u16*   AOs    = (u16*)(ws + 74976512);         //    720,896
    u16*   WqkvT  = (u16*)(ws + 75697408);         //  6,291,456  [..qkv]
    u16*   fc1w2T = (u16*)(ws + 75697408);         //  4,194,304  (after qkv)
    u16*   fc2w1T = (u16*)(ws + 79891712);         //  4,194,304  (after qkv)
    u16*   WoT    = (u16*)(ws + 84086016);         //    131,072
    u16*   fc1w1T = (u16*)(ws + 84217088);         //  1,048,576
    u16*   fc2w2T = (u16*)(ws + 85265664);         //  1,048,576
    float* out    = (float*)d_out;

    // --- LN1 + selection path (fp32)
    ln_kernel<0><<<BT, 256, 0, stream>>>(hidden, ln1_g, ln1_b, h);
    pool_partial_kernel<<<dim3(11, 8), 256, 0, stream>>>(h, part);
    pool_finish_kernel<<<24, 256, 0, stream>>>(part, W_ent, b_ent, ent);
    select_kernel<<<1, 256, 0, stream>>>(ent, rules, Wq_er, Wk_er, Wq_es, Wk_es, srule, gate);
    hg_kernel<<<BT, 256, 0, stream>>>(h, gate, hgb);

    // --- weight prep (phase 1: needed before/at qkv)
    transpose_bf16_kernel<<<dim3(32, 32), 256, 0, stream>>>(Wq, WqkvT,               1024, 1024);
    transpose_bf16_kernel<<<dim3(32, 32), 256, 0, stream>>>(Wk, WqkvT + 1024*1024,   1024, 1024);
    transpose_bf16_kernel<<<dim3(32, 32), 256, 0, stream>>>(Wv, WqkvT + 2*1024*1024, 1024, 1024);
    transpose_bf16_kernel<<<dim3(32, 2),  256, 0, stream>>>(Wo, WoT, 64, 1024);
    transpose_bf16_kernel<<<dim3(16, 32), 256, 0, stream>>>(fc1_w1, fc1w1T, 1024, 512);
    transpose_bf16_kernel<<<dim3(32, 16), 256, 0, stream>>>(fc2_w2, fc2w2T, 512, 1024);

    // --- QKV (MFMA, bf16 out) + V transpose + attention (MFMA)
    qkv_mfma_kernel<<<dim3(11, 3, 32), 256, 0, stream>>>(hgb, WqkvT, bq, bk, bv, srule,
                                                         Qb, Kb, Vb);
    vtrans_kernel<<<dim3(11, 32), 256, 0, stream>>>(Vb, VT);
    // weight prep phase 2 (aliases WqkvT region, so must come after qkv)
    transpose_bf16_kernel<<<dim3(128, 16), 256, 0, stream>>>(fc1_w2, fc1w2T, 512, 4096);
    transpose_bf16_kernel<<<dim3(16, 128), 256, 0, stream>>>(fc2_w1, fc2w1T, 4096, 512);

    attn_mfma_kernel<<<dim3(11, 4, 8), 256, 0, stream>>>(Qb, Kb, VT, amask, AO);
    aosum_kernel<<<1408, 256, 0, stream>>>(AO, AOs);

    // --- combine: hmid = hidden + AOs @ WoT^T + 4*bo   (MFMA)
    gemm_bt<0, 0><<<dim3(8, 44), 256, 0, stream>>>(AOs, 64, WoT, 64, hmid, 1024,
                                                   BT, 64, 0, hidden, bo, 4.f);
    // --- LN2 -> bf16
    ln_kernel<1><<<BT, 256, 0, stream>>>(hmid, ln2_g, ln2_b, xln2);

    // --- MLP (all MFMA)
    gemm_bt<1, 1><<<dim3(4, 44), 256, 0, stream>>>(xln2, 1024, fc1w1T, 1024, x1, 512,
                                                   BT, 1024, 0, nullptr, nullptr, 0.f);
    for (int c = 0; c < 4; ++c) {
        gemm_bt<2, 1><<<dim3(8, 44), 256, 0, stream>>>(x1, 512, fc1w2T + (size_t)c * 1024 * 512, 512,
                                                       x2c, 1024, BT, 512, 0, nullptr, nullptr, 0.f);
        gemm_bt<0, 0><<<dim3(4, 44), 256, 0, stream>>>(x2c, 1024, fc2w1T + c * 1024, 4096,
                                                       x3f, 512, BT, 1024, (c > 0) ? 1 : 0,
                                                       nullptr, nullptr, 0.f);
    }
    reluconv_kernel<<<(BT * 512) / 1024, 256, 0, stream>>>(x3f, x3b);
    gemm_bt<0, 0><<<dim3(8, 44), 256, 0, stream>>>(x3b, 512, fc2w2T, 512, out, 1024,
                                                   BT, 512, 0, hmid, nullptr, 0.f);
}

// Round 5
// 352.561 us; speedup vs baseline: 7.1069x; 1.4218x over previous
//
#include <hip/hip_runtime.h>
#include <hip/hip_bf16.h>
#include <math.h>

// Problem constants
#define BB 8
#define TT 704
#define DD 1024
#define RR 16
#define KK 4
#define HDH 64
#define BT (BB*TT)   // 5632

typedef unsigned short u16;
typedef __attribute__((ext_vector_type(4))) float f32x4;
typedef __attribute__((ext_vector_type(8))) short bf16x8;
typedef __attribute__((ext_vector_type(4))) unsigned short u16x4;
typedef __attribute__((ext_vector_type(8))) unsigned short u16x8;

__device__ __forceinline__ u16 f2bf(float f) {
    union { float f; unsigned int u; } cv; cv.f = f;
    unsigned int u = cv.u;
    unsigned int r = (u + 0x7fffu + ((u >> 16) & 1u)) >> 16;
    return (u16)r;
}

__device__ __forceinline__ void gl2lds(const u16* g, u16* l) {
    __builtin_amdgcn_global_load_lds(
        (const __attribute__((address_space(1))) void*)g,
        (__attribute__((address_space(3))) void*)l, 16, 0, 0);
}

template<int N> __device__ __forceinline__ void waitv() {
    if constexpr (N == 0) asm volatile("s_waitcnt vmcnt(0)" ::: "memory");
    else if constexpr (N == 2) asm volatile("s_waitcnt vmcnt(2)" ::: "memory");
    else if constexpr (N == 3) asm volatile("s_waitcnt vmcnt(3)" ::: "memory");
    else asm volatile("s_waitcnt vmcnt(4)" ::: "memory");
}

// ---------------------------------------------------------------- LayerNorm
template<int OBF16>
__global__ __launch_bounds__(256)
void ln_kernel(const float* __restrict__ x, const float* __restrict__ g,
               const float* __restrict__ be, void* __restrict__ yv)
{
    const int row = blockIdx.x;
    const int tid = threadIdx.x;
    __shared__ float sbuf[4];
    const size_t off = (size_t)row * DD + tid * 4;
    float4 v = *(const float4*)(x + off);
    float s = v.x + v.y + v.z + v.w;
#pragma unroll
    for (int o = 32; o; o >>= 1) s += __shfl_xor(s, o);
    if ((tid & 63) == 0) sbuf[tid >> 6] = s;
    __syncthreads();
    float mean = (sbuf[0] + sbuf[1] + sbuf[2] + sbuf[3]) * (1.f / 1024.f);
    float dx = v.x - mean, dy = v.y - mean, dz = v.z - mean, dw = v.w - mean;
    float q = dx*dx + dy*dy + dz*dz + dw*dw;
    __syncthreads();
#pragma unroll
    for (int o = 32; o; o >>= 1) q += __shfl_xor(q, o);
    if ((tid & 63) == 0) sbuf[tid >> 6] = q;
    __syncthreads();
    float var = (sbuf[0] + sbuf[1] + sbuf[2] + sbuf[3]) * (1.f / 1024.f);
    float rstd = rsqrtf(var + 1e-5f);
    float4 gg = *(const float4*)(g + tid * 4);
    float4 bb4 = *(const float4*)(be + tid * 4);
    float o0 = dx * rstd * gg.x + bb4.x;
    float o1 = dy * rstd * gg.y + bb4.y;
    float o2 = dz * rstd * gg.z + bb4.z;
    float o3 = dw * rstd * gg.w + bb4.w;
    if (OBF16) {
        u16x4 o4 = {f2bf(o0), f2bf(o1), f2bf(o2), f2bf(o3)};
        *(u16x4*)((u16*)yv + off) = o4;
    } else {
        float4 o4 = {o0, o1, o2, o3};
        *(float4*)((float*)yv + off) = o4;
    }
}

// -------------------------------------------------- entity pooling (2-phase)
__global__ __launch_bounds__(256)
void pool_partial_kernel(const float* __restrict__ h, float* __restrict__ partial)
{
    const int chunk = blockIdx.x, b = blockIdx.y;   // 11 chunks of 64 tokens
    const int d = threadIdx.x * 4;
    const float* p = h + ((size_t)b * TT + chunk * 64) * DD + d;
    float4 s = {0.f, 0.f, 0.f, 0.f};
    for (int t = 0; t < 64; ++t) {
        float4 v = *(const float4*)(p + (size_t)t * DD);
        s.x += v.x; s.y += v.y; s.z += v.z; s.w += v.w;
    }
    *(float4*)(partial + ((size_t)(b * 11 + chunk)) * 1024 + d) = s;
}

__global__ __launch_bounds__(256)
void pool_finish_kernel(const float* __restrict__ partial, const float* __restrict__ W_ent,
                        const float* __restrict__ b_ent, float* __restrict__ entities)
{
    const int b = blockIdx.x / 3, e = blockIdx.x % 3;
    const int c0 = (e == 0) ? 0 : (e == 1) ? 2 : 3;
    const int c1 = (e == 0) ? 2 : (e == 1) ? 3 : 11;
    const float invlen = (e == 0) ? (1.f/128.f) : (e == 1) ? (1.f/64.f) : (1.f/512.f);
    __shared__ float pooled[1024];
    __shared__ float part[8][32];
    const int tid = threadIdx.x;
    {
        const int d = tid * 4;
        float4 s = {0.f, 0.f, 0.f, 0.f};
        for (int c = c0; c < c1; ++c) {
            float4 v = *(const float4*)(partial + ((size_t)(b * 11 + c)) * 1024 + d);
            s.x += v.x; s.y += v.y; s.z += v.z; s.w += v.w;
        }
        pooled[d+0] = s.x * invlen; pooled[d+1] = s.y * invlen;
        pooled[d+2] = s.z * invlen; pooled[d+3] = s.w * invlen;
    }
    __syncthreads();
    const int g = tid >> 5, j = tid & 31;
    float s = 0.f;
    for (int d = g * 128; d < g * 128 + 128; ++d) s = fmaf(pooled[d], W_ent[d * 32 + j], s);
    part[g][j] = s;
    __syncthreads();
    if (tid < 32) {
        float s2 = b_ent[tid];
        for (int g2 = 0; g2 < 8; ++g2) s2 += part[g2][tid];
        entities[blockIdx.x * 32 + tid] = s2;
    }
}

// ----------------------------------------------------- rule/entity selection
__global__ __launch_bounds__(256)
void select_kernel(const float* __restrict__ entities, const float* __restrict__ rules,
                   const float* __restrict__ Wq_er, const float* __restrict__ Wk_er,
                   const float* __restrict__ Wq_es, const float* __restrict__ Wk_es,
                   int* __restrict__ slot_rule, float* __restrict__ gate)
{
    __shared__ float q_er_s[2048];   // [k][r][d]  4*16*32
    __shared__ float k_er_s[768];    // [b][e][d]  8*3*32
    __shared__ float k_es_s[384];    // [b][e][i]  8*3*16
    __shared__ int   sel_e[32];
    const int tid = threadIdx.x;
    for (int idx = tid; idx < 2048; idx += 256) {
        int k = idx >> 9, rem = idx & 511, r = rem >> 5, d = rem & 31;
        float s = 0.f;
        for (int hh = 0; hh < 64; ++hh)
            s = fmaf(rules[(k * 16 + r) * 64 + hh], Wq_er[hh * 32 + d], s);
        q_er_s[idx] = s;
    }
    for (int idx = tid; idx < 768; idx += 256) {
        int be = idx >> 5, d = idx & 31;
        float s = 0.f;
        for (int ss = 0; ss < 32; ++ss)
            s = fmaf(entities[be * 32 + ss], Wk_er[ss * 32 + d], s);
        k_er_s[idx] = s;
    }
    for (int idx = tid; idx < 384; idx += 256) {
        int be = idx >> 4, i = idx & 15;
        float s = 0.f;
        for (int ss = 0; ss < 32; ++ss)
            s = fmaf(entities[be * 32 + ss], Wk_es[ss * 16 + i], s);
        k_es_s[idx] = s;
    }
    __syncthreads();
    if (tid < 32) {
        const int b = tid >> 2, k = tid & 3;
        float best = -1e30f; int bi = 0;
        for (int r = 0; r < 16; ++r)
            for (int e = 0; e < 3; ++e) {
                const float* qp = &q_er_s[(k * 16 + r) * 32];
                const float* kp = &k_er_s[(b * 3 + e) * 32];
                float s = 0.f;
                for (int d = 0; d < 32; ++d) s = fmaf(qp[d], kp[d], s);
                s *= 0.17677669529663687f;   // 1/sqrt(32)
                int idx = r * 3 + e;
                if (s > best) { best = s; bi = idx; }   // first-wins tie => matches lax.top_k
            }
        const int rstar = bi / 3;
        slot_rule[b * 4 + k] = rstar;
        float qes[16];
        for (int i = 0; i < 16; ++i) {
            float s = 0.f;
            for (int hh = 0; hh < 64; ++hh)
                s = fmaf(rules[(k * 16 + rstar) * 64 + hh], Wq_es[(k * 64 + hh) * 16 + i], s);
            qes[i] = s;
        }
        float best2 = -1e30f; int ei = 0;
        for (int e = 0; e < 3; ++e) {
            float s = 0.f;
            for (int i = 0; i < 16; ++i) s = fmaf(qes[i], k_es_s[(b * 3 + e) * 16 + i], s);
            s *= 0.25f;   // 1/sqrt(16)
            if (s > best2) { best2 = s; ei = e; }
        }
        sel_e[tid] = ei;
    }
    __syncthreads();
    if (tid < 24) {
        const int b = tid / 3, e = tid % 3;
        float g = 0.f;
        for (int k = 0; k < 4; ++k) g += (sel_e[b * 4 + k] == e) ? 1.f : 0.f;
        gate[b * 3 + e] = g;
    }
}

// ---------------------------------------------- gated hidden -> bf16 staging
__global__ __launch_bounds__(256)
void hg_kernel(const float* __restrict__ h, const float* __restrict__ gate,
               u16* __restrict__ hgb)
{
    const int row = blockIdx.x;   // b*T + t
    const int b = row / TT, t = row - b * TT;
    const float g = gate[b * 3 + ((t < 128) ? 0 : (t < 192) ? 1 : 2)];
    const size_t off = (size_t)row * DD + threadIdx.x * 4;
    float4 v = *(const float4*)(h + off);
    u16x4 o = {f2bf(v.x * g), f2bf(v.y * g), f2bf(v.z * g), f2bf(v.w * g)};
    *(u16x4*)(hgb + off) = o;
}

// --------------------------------------- fp32 [R][C] -> bf16 [C][R] transpose
__global__ __launch_bounds__(256)
void transpose_bf16_kernel(const float* __restrict__ in, u16* __restrict__ out,
                           int R, int C)
{
    __shared__ float tile[32][33];
    const int tx = threadIdx.x & 31, ty = threadIdx.x >> 5;
    const int c0 = blockIdx.x * 32, r0 = blockIdx.y * 32;
#pragma unroll
    for (int j = 0; j < 4; ++j)
        tile[ty + j * 8][tx] = in[(size_t)(r0 + ty + j * 8) * C + c0 + tx];
    __syncthreads();
#pragma unroll
    for (int j = 0; j < 4; ++j)
        out[(size_t)(c0 + ty + j * 8) * R + r0 + tx] = f2bf(tile[tx][ty + j * 8]);
}

// ------------------------------- pipelined MFMA bf16 GEMM, 128xBN tile, 3-buf
// C[z] = act(A[M, z*Ksub : (z+1)*Ksub] @ Bt[N, same]^T) (+bias*bscale) (+resid)
template<int BN, int ACT, int OBF16>   // ACT: 0 none, 1 relu, 2 gelu(exact)
__global__ __launch_bounds__(256)
void gemm2(const u16* __restrict__ A, int lda, const u16* __restrict__ Bt, int ldb,
           void* C0, void* C1, void* C2, void* C3, int ldc, int M, int Ksub,
           const float* __restrict__ resid, const float* __restrict__ bias, float bscale)
{
    constexpr int MI = (BN == 128) ? 4 : 2;     // 16-row frags per wave
    constexpr int NLOAD = 2 + ((BN == 128) ? 2 : 1);
    __shared__ u16 As[3][128 * 32];
    __shared__ u16 Bs[3][BN * 32];
    const int tid = threadIdx.x;
    const int wid = tid >> 6, lane = tid & 63;
    const int z = blockIdx.z;
    const int row0 = blockIdx.y * 128, col0 = blockIdx.x * BN;
    const size_t koff = (size_t)z * Ksub;
    // staging addresses (wave-linear dest per gl2lds semantics)
    const int srA = wid * 32 + (lane >> 2);
    const int sc = (lane & 3) * 8;
    const u16* ag = A + (size_t)(row0 + srA) * lda + koff + sc;
    const int srB = (BN == 128) ? (wid * 32 + (lane >> 2)) : (wid * 16 + (lane >> 2));
    const u16* bg = Bt + (size_t)(col0 + srB) * ldb + koff + sc;
    const int nt = Ksub >> 5;

    auto STAGE = [&](int buf, int t) {
        const u16* a = ag + t * 32;
        const u16* b = bg + t * 32;
        gl2lds(a, &As[buf][wid * 1024]);
        gl2lds(a + (size_t)16 * lda, &As[buf][wid * 1024 + 512]);
        if constexpr (BN == 128) {
            gl2lds(b, &Bs[buf][wid * 1024]);
            gl2lds(b + (size_t)16 * ldb, &Bs[buf][wid * 1024 + 512]);
        } else {
            gl2lds(b, &Bs[buf][wid * 512]);
        }
    };

    f32x4 acc[MI][4];
#pragma unroll
    for (int i = 0; i < MI; ++i)
#pragma unroll
        for (int j = 0; j < 4; ++j) acc[i][j] = (f32x4){0.f, 0.f, 0.f, 0.f};

    const int fr = lane & 15, kb8 = (lane >> 4) * 8;
    const int wrbase = (BN == 128) ? (wid >> 1) * 64 : wid * 32;
    const int wcbase = (BN == 128) ? (wid & 1) * 64 : 0;
    const int paoff = (wrbase + fr) * 32 + kb8;
    const int pboff = (wcbase + fr) * 32 + kb8;

    STAGE(0, 0);
    if (nt > 1) STAGE(1, 1);
    for (int t = 0; t < nt; ++t) {
        if (t + 1 < nt) waitv<NLOAD>(); else waitv<0>();
        __builtin_amdgcn_s_barrier();
        asm volatile("" ::: "memory");
        const int buf = t % 3;
#pragma unroll
        for (int mi = 0; mi < MI; ++mi) {
            bf16x8 af = *(const bf16x8*)&As[buf][paoff + mi * 512];
#pragma unroll
            for (int ni = 0; ni < 4; ++ni) {
                bf16x8 bfv = *(const bf16x8*)&Bs[buf][pboff + ni * 512];
                acc[mi][ni] = __builtin_amdgcn_mfma_f32_16x16x32_bf16(af, bfv, acc[mi][ni], 0, 0, 0);
            }
        }
        if (t + 2 < nt) STAGE((t + 2) % 3, t + 2);
    }

    void* Cp = (z == 0) ? C0 : (z == 1) ? C1 : (z == 2) ? C2 : C3;
    const int fq4 = (lane >> 4) * 4;
#pragma unroll
    for (int mi = 0; mi < MI; ++mi) {
#pragma unroll
        for (int j = 0; j < 4; ++j) {
            const int row = row0 + wrbase + mi * 16 + fq4 + j;
#pragma unroll
            for (int ni = 0; ni < 4; ++ni) {
                const int col = col0 + wcbase + ni * 16 + fr;
                float v = acc[mi][ni][j];
                if (bias) v += bscale * bias[col];
                if (ACT == 1) v = fmaxf(v, 0.f);
                else if (ACT == 2) v = 0.5f * v * (1.f + erff(v * 0.70710678118654752f));
                const size_t off = (size_t)row * ldc + col;
                if (OBF16) {
                    ((u16*)Cp)[off] = f2bf(v);
                } else {
                    if (resid) v += resid[off];
                    ((float*)Cp)[off] = v;
                }
            }
        }
    }
}

// ------------------------------------------- split-K reduce: relu + bf16 out
template<int NP>
__global__ __launch_bounds__(256)
void red_relu_kernel(const float* __restrict__ p0, const float* __restrict__ p1,
                     const float* __restrict__ p2, const float* __restrict__ p3,
                     u16* __restrict__ out)
{
    const int i = (blockIdx.x * 256 + threadIdx.x) * 4;
    float4 a = *(const float4*)(p0 + i);
    float4 b = *(const float4*)(p1 + i);
    a.x += b.x; a.y += b.y; a.z += b.z; a.w += b.w;
    if (NP == 4) {
        float4 c = *(const float4*)(p2 + i);
        float4 d = *(const float4*)(p3 + i);
        a.x += c.x + d.x; a.y += c.y + d.y; a.z += c.z + d.z; a.w += c.w + d.w;
    }
    u16x4 o = {f2bf(fmaxf(a.x, 0.f)), f2bf(fmaxf(a.y, 0.f)),
               f2bf(fmaxf(a.z, 0.f)), f2bf(fmaxf(a.w, 0.f))};
    *(u16x4*)(out + i) = o;
}

// ------------------------------- QKV projection via MFMA, 64x64 tiles, 3-buf
__global__ __launch_bounds__(256)
void qkv_mfma_kernel(const u16* __restrict__ hgb, const u16* __restrict__ WqkvT,
                     const float* __restrict__ bq, const float* __restrict__ bk,
                     const float* __restrict__ bv, const int* __restrict__ slot_rule,
                     u16* __restrict__ Qb, u16* __restrict__ Kb, u16* __restrict__ Vb)
{
    const int mt = blockIdx.x, typ = blockIdx.y, z = blockIdx.z;  // z = b*4+slot
    const int b = z >> 2;
    const int r = slot_rule[z];
    const u16* A  = hgb + (size_t)b * TT * DD + (size_t)mt * 64 * DD;
    const u16* Bt = WqkvT + (size_t)typ * DD * DD + (size_t)(r * 64) * DD;
    __shared__ u16 As[3][64 * 32];
    __shared__ u16 Bs[3][64 * 32];
    const int tid = threadIdx.x;
    const int wid = tid >> 6, lane = tid & 63;
    const int wr = wid >> 1, wc = wid & 1;
    const u16* ag = A + (size_t)(tid >> 2) * DD + (tid & 3) * 8;
    const u16* bg = Bt + (size_t)(tid >> 2) * DD + (tid & 3) * 8;
    auto STAGE = [&](int buf, int t) {
        gl2lds(ag + t * 32, &As[buf][wid * 512]);
        gl2lds(bg + t * 32, &Bs[buf][wid * 512]);
    };
    f32x4 acc[2][2];
#pragma unroll
    for (int i = 0; i < 2; ++i)
#pragma unroll
        for (int j = 0; j < 2; ++j) acc[i][j] = (f32x4){0.f, 0.f, 0.f, 0.f};
    const int fr = lane & 15, kb8 = (lane >> 4) * 8;
    const int paoff = (wr * 32 + fr) * 32 + kb8;
    const int pboff = (wc * 32 + fr) * 32 + kb8;
    const int nt = 32;
    STAGE(0, 0);
    STAGE(1, 1);
    for (int t = 0; t < nt; ++t) {
        if (t + 1 < nt) waitv<2>(); else waitv<0>();
        __builtin_amdgcn_s_barrier();
        asm volatile("" ::: "memory");
        const int buf = t % 3;
#pragma unroll
        for (int mi = 0; mi < 2; ++mi) {
            bf16x8 af = *(const bf16x8*)&As[buf][paoff + mi * 512];
#pragma unroll
            for (int ni = 0; ni < 2; ++ni) {
                bf16x8 bfv = *(const bf16x8*)&Bs[buf][pboff + ni * 512];
                acc[mi][ni] = __builtin_amdgcn_mfma_f32_16x16x32_bf16(af, bfv, acc[mi][ni], 0, 0, 0);
            }
        }
        if (t + 2 < nt) STAGE((t + 2) % 3, t + 2);
    }
    const float* bias = (typ == 0) ? bq : (typ == 1) ? bk : bv;
    const float scale = (typ == 0) ? 0.125f : 1.f;
    u16* out = ((typ == 0) ? Qb : (typ == 1) ? Kb : Vb) + (size_t)z * TT * 64;
    const int fq4 = (lane >> 4) * 4;
#pragma unroll
    for (int mi = 0; mi < 2; ++mi)
#pragma unroll
        for (int j = 0; j < 4; ++j) {
            const int row = mt * 64 + wr * 32 + mi * 16 + fq4 + j;
#pragma unroll
            for (int ni = 0; ni < 2; ++ni) {
                const int col = wc * 32 + ni * 16 + fr;
                out[(size_t)row * 64 + col] = f2bf((acc[mi][ni][j] + bias[r * 64 + col]) * scale);
            }
        }
}

// ---------------------------------- V [z][t][64] -> VT [z][64][704]  (bf16)
__global__ __launch_bounds__(256)
void vtrans_kernel(const u16* __restrict__ Vb, u16* __restrict__ VT)
{
    const int tt = blockIdx.x, z = blockIdx.y;   // 11 x 32
    const int d = threadIdx.x & 63, tc = threadIdx.x >> 6;
    const size_t bs = (size_t)z * TT;
    u16x8 a, b2;
#pragma unroll
    for (int i = 0; i < 8; ++i)
        a[i] = Vb[(bs + tt * 64 + tc * 16 + i) * 64 + d];
#pragma unroll
    for (int i = 0; i < 8; ++i)
        b2[i] = Vb[(bs + tt * 64 + tc * 16 + 8 + i) * 64 + d];
    u16* dst = VT + ((size_t)z * 64 + d) * TT + tt * 64 + tc * 16;
    *(u16x8*)dst = a;
    *(u16x8*)(dst + 8) = b2;
}

// ----------------------------------------- MFMA bf16 flash attention / slot
__global__ __launch_bounds__(256)
void attn_mfma_kernel(const u16* __restrict__ Qb, const u16* __restrict__ Kb,
                      const u16* __restrict__ VT, const float* __restrict__ amask,
                      float* __restrict__ AO)
{
    const int qt = blockIdx.x, slot = blockIdx.y, b = blockIdx.z;
    const int z = b * 4 + slot;
    const size_t bs = (size_t)z * TT;
    const int tid = threadIdx.x;
    const int w = tid >> 6, lane = tid & 63;
    const int fr = lane & 15, g = lane >> 4;
    const int q0 = qt * 64 + w * 16;

    __shared__ u16 Ks[64 * 72];    // [key][d], stride 72
    __shared__ u16 VTs[64 * 72];   // [d][key]
    __shared__ u16 Ps[4][16 * 72]; // per-wave P tile [q][key]

    bf16x8 qa[2];
    qa[0] = *(const bf16x8*)(Qb + (bs + q0 + fr) * 64 + g * 8);
    qa[1] = *(const bf16x8*)(Qb + (bs + q0 + fr) * 64 + 32 + g * 8);

    float m_run[4], l_run[4];
    f32x4 oacc[4];
#pragma unroll
    for (int j = 0; j < 4; ++j) { m_run[j] = -1e30f; l_run[j] = 0.f; }
#pragma unroll
    for (int ni = 0; ni < 4; ++ni) oacc[ni] = (f32x4){0.f, 0.f, 0.f, 0.f};

    const float* mrow = amask + ((size_t)b * TT + q0 + g * 4) * TT;

    for (int kc = 0; kc < 11; ++kc) {
        const int kv0 = kc * 64;
        __syncthreads();
#pragma unroll
        for (int it = 0; it < 2; ++it) {
            const int idx = tid + it * 256;
            const int row = idx >> 3, ch = (idx & 7) * 8;
            *(u16x8*)&Ks[row * 72 + ch]  = *(const u16x8*)(Kb + (bs + kv0 + row) * 64 + ch);
            *(u16x8*)&VTs[row * 72 + ch] = *(const u16x8*)(VT + ((size_t)z * 64 + row) * TT + kv0 + ch);
        }
        __syncthreads();
        // S = Q K^T
        f32x4 sacc[4];
#pragma unroll
        for (int ni = 0; ni < 4; ++ni) sacc[ni] = (f32x4){0.f, 0.f, 0.f, 0.f};
#pragma unroll
        for (int c = 0; c < 2; ++c)
#pragma unroll
            for (int ni = 0; ni < 4; ++ni) {
                bf16x8 bf = *(const bf16x8*)&Ks[(ni * 16 + fr) * 72 + c * 32 + g * 8];
                sacc[ni] = __builtin_amdgcn_mfma_f32_16x16x32_bf16(qa[c], bf, sacc[ni], 0, 0, 0);
            }
        // + mask, row max
        float mloc[4] = {-1e30f, -1e30f, -1e30f, -1e30f};
#pragma unroll
        for (int ni = 0; ni < 4; ++ni)
#pragma unroll
            for (int j = 0; j < 4; ++j) {
                float s = sacc[ni][j] + mrow[(size_t)j * TT + kv0 + ni * 16 + fr];
                sacc[ni][j] = s;
                mloc[j] = fmaxf(mloc[j], s);
            }
#pragma unroll
        for (int o = 1; o < 16; o <<= 1)
#pragma unroll
            for (int j = 0; j < 4; ++j) mloc[j] = fmaxf(mloc[j], __shfl_xor(mloc[j], o));
        float fac[4], lsum[4];
#pragma unroll
        for (int j = 0; j < 4; ++j) {
            const float mn = fmaxf(m_run[j], mloc[j]);
            fac[j] = __expf(m_run[j] - mn);
            m_run[j] = mn;
            lsum[j] = 0.f;
        }
#pragma unroll
        for (int ni = 0; ni < 4; ++ni)
#pragma unroll
            for (int j = 0; j < 4; ++j) {
                const float p = __expf(sacc[ni][j] - m_run[j]);
                lsum[j] += p;
                Ps[w][(g * 4 + j) * 72 + ni * 16 + fr] = f2bf(p);
            }
#pragma unroll
        for (int o = 1; o < 16; o <<= 1)
#pragma unroll
            for (int j = 0; j < 4; ++j) lsum[j] += __shfl_xor(lsum[j], o);
#pragma unroll
        for (int j = 0; j < 4; ++j) l_run[j] = l_run[j] * fac[j] + lsum[j];
#pragma unroll
        for (int ni = 0; ni < 4; ++ni)
#pragma unroll
            for (int j = 0; j < 4; ++j) oacc[ni][j] *= fac[j];
        // O += P V
#pragma unroll
        for (int c = 0; c < 2; ++c) {
            bf16x8 paf = *(const bf16x8*)&Ps[w][fr * 72 + c * 32 + g * 8];
#pragma unroll
            for (int ni = 0; ni < 4; ++ni) {
                bf16x8 vf = *(const bf16x8*)&VTs[(ni * 16 + fr) * 72 + c * 32 + g * 8];
                oacc[ni] = __builtin_amdgcn_mfma_f32_16x16x32_bf16(paf, vf, oacc[ni], 0, 0, 0);
            }
        }
    }
#pragma unroll
    for (int j = 0; j < 4; ++j) {
        const float inv = 1.f / l_run[j];
        const int t = q0 + g * 4 + j;
#pragma unroll
        for (int ni = 0; ni < 4; ++ni)
            AO[(bs + t) * 64 + ni * 16 + fr] = oacc[ni][j] * inv;
    }
}

// ------------------------------------------------ sum AO over slots -> bf16
__global__ __launch_bounds__(256)
void aosum_kernel(const float* __restrict__ AO, u16* __restrict__ AOs)
{
    const int i = blockIdx.x * 256 + threadIdx.x;   // over BT*64
    const int bt = i >> 6;
    const int b = bt / TT, t = bt - b * TT;
    const int c = i & 63;
    float s = 0.f;
#pragma unroll
    for (int slot = 0; slot < 4; ++slot)
        s += AO[(((size_t)(b * 4 + slot)) * TT + t) * 64 + c];
    AOs[i] = f2bf(s);
}

// ---------------------------------------------------------------- launcher
extern "C" void kernel_launch(void* const* d_in, const int* in_sizes, int n_in,
                              void* d_out, int out_size, void* d_ws, size_t ws_size,
                              hipStream_t stream)
{
    const float* hidden = (const float*)d_in[0];
    const float* amask  = (const float*)d_in[1];
    const float* rules  = (const float*)d_in[2];
    const float* W_ent  = (const float*)d_in[3];
    const float* b_ent  = (const float*)d_in[4];
    const float* Wq_er  = (const float*)d_in[5];
    const float* Wk_er  = (const float*)d_in[6];
    const float* Wq_es  = (const float*)d_in[7];
    const float* Wk_es  = (const float*)d_in[8];
    const float* Wq     = (const float*)d_in[9];
    const float* bq     = (const float*)d_in[10];
    const float* Wk     = (const float*)d_in[11];
    const float* bk     = (const float*)d_in[12];
    const float* Wv     = (const float*)d_in[13];
    const float* bv     = (const float*)d_in[14];
    const float* Wo     = (const float*)d_in[15];
    const float* bo     = (const float*)d_in[16];
    const float* ln1_g  = (const float*)d_in[17];
    const float* ln1_b  = (const float*)d_in[18];
    const float* ln2_g  = (const float*)d_in[19];
    const float* ln2_b  = (const float*)d_in[20];
    const float* fc1_w1 = (const float*)d_in[21];
    const float* fc1_w2 = (const float*)d_in[22];
    const float* fc2_w1 = (const float*)d_in[23];
    const float* fc2_w2 = (const float*)d_in[24];

    char* ws = (char*)d_ws;
    // -------- workspace map (bytes); total 92,081,408 <= proven 92,278,016
    float* h      = (float*)(ws + 0);              // 23,068,672 [ln1..hg]
    u16*   x1     = (u16*)(ws + 0);                //  5,767,168 [G1red..G2b]
    u16*   x3b    = (u16*)(ws + 5767168);          //  5,767,168 [G3red..G4]
    float* g1p0   = (float*)(ws + 11534336);       // 11,534,336 [G1..G1red]
    float* g3p1   = (float*)(ws + 11534336);       //  5,767,168 [G3..G3red]
    float* g3p2   = (float*)(ws + 17301504);       //  5,767,168 [G3..G3red]
    float* hmid   = (float*)(ws + 23068672);       // 23,068,672 [combine..G4]
    u16*   hgb    = (u16*)(ws + 46137344);         // 11,534,336 [hg..qkv]
    u16*   xln2   = (u16*)(ws + 46137344);         //   (reuse)  [ln2..G1]
    u16*   x2h    = (u16*)(ws + 46137344);         // 23,068,672 [G2x..G3x]
    u16*   Qb     = (u16*)(ws + 57671680);         //  2,883,584 [qkv..attn]
    float* g1p1   = (float*)(ws + 57671680);       // 11,534,336 [G1..G1red]
    u16*   Kb     = (u16*)(ws + 60555264);         //  2,883,584
    u16*   Vb     = (u16*)(ws + 63438848);         //  2,883,584
    u16*   VT     = (u16*)(ws + 66322432);         //  2,883,584
    float* AO     = (float*)(ws + 69206016);       //  5,767,168 [attn..aosum]
    float* part   = (float*)(ws + 69206016);       //    360,448 (dead before AO)
    float* g3p0   = (float*)(ws + 69206016);       //  5,767,168 [G3..G3red]
    float* ent    = (float*)(ws + 74973184);       //      3,072
    float* gate   = (float*)(ws + 74976256);       //        128
    int*   srule  = (int*)(ws + 74976384);         //        128
    u16*   AOs    = (u16*)(ws + 74976512);         //    720,896  -> ends 75,697,408
    u16*   WqkvT  = (u16*)(ws + 75697408);         //  6,291,456 [..qkv]
    u16*   fc1w2T = (u16*)(ws + 75697408);         //  4,194,304 (after qkv)
    u16*   fc2w1T = (u16*)(ws + 79891712);         //  4,194,304 (after qkv)
    u16*   WoT    = (u16*)(ws + 84086016);         //    131,072
    u16*   fc1w1T = (u16*)(ws + 84217088);         //  1,048,576
    u16*   fc2w2T = (u16*)(ws + 85265664);         //  1,048,576  -> ends 86,314,240
    float* g3p3   = (float*)(ws + 86314240);       //  5,767,168  -> ends 92,081,408
    float* out    = (float*)d_out;

    // --- LN1 + selection path (fp32)
    ln_kernel<0><<<BT, 256, 0, stream>>>(hidden, ln1_g, ln1_b, h);
    pool_partial_kernel<<<dim3(11, 8), 256, 0, stream>>>(h, part);
    pool_finish_kernel<<<24, 256, 0, stream>>>(part, W_ent, b_ent, ent);
    select_kernel<<<1, 256, 0, stream>>>(ent, rules, Wq_er, Wk_er, Wq_es, Wk_es, srule, gate);
    hg_kernel<<<BT, 256, 0, stream>>>(h, gate, hgb);

    // --- weight prep (phase 1: needed before/at qkv)
    transpose_bf16_kernel<<<dim3(32, 32), 256, 0, stream>>>(Wq, WqkvT,               1024, 1024);
    transpose_bf16_kernel<<<dim3(32, 32), 256, 0, stream>>>(Wk, WqkvT + 1024*1024,   1024, 1024);
    transpose_bf16_kernel<<<dim3(32, 32), 256, 0, stream>>>(Wv, WqkvT + 2*1024*1024, 1024, 1024);
    transpose_bf16_kernel<<<dim3(32, 2),  256, 0, stream>>>(Wo, WoT, 64, 1024);
    transpose_bf16_kernel<<<dim3(16, 32), 256, 0, stream>>>(fc1_w1, fc1w1T, 1024, 512);
    transpose_bf16_kernel<<<dim3(32, 16), 256, 0, stream>>>(fc2_w2, fc2w2T, 512, 1024);

    // --- QKV (MFMA, bf16 out) + V transpose + attention (MFMA)
    qkv_mfma_kernel<<<dim3(11, 3, 32), 256, 0, stream>>>(hgb, WqkvT, bq, bk, bv, srule,
                                                         Qb, Kb, Vb);
    vtrans_kernel<<<dim3(11, 32), 256, 0, stream>>>(Vb, VT);
    // weight prep phase 2 (aliases WqkvT region, so must come after qkv)
    transpose_bf16_kernel<<<dim3(128, 16), 256, 0, stream>>>(fc1_w2, fc1w2T, 512, 4096);
    transpose_bf16_kernel<<<dim3(16, 128), 256, 0, stream>>>(fc2_w1, fc2w1T, 4096, 512);

    attn_mfma_kernel<<<dim3(11, 4, 8), 256, 0, stream>>>(Qb, Kb, VT, amask, AO);
    aosum_kernel<<<1408, 256, 0, stream>>>(AO, AOs);

    // --- combine: hmid = hidden + AOs @ WoT^T + 4*bo   (K=64)
    gemm2<128, 0, 0><<<dim3(8, 44, 1), 256, 0, stream>>>(
        AOs, 64, WoT, 64, hmid, nullptr, nullptr, nullptr, 1024, BT, 64, hidden, bo, 4.f);
    // --- LN2 -> bf16
    ln_kernel<1><<<BT, 256, 0, stream>>>(hmid, ln2_g, ln2_b, xln2);

    // --- G1: x1 = relu(xln2 @ fc1w1T^T), split-K 2
    gemm2<64, 0, 0><<<dim3(8, 44, 2), 256, 0, stream>>>(
        xln2, 1024, fc1w1T, 1024, g1p0, g1p1, nullptr, nullptr, 512, BT, 512,
        nullptr, nullptr, 0.f);
    red_relu_kernel<2><<<2816, 256, 0, stream>>>(g1p0, g1p1, nullptr, nullptr, x1);

    // --- G2/G3 per M-half (2816 rows)
    for (int half = 0; half < 2; ++half) {
        const u16* x1h = x1 + (size_t)half * 2816 * 512;
        u16* x3bh = x3b + (size_t)half * 2816 * 512;
        gemm2<128, 2, 1><<<dim3(32, 22, 1), 256, 0, stream>>>(
            x1h, 512, fc1w2T, 512, x2h, nullptr, nullptr, nullptr, 4096, 2816, 512,
            nullptr, nullptr, 0.f);
        gemm2<64, 0, 0><<<dim3(8, 22, 4), 256, 0, stream>>>(
            x2h, 4096, fc2w1T, 4096, g3p0, g3p1, g3p2, g3p3, 512, 2816, 1024,
            nullptr, nullptr, 0.f);
        red_relu_kernel<4><<<1408, 256, 0, stream>>>(g3p0, g3p1, g3p2, g3p3, x3bh);
    }

    // --- G4: out = hmid + x3b @ fc2w2T^T
    gemm2<64, 0, 0><<<dim3(16, 44, 1), 256, 0, stream>>>(
        x3b, 512, fc2w2T, 512, out, nullptr, nullptr, nullptr, 1024, BT, 512,
        hmid, nullptr, 0.f);
}

// Round 6
// 322.196 us; speedup vs baseline: 7.7767x; 1.0942x over previous
//
#include <hip/hip_runtime.h>
#include <hip/hip_bf16.h>
#include <math.h>

// Problem constants
#define BB 8
#define TT 704
#define DD 1024
#define RR 16
#define KK 4
#define HDH 64
#define BT (BB*TT)   // 5632

typedef unsigned short u16;
typedef __attribute__((ext_vector_type(4))) float f32x4;
typedef __attribute__((ext_vector_type(8))) short bf16x8;
typedef __attribute__((ext_vector_type(4))) unsigned short u16x4;
typedef __attribute__((ext_vector_type(8))) unsigned short u16x8;

__device__ __forceinline__ u16 f2bf(float f) {
    union { float f; unsigned int u; } cv; cv.f = f;
    unsigned int u = cv.u;
    unsigned int r = (u + 0x7fffu + ((u >> 16) & 1u)) >> 16;
    return (u16)r;
}

__device__ __forceinline__ void gl2lds(const u16* g, u16* l) {
    __builtin_amdgcn_global_load_lds(
        (const __attribute__((address_space(1))) void*)g,
        (__attribute__((address_space(3))) void*)l, 16, 0, 0);
}

template<int N> __device__ __forceinline__ void waitv() {
    if constexpr (N == 0) asm volatile("s_waitcnt vmcnt(0)" ::: "memory");
    else if constexpr (N == 2) asm volatile("s_waitcnt vmcnt(2)" ::: "memory");
    else if constexpr (N == 3) asm volatile("s_waitcnt vmcnt(3)" ::: "memory");
    else asm volatile("s_waitcnt vmcnt(4)" ::: "memory");
}

// ---------------------------------------------------------------- LayerNorm
template<int OBF16>
__global__ __launch_bounds__(256)
void ln_kernel(const float* __restrict__ x, const float* __restrict__ g,
               const float* __restrict__ be, void* __restrict__ yv)
{
    const int row = blockIdx.x;
    const int tid = threadIdx.x;
    __shared__ float sbuf[4];
    const size_t off = (size_t)row * DD + tid * 4;
    float4 v = *(const float4*)(x + off);
    float s = v.x + v.y + v.z + v.w;
#pragma unroll
    for (int o = 32; o; o >>= 1) s += __shfl_xor(s, o);
    if ((tid & 63) == 0) sbuf[tid >> 6] = s;
    __syncthreads();
    float mean = (sbuf[0] + sbuf[1] + sbuf[2] + sbuf[3]) * (1.f / 1024.f);
    float dx = v.x - mean, dy = v.y - mean, dz = v.z - mean, dw = v.w - mean;
    float q = dx*dx + dy*dy + dz*dz + dw*dw;
    __syncthreads();
#pragma unroll
    for (int o = 32; o; o >>= 1) q += __shfl_xor(q, o);
    if ((tid & 63) == 0) sbuf[tid >> 6] = q;
    __syncthreads();
    float var = (sbuf[0] + sbuf[1] + sbuf[2] + sbuf[3]) * (1.f / 1024.f);
    float rstd = rsqrtf(var + 1e-5f);
    float4 gg = *(const float4*)(g + tid * 4);
    float4 bb4 = *(const float4*)(be + tid * 4);
    float o0 = dx * rstd * gg.x + bb4.x;
    float o1 = dy * rstd * gg.y + bb4.y;
    float o2 = dz * rstd * gg.z + bb4.z;
    float o3 = dw * rstd * gg.w + bb4.w;
    if (OBF16) {
        u16x4 o4 = {f2bf(o0), f2bf(o1), f2bf(o2), f2bf(o3)};
        *(u16x4*)((u16*)yv + off) = o4;
    } else {
        float4 o4 = {o0, o1, o2, o3};
        *(float4*)((float*)yv + off) = o4;
    }
}

// -------------------------------------------------- entity pooling (2-phase)
__global__ __launch_bounds__(256)
void pool_partial_kernel(const float* __restrict__ h, float* __restrict__ partial)
{
    const int chunk = blockIdx.x, b = blockIdx.y;   // 11 chunks of 64 tokens
    const int d = threadIdx.x * 4;
    const float* p = h + ((size_t)b * TT + chunk * 64) * DD + d;
    float4 s = {0.f, 0.f, 0.f, 0.f};
    for (int t = 0; t < 64; ++t) {
        float4 v = *(const float4*)(p + (size_t)t * DD);
        s.x += v.x; s.y += v.y; s.z += v.z; s.w += v.w;
    }
    *(float4*)(partial + ((size_t)(b * 11 + chunk)) * 1024 + d) = s;
}

__global__ __launch_bounds__(256)
void pool_finish_kernel(const float* __restrict__ partial, const float* __restrict__ W_ent,
                        const float* __restrict__ b_ent, float* __restrict__ entities)
{
    const int b = blockIdx.x / 3, e = blockIdx.x % 3;
    const int c0 = (e == 0) ? 0 : (e == 1) ? 2 : 3;
    const int c1 = (e == 0) ? 2 : (e == 1) ? 3 : 11;
    const float invlen = (e == 0) ? (1.f/128.f) : (e == 1) ? (1.f/64.f) : (1.f/512.f);
    __shared__ float pooled[1024];
    __shared__ float part[8][32];
    const int tid = threadIdx.x;
    {
        const int d = tid * 4;
        float4 s = {0.f, 0.f, 0.f, 0.f};
        for (int c = c0; c < c1; ++c) {
            float4 v = *(const float4*)(partial + ((size_t)(b * 11 + c)) * 1024 + d);
            s.x += v.x; s.y += v.y; s.z += v.z; s.w += v.w;
        }
        pooled[d+0] = s.x * invlen; pooled[d+1] = s.y * invlen;
        pooled[d+2] = s.z * invlen; pooled[d+3] = s.w * invlen;
    }
    __syncthreads();
    const int g = tid >> 5, j = tid & 31;
    float s = 0.f;
    for (int d = g * 128; d < g * 128 + 128; ++d) s = fmaf(pooled[d], W_ent[d * 32 + j], s);
    part[g][j] = s;
    __syncthreads();
    if (tid < 32) {
        float s2 = b_ent[tid];
        for (int g2 = 0; g2 < 8; ++g2) s2 += part[g2][tid];
        entities[blockIdx.x * 32 + tid] = s2;
    }
}

// ------------------------- rule/entity selection (LDS-staged, wave-parallel)
__global__ __launch_bounds__(256)
void select_kernel(const float* __restrict__ entities, const float* __restrict__ rules,
                   const float* __restrict__ Wq_er, const float* __restrict__ Wk_er,
                   const float* __restrict__ Wq_es, const float* __restrict__ Wk_es,
                   int* __restrict__ slot_rule, float* __restrict__ gate)
{
    __shared__ float rules_s[4096];   // [k][r][64]
    __shared__ float Wq_er_s[2048];   // [64][32]
    __shared__ float Wq_es_s[4096];   // [k][64][16]
    __shared__ float Wk_er_s[1024];   // [32][32]
    __shared__ float Wk_es_s[512];    // [32][16]
    __shared__ float ent_s[768];      // [b][e][32]
    __shared__ float q_er_s[2048];    // [k][r][32]
    __shared__ float k_er_s[768];
    __shared__ float k_es_s[384];
    __shared__ float qes_s[32][16];
    __shared__ int   rsel_s[32];
    __shared__ int   sel_e[32];
    const int tid = threadIdx.x;
    // stage all inputs coalesced
    for (int i = tid; i < 1024; i += 256) *(float4*)&rules_s[i*4] = *(const float4*)&rules[i*4];
    for (int i = tid; i < 512;  i += 256) *(float4*)&Wq_er_s[i*4] = *(const float4*)&Wq_er[i*4];
    for (int i = tid; i < 1024; i += 256) *(float4*)&Wq_es_s[i*4] = *(const float4*)&Wq_es[i*4];
    if (tid < 256) *(float4*)&Wk_er_s[tid*4] = *(const float4*)&Wk_er[tid*4];
    if (tid < 128) *(float4*)&Wk_es_s[tid*4] = *(const float4*)&Wk_es[tid*4];
    if (tid < 192) *(float4*)&ent_s[tid*4] = *(const float4*)&entities[tid*4];
    __syncthreads();
    // projections (all from LDS; fmaf order identical to serial reference)
    for (int idx = tid; idx < 2048; idx += 256) {
        int k = idx >> 9, rem = idx & 511, r = rem >> 5, d = rem & 31;
        float s = 0.f;
        for (int hh = 0; hh < 64; ++hh)
            s = fmaf(rules_s[(k * 16 + r) * 64 + hh], Wq_er_s[hh * 32 + d], s);
        q_er_s[idx] = s;
    }
    for (int idx = tid; idx < 768; idx += 256) {
        int be = idx >> 5, d = idx & 31;
        float s = 0.f;
        for (int ss = 0; ss < 32; ++ss)
            s = fmaf(ent_s[be * 32 + ss], Wk_er_s[ss * 32 + d], s);
        k_er_s[idx] = s;
    }
    for (int idx = tid; idx < 384; idx += 256) {
        int be = idx >> 4, i = idx & 15;
        float s = 0.f;
        for (int ss = 0; ss < 32; ++ss)
            s = fmaf(ent_s[be * 32 + ss], Wk_es_s[ss * 16 + i], s);
        k_es_s[idx] = s;
    }
    __syncthreads();
    // argmax over 48 (r,e) per (b,k) pair: 8 lanes/pair, 6 candidates each,
    // butterfly combine (strict >, tie -> lower idx == first-wins order)
    {
        const int pair = tid >> 3, slice = tid & 7;
        const int b = pair >> 2, k = pair & 3;
        float best = -1e30f; int bj = 48;
        for (int j = slice * 6; j < slice * 6 + 6; ++j) {
            const int r = j / 3, e = j - 3 * r;
            const float* qp = &q_er_s[(k * 16 + r) * 32];
            const float* kp = &k_er_s[(b * 3 + e) * 32];
            float s = 0.f;
            for (int d = 0; d < 32; ++d) s = fmaf(qp[d], kp[d], s);
            s *= 0.17677669529663687f;   // 1/sqrt(32)
            if (s > best) { best = s; bj = j; }
        }
#pragma unroll
        for (int off = 1; off < 8; off <<= 1) {
            float os = __shfl_xor(best, off);
            int oj = __shfl_xor(bj, off);
            if (os > best || (os == best && oj < bj)) { best = os; bj = oj; }
        }
        if (slice == 0) { rsel_s[pair] = bj / 3; slot_rule[pair] = bj / 3; }
    }
    __syncthreads();
    // qes: 2 columns per lane
    {
        const int pair = tid >> 3, slice = tid & 7;
        const int k = pair & 3, rstar = rsel_s[pair];
#pragma unroll
        for (int ii = 0; ii < 2; ++ii) {
            const int i = slice * 2 + ii;
            float s = 0.f;
            for (int hh = 0; hh < 64; ++hh)
                s = fmaf(rules_s[(k * 16 + rstar) * 64 + hh], Wq_es_s[(k * 64 + hh) * 16 + i], s);
            qes_s[pair][i] = s;
        }
    }
    __syncthreads();
    if ((tid & 7) == 0) {
        const int pair = tid >> 3, b = pair >> 2;
        float best2 = -1e30f; int ei = 0;
        for (int e = 0; e < 3; ++e) {
            float s = 0.f;
            for (int i = 0; i < 16; ++i) s = fmaf(qes_s[pair][i], k_es_s[(b * 3 + e) * 16 + i], s);
            s *= 0.25f;   // 1/sqrt(16)
            if (s > best2) { best2 = s; ei = e; }
        }
        sel_e[pair] = ei;
    }
    __syncthreads();
    if (tid < 24) {
        const int b = tid / 3, e = tid % 3;
        float g = 0.f;
        for (int k = 0; k < 4; ++k) g += (sel_e[b * 4 + k] == e) ? 1.f : 0.f;
        gate[b * 3 + e] = g;
    }
}

// ---------------------------------------------- gated hidden -> bf16 staging
__global__ __launch_bounds__(256)
void hg_kernel(const float* __restrict__ h, const float* __restrict__ gate,
               u16* __restrict__ hgb)
{
    const int row = blockIdx.x;   // b*T + t
    const int b = row / TT, t = row - b * TT;
    const float g = gate[b * 3 + ((t < 128) ? 0 : (t < 192) ? 1 : 2)];
    const size_t off = (size_t)row * DD + threadIdx.x * 4;
    float4 v = *(const float4*)(h + off);
    u16x4 o = {f2bf(v.x * g), f2bf(v.y * g), f2bf(v.z * g), f2bf(v.w * g)};
    *(u16x4*)(hgb + off) = o;
}

// ----------------------------- batched fp32 [R][C] -> bf16 [C][R] transposes
__device__ __forceinline__ void transpose_tile(const float* __restrict__ in,
                                               u16* __restrict__ out,
                                               int R, int C, int tr, int tc)
{
    __shared__ float tile[32][33];
    const int tx = threadIdx.x & 31, ty = threadIdx.x >> 5;
    const int c0 = tc * 32, r0 = tr * 32;
#pragma unroll
    for (int j = 0; j < 4; ++j)
        tile[ty + j * 8][tx] = in[(size_t)(r0 + ty + j * 8) * C + c0 + tx];
    __syncthreads();
#pragma unroll
    for (int j = 0; j < 4; ++j)
        out[(size_t)(c0 + ty + j * 8) * R + r0 + tx] = f2bf(tile[tx][ty + j * 8]);
}

__global__ __launch_bounds__(256)
void transpose_batch1_kernel(const float* __restrict__ Wq, const float* __restrict__ Wk,
                             const float* __restrict__ Wv, const float* __restrict__ Wo,
                             const float* __restrict__ fc1w1, const float* __restrict__ fc2w2,
                             u16* __restrict__ WqkvT, u16* __restrict__ WoT,
                             u16* __restrict__ fc1w1T, u16* __restrict__ fc2w2T)
{
    const int bid = blockIdx.x;
    if (bid < 3072) {
        const int m = bid >> 10, t = bid & 1023;
        const float* in = (m == 0) ? Wq : (m == 1) ? Wk : Wv;
        transpose_tile(in, WqkvT + (size_t)m * 1024 * 1024, 1024, 1024, t >> 5, t & 31);
    } else if (bid < 3136) {
        const int t = bid - 3072;
        transpose_tile(Wo, WoT, 64, 1024, t >> 5, t & 31);
    } else if (bid < 3648) {
        const int t = bid - 3136;
        transpose_tile(fc1w1, fc1w1T, 1024, 512, t >> 4, t & 15);
    } else {
        const int t = bid - 3648;
        transpose_tile(fc2w2, fc2w2T, 512, 1024, t >> 5, t & 31);
    }
}

__global__ __launch_bounds__(256)
void transpose_batch2_kernel(const float* __restrict__ fc1w2, const float* __restrict__ fc2w1,
                             u16* __restrict__ fc1w2T, u16* __restrict__ fc2w1T)
{
    const int bid = blockIdx.x;
    if (bid < 2048) transpose_tile(fc1w2, fc1w2T, 512, 4096, bid >> 7, bid & 127);
    else { const int t = bid - 2048; transpose_tile(fc2w1, fc2w1T, 4096, 512, t >> 4, t & 15); }
}

// ------------------------------- pipelined MFMA bf16 GEMM, 128xBN tile, 3-buf
// C[z] = act(A[M, z*Ksub : (z+1)*Ksub] @ Bt[N, same]^T) (+bias*bscale) (+resid)
template<int BN, int ACT, int OBF16>   // ACT: 0 none, 1 relu, 2 gelu(exact)
__global__ __launch_bounds__(256)
void gemm2(const u16* __restrict__ A, int lda, const u16* __restrict__ Bt, int ldb,
           void* C0, void* C1, void* C2, void* C3, int ldc, int M, int Ksub,
           const float* __restrict__ resid, const float* __restrict__ bias, float bscale)
{
    constexpr int MI = (BN == 128) ? 4 : 2;     // 16-row frags per wave
    constexpr int NLOAD = 2 + ((BN == 128) ? 2 : 1);
    __shared__ u16 As[3][128 * 32];
    __shared__ u16 Bs[3][BN * 32];
    const int tid = threadIdx.x;
    const int wid = tid >> 6, lane = tid & 63;
    const int z = blockIdx.z;
    const int row0 = blockIdx.y * 128, col0 = blockIdx.x * BN;
    const size_t koff = (size_t)z * Ksub;
    const int srA = wid * 32 + (lane >> 2);
    const int sc = (lane & 3) * 8;
    const u16* ag = A + (size_t)(row0 + srA) * lda + koff + sc;
    const int srB = (BN == 128) ? (wid * 32 + (lane >> 2)) : (wid * 16 + (lane >> 2));
    const u16* bg = Bt + (size_t)(col0 + srB) * ldb + koff + sc;
    const int nt = Ksub >> 5;

    auto STAGE = [&](int buf, int t) {
        const u16* a = ag + t * 32;
        const u16* b = bg + t * 32;
        gl2lds(a, &As[buf][wid * 1024]);
        gl2lds(a + (size_t)16 * lda, &As[buf][wid * 1024 + 512]);
        if constexpr (BN == 128) {
            gl2lds(b, &Bs[buf][wid * 1024]);
            gl2lds(b + (size_t)16 * ldb, &Bs[buf][wid * 1024 + 512]);
        } else {
            gl2lds(b, &Bs[buf][wid * 512]);
        }
    };

    f32x4 acc[MI][4];
#pragma unroll
    for (int i = 0; i < MI; ++i)
#pragma unroll
        for (int j = 0; j < 4; ++j) acc[i][j] = (f32x4){0.f, 0.f, 0.f, 0.f};

    const int fr = lane & 15, kb8 = (lane >> 4) * 8;
    const int wrbase = (BN == 128) ? (wid >> 1) * 64 : wid * 32;
    const int wcbase = (BN == 128) ? (wid & 1) * 64 : 0;
    const int paoff = (wrbase + fr) * 32 + kb8;
    const int pboff = (wcbase + fr) * 32 + kb8;

    STAGE(0, 0);
    if (nt > 1) STAGE(1, 1);
    for (int t = 0; t < nt; ++t) {
        if (t + 1 < nt) waitv<NLOAD>(); else waitv<0>();
        __builtin_amdgcn_s_barrier();
        asm volatile("" ::: "memory");
        const int buf = t % 3;
#pragma unroll
        for (int mi = 0; mi < MI; ++mi) {
            bf16x8 af = *(const bf16x8*)&As[buf][paoff + mi * 512];
#pragma unroll
            for (int ni = 0; ni < 4; ++ni) {
                bf16x8 bfv = *(const bf16x8*)&Bs[buf][pboff + ni * 512];
                acc[mi][ni] = __builtin_amdgcn_mfma_f32_16x16x32_bf16(af, bfv, acc[mi][ni], 0, 0, 0);
            }
        }
        if (t + 2 < nt) STAGE((t + 2) % 3, t + 2);
    }

    void* Cp = (z == 0) ? C0 : (z == 1) ? C1 : (z == 2) ? C2 : C3;
    const int fq4 = (lane >> 4) * 4;
#pragma unroll
    for (int mi = 0; mi < MI; ++mi) {
#pragma unroll
        for (int j = 0; j < 4; ++j) {
            const int row = row0 + wrbase + mi * 16 + fq4 + j;
#pragma unroll
            for (int ni = 0; ni < 4; ++ni) {
                const int col = col0 + wcbase + ni * 16 + fr;
                float v = acc[mi][ni][j];
                if (bias) v += bscale * bias[col];
                if (ACT == 1) v = fmaxf(v, 0.f);
                else if (ACT == 2) v = 0.5f * v * (1.f + erff(v * 0.70710678118654752f));
                const size_t off = (size_t)row * ldc + col;
                if (OBF16) {
                    ((u16*)Cp)[off] = f2bf(v);
                } else {
                    if (resid) v += resid[off];
                    ((float*)Cp)[off] = v;
                }
            }
        }
    }
}

// ------------------------------------------- split-K reduce: relu + bf16 out
template<int NP>
__global__ __launch_bounds__(256)
void red_relu_kernel(const float* __restrict__ p0, const float* __restrict__ p1,
                     const float* __restrict__ p2, const float* __restrict__ p3,
                     u16* __restrict__ out)
{
    const int i = (blockIdx.x * 256 + threadIdx.x) * 4;
    float4 a = *(const float4*)(p0 + i);
    float4 b = *(const float4*)(p1 + i);
    a.x += b.x; a.y += b.y; a.z += b.z; a.w += b.w;
    if (NP == 4) {
        float4 c = *(const float4*)(p2 + i);
        float4 d = *(const float4*)(p3 + i);
        a.x += c.x + d.x; a.y += c.y + d.y; a.z += c.z + d.z; a.w += c.w + d.w;
    }
    u16x4 o = {f2bf(fmaxf(a.x, 0.f)), f2bf(fmaxf(a.y, 0.f)),
               f2bf(fmaxf(a.z, 0.f)), f2bf(fmaxf(a.w, 0.f))};
    *(u16x4*)(out + i) = o;
}

// ------------------------------- QKV projection via MFMA, 64x64 tiles, 3-buf
__global__ __launch_bounds__(256)
void qkv_mfma_kernel(const u16* __restrict__ hgb, const u16* __restrict__ WqkvT,
                     const float* __restrict__ bq, const float* __restrict__ bk,
                     const float* __restrict__ bv, const int* __restrict__ slot_rule,
                     u16* __restrict__ Qb, u16* __restrict__ Kb, u16* __restrict__ Vb)
{
    const int mt = blockIdx.x, typ = blockIdx.y, z = blockIdx.z;  // z = b*4+slot
    const int b = z >> 2;
    const int r = slot_rule[z];
    const u16* A  = hgb + (size_t)b * TT * DD + (size_t)mt * 64 * DD;
    const u16* Bt = WqkvT + (size_t)typ * DD * DD + (size_t)(r * 64) * DD;
    __shared__ u16 As[3][64 * 32];
    __shared__ u16 Bs[3][64 * 32];
    const int tid = threadIdx.x;
    const int wid = tid >> 6, lane = tid & 63;
    const int wr = wid >> 1, wc = wid & 1;
    const u16* ag = A + (size_t)(tid >> 2) * DD + (tid & 3) * 8;
    const u16* bg = Bt + (size_t)(tid >> 2) * DD + (tid & 3) * 8;
    auto STAGE = [&](int buf, int t) {
        gl2lds(ag + t * 32, &As[buf][wid * 512]);
        gl2lds(bg + t * 32, &Bs[buf][wid * 512]);
    };
    f32x4 acc[2][2];
#pragma unroll
    for (int i = 0; i < 2; ++i)
#pragma unroll
        for (int j = 0; j < 2; ++j) acc[i][j] = (f32x4){0.f, 0.f, 0.f, 0.f};
    const int fr = lane & 15, kb8 = (lane >> 4) * 8;
    const int paoff = (wr * 32 + fr) * 32 + kb8;
    const int pboff = (wc * 32 + fr) * 32 + kb8;
    const int nt = 32;
    STAGE(0, 0);
    STAGE(1, 1);
    for (int t = 0; t < nt; ++t) {
        if (t + 1 < nt) waitv<2>(); else waitv<0>();
        __builtin_amdgcn_s_barrier();
        asm volatile("" ::: "memory");
        const int buf = t % 3;
#pragma unroll
        for (int mi = 0; mi < 2; ++mi) {
            bf16x8 af = *(const bf16x8*)&As[buf][paoff + mi * 512];
#pragma unroll
            for (int ni = 0; ni < 2; ++ni) {
                bf16x8 bfv = *(const bf16x8*)&Bs[buf][pboff + ni * 512];
                acc[mi][ni] = __builtin_amdgcn_mfma_f32_16x16x32_bf16(af, bfv, acc[mi][ni], 0, 0, 0);
            }
        }
        if (t + 2 < nt) STAGE((t + 2) % 3, t + 2);
    }
    const float* bias = (typ == 0) ? bq : (typ == 1) ? bk : bv;
    const float scale = (typ == 0) ? 0.125f : 1.f;
    u16* out = ((typ == 0) ? Qb : (typ == 1) ? Kb : Vb) + (size_t)z * TT * 64;
    const int fq4 = (lane >> 4) * 4;
#pragma unroll
    for (int mi = 0; mi < 2; ++mi)
#pragma unroll
        for (int j = 0; j < 4; ++j) {
            const int row = mt * 64 + wr * 32 + mi * 16 + fq4 + j;
#pragma unroll
            for (int ni = 0; ni < 2; ++ni) {
                const int col = wc * 32 + ni * 16 + fr;
                out[(size_t)row * 64 + col] = f2bf((acc[mi][ni][j] + bias[r * 64 + col]) * scale);
            }
        }
}

// ---------------------------------- V [z][t][64] -> VT [z][64][704]  (bf16)
__global__ __launch_bounds__(256)
void vtrans_kernel(const u16* __restrict__ Vb, u16* __restrict__ VT)
{
    const int tt = blockIdx.x, z = blockIdx.y;   // 11 x 32
    const int d = threadIdx.x & 63, tc = threadIdx.x >> 6;
    const size_t bs = (size_t)z * TT;
    u16x8 a, b2;
#pragma unroll
    for (int i = 0; i < 8; ++i)
        a[i] = Vb[(bs + tt * 64 + tc * 16 + i) * 64 + d];
#pragma unroll
    for (int i = 0; i < 8; ++i)
        b2[i] = Vb[(bs + tt * 64 + tc * 16 + 8 + i) * 64 + d];
    u16* dst = VT + ((size_t)z * 64 + d) * TT + tt * 64 + tc * 16;
    *(u16x8*)dst = a;
    *(u16x8*)(dst + 8) = b2;
}

// ----------------------------------------- MFMA bf16 flash attention / slot
__global__ __launch_bounds__(256)
void attn_mfma_kernel(const u16* __restrict__ Qb, const u16* __restrict__ Kb,
                      const u16* __restrict__ VT, const float* __restrict__ amask,
                      float* __restrict__ AO)
{
    const int qt = blockIdx.x, slot = blockIdx.y, b = blockIdx.z;
    const int z = b * 4 + slot;
    const size_t bs = (size_t)z * TT;
    const int tid = threadIdx.x;
    const int w = tid >> 6, lane = tid & 63;
    const int fr = lane & 15, g = lane >> 4;
    const int q0 = qt * 64 + w * 16;

    __shared__ u16 Ks[64 * 72];    // [key][d], stride 72
    __shared__ u16 VTs[64 * 72];   // [d][key]
    __shared__ u16 Ps[4][16 * 72]; // per-wave P tile [q][key]

    bf16x8 qa[2];
    qa[0] = *(const bf16x8*)(Qb + (bs + q0 + fr) * 64 + g * 8);
    qa[1] = *(const bf16x8*)(Qb + (bs + q0 + fr) * 64 + 32 + g * 8);

    float m_run[4], l_run[4];
    f32x4 oacc[4];
#pragma unroll
    for (int j = 0; j < 4; ++j) { m_run[j] = -1e30f; l_run[j] = 0.f; }
#pragma unroll
    for (int ni = 0; ni < 4; ++ni) oacc[ni] = (f32x4){0.f, 0.f, 0.f, 0.f};

    const float* mrow = amask + ((size_t)b * TT + q0 + g * 4) * TT;

    for (int kc = 0; kc < 11; ++kc) {
        const int kv0 = kc * 64;
        __syncthreads();
#pragma unroll
        for (int it = 0; it < 2; ++it) {
            const int idx = tid + it * 256;
            const int row = idx >> 3, ch = (idx & 7) * 8;
            *(u16x8*)&Ks[row * 72 + ch]  = *(const u16x8*)(Kb + (bs + kv0 + row) * 64 + ch);
            *(u16x8*)&VTs[row * 72 + ch] = *(const u16x8*)(VT + ((size_t)z * 64 + row) * TT + kv0 + ch);
        }
        __syncthreads();
        // S = Q K^T
        f32x4 sacc[4];
#pragma unroll
        for (int ni = 0; ni < 4; ++ni) sacc[ni] = (f32x4){0.f, 0.f, 0.f, 0.f};
#pragma unroll
        for (int c = 0; c < 2; ++c)
#pragma unroll
            for (int ni = 0; ni < 4; ++ni) {
                bf16x8 bf = *(const bf16x8*)&Ks[(ni * 16 + fr) * 72 + c * 32 + g * 8];
                sacc[ni] = __builtin_amdgcn_mfma_f32_16x16x32_bf16(qa[c], bf, sacc[ni], 0, 0, 0);
            }
        // + mask, row max
        float mloc[4] = {-1e30f, -1e30f, -1e30f, -1e30f};
#pragma unroll
        for (int ni = 0; ni < 4; ++ni)
#pragma unroll
            for (int j = 0; j < 4; ++j) {
                float s = sacc[ni][j] + mrow[(size_t)j * TT + kv0 + ni * 16 + fr];
                sacc[ni][j] = s;
                mloc[j] = fmaxf(mloc[j], s);
            }
#pragma unroll
        for (int o = 1; o < 16; o <<= 1)
#pragma unroll
            for (int j = 0; j < 4; ++j) mloc[j] = fmaxf(mloc[j], __shfl_xor(mloc[j], o));
        float fac[4], lsum[4];
#pragma unroll
        for (int j = 0; j < 4; ++j) {
            const float mn = fmaxf(m_run[j], mloc[j]);
            fac[j] = __expf(m_run[j] - mn);
            m_run[j] = mn;
            lsum[j] = 0.f;
        }
#pragma unroll
        for (int ni = 0; ni < 4; ++ni)
#pragma unroll
            for (int j = 0; j < 4; ++j) {
                const float p = __expf(sacc[ni][j] - m_run[j]);
                lsum[j] += p;
                Ps[w][(g * 4 + j) * 72 + ni * 16 + fr] = f2bf(p);
            }
#pragma unroll
        for (int o = 1; o < 16; o <<= 1)
#pragma unroll
            for (int j = 0; j < 4; ++j) lsum[j] += __shfl_xor(lsum[j], o);
#pragma unroll
        for (int j = 0; j < 4; ++j) l_run[j] = l_run[j] * fac[j] + lsum[j];
#pragma unroll
        for (int ni = 0; ni < 4; ++ni)
#pragma unroll
            for (int j = 0; j < 4; ++j) oacc[ni][j] *= fac[j];
        // O += P V
#pragma unroll
        for (int c = 0; c < 2; ++c) {
            bf16x8 paf = *(const bf16x8*)&Ps[w][fr * 72 + c * 32 + g * 8];
#pragma unroll
            for (int ni = 0; ni < 4; ++ni) {
                bf16x8 vf = *(const bf16x8*)&VTs[(ni * 16 + fr) * 72 + c * 32 + g * 8];
                oacc[ni] = __builtin_amdgcn_mfma_f32_16x16x32_bf16(paf, vf, oacc[ni], 0, 0, 0);
            }
        }
    }
#pragma unroll
    for (int j = 0; j < 4; ++j) {
        const float inv = 1.f / l_run[j];
        const int t = q0 + g * 4 + j;
#pragma unroll
        for (int ni = 0; ni < 4; ++ni)
            AO[(bs + t) * 64 + ni * 16 + fr] = oacc[ni][j] * inv;
    }
}

// ------------------------------------------------ sum AO over slots -> bf16
__global__ __launch_bounds__(256)
void aosum_kernel(const float* __restrict__ AO, u16* __restrict__ AOs)
{
    const int i = blockIdx.x * 256 + threadIdx.x;   // over BT*64
    const int bt = i >> 6;
    const int b = bt / TT, t = bt - b * TT;
    const int c = i & 63;
    float s = 0.f;
#pragma unroll
    for (int slot = 0; slot < 4; ++slot)
        s += AO[(((size_t)(b * 4 + slot)) * TT + t) * 64 + c];
    AOs[i] = f2bf(s);
}

// ---------------------------------------------------------------- launcher
extern "C" void kernel_launch(void* const* d_in, const int* in_sizes, int n_in,
                              void* d_out, int out_size, void* d_ws, size_t ws_size,
                              hipStream_t stream)
{
    const float* hidden = (const float*)d_in[0];
    const float* amask  = (const float*)d_in[1];
    const float* rules  = (const float*)d_in[2];
    const float* W_ent  = (const float*)d_in[3];
    const float* b_ent  = (const float*)d_in[4];
    const float* Wq_er  = (const float*)d_in[5];
    const float* Wk_er  = (const float*)d_in[6];
    const float* Wq_es  = (const float*)d_in[7];
    const float* Wk_es  = (const float*)d_in[8];
    const float* Wq     = (const float*)d_in[9];
    const float* bq     = (const float*)d_in[10];
    const float* Wk     = (const float*)d_in[11];
    const float* bk     = (const float*)d_in[12];
    const float* Wv     = (const float*)d_in[13];
    const float* bv     = (const float*)d_in[14];
    const float* Wo     = (const float*)d_in[15];
    const float* bo     = (const float*)d_in[16];
    const float* ln1_g  = (const float*)d_in[17];
    const float* ln1_b  = (const float*)d_in[18];
    const float* ln2_g  = (const float*)d_in[19];
    const float* ln2_b  = (const float*)d_in[20];
    const float* fc1_w1 = (const float*)d_in[21];
    const float* fc1_w2 = (const float*)d_in[22];
    const float* fc2_w1 = (const float*)d_in[23];
    const float* fc2_w2 = (const float*)d_in[24];

    char* ws = (char*)d_ws;
    // -------- workspace map (bytes); total 92,081,408 <= proven 92,278,016
    float* h      = (float*)(ws + 0);              // 23,068,672 [ln1..hg]
    u16*   x1     = (u16*)(ws + 0);                //  5,767,168 [G1red..G2b]
    u16*   x3b    = (u16*)(ws + 5767168);          //  5,767,168 [G3red..G4]
    float* g1p0   = (float*)(ws + 11534336);       // 11,534,336 [G1..G1red]
    float* g3p1   = (float*)(ws + 11534336);       //  5,767,168 [G3..G3red]
    float* g3p2   = (float*)(ws + 17301504);       //  5,767,168 [G3..G3red]
    float* hmid   = (float*)(ws + 23068672);       // 23,068,672 [combine..G4]
    u16*   hgb    = (u16*)(ws + 46137344);         // 11,534,336 [hg..qkv]
    u16*   xln2   = (u16*)(ws + 46137344);         //   (reuse)  [ln2..G1]
    u16*   x2h    = (u16*)(ws + 46137344);         // 23,068,672 [G2x..G3x]
    u16*   Qb     = (u16*)(ws + 57671680);         //  2,883,584 [qkv..attn]
    float* g1p1   = (float*)(ws + 57671680);       // 11,534,336 [G1..G1red]
    u16*   Kb     = (u16*)(ws + 60555264);         //  2,883,584
    u16*   Vb     = (u16*)(ws + 63438848);         //  2,883,584
    u16*   VT     = (u16*)(ws + 66322432);         //  2,883,584
    float* AO     = (float*)(ws + 69206016);       //  5,767,168 [attn..aosum]
    float* part   = (float*)(ws + 69206016);       //    360,448 (dead before AO)
    float* g3p0   = (float*)(ws + 69206016);       //  5,767,168 [G3..G3red]
    float* ent    = (float*)(ws + 74973184);       //      3,072
    float* gate   = (float*)(ws + 74976256);       //        128
    int*   srule  = (int*)(ws + 74976384);         //        128
    u16*   AOs    = (u16*)(ws + 74976512);         //    720,896  -> ends 75,697,408
    u16*   WqkvT  = (u16*)(ws + 75697408);         //  6,291,456 [..qkv]
    u16*   fc1w2T = (u16*)(ws + 75697408);         //  4,194,304 (after qkv)
    u16*   fc2w1T = (u16*)(ws + 79891712);         //  4,194,304 (after qkv)
    u16*   WoT    = (u16*)(ws + 84086016);         //    131,072
    u16*   fc1w1T = (u16*)(ws + 84217088);         //  1,048,576
    u16*   fc2w2T = (u16*)(ws + 85265664);         //  1,048,576  -> ends 86,314,240
    float* g3p3   = (float*)(ws + 86314240);       //  5,767,168  -> ends 92,081,408
    float* out    = (float*)d_out;

    // --- LN1 + selection path (fp32)
    ln_kernel<0><<<BT, 256, 0, stream>>>(hidden, ln1_g, ln1_b, h);
    pool_partial_kernel<<<dim3(11, 8), 256, 0, stream>>>(h, part);
    pool_finish_kernel<<<24, 256, 0, stream>>>(part, W_ent, b_ent, ent);
    select_kernel<<<1, 256, 0, stream>>>(ent, rules, Wq_er, Wk_er, Wq_es, Wk_es, srule, gate);
    hg_kernel<<<BT, 256, 0, stream>>>(h, gate, hgb);

    // --- weight prep (phase 1: batched; needed before/at qkv)
    transpose_batch1_kernel<<<4160, 256, 0, stream>>>(Wq, Wk, Wv, Wo, fc1_w1, fc2_w2,
                                                      WqkvT, WoT, fc1w1T, fc2w2T);

    // --- QKV (MFMA, bf16 out) + V transpose + attention (MFMA)
    qkv_mfma_kernel<<<dim3(11, 3, 32), 256, 0, stream>>>(hgb, WqkvT, bq, bk, bv, srule,
                                                         Qb, Kb, Vb);
    vtrans_kernel<<<dim3(11, 32), 256, 0, stream>>>(Vb, VT);
    // weight prep phase 2 (aliases WqkvT region, so must come after qkv)
    transpose_batch2_kernel<<<4096, 256, 0, stream>>>(fc1_w2, fc2_w1, fc1w2T, fc2w1T);

    attn_mfma_kernel<<<dim3(11, 4, 8), 256, 0, stream>>>(Qb, Kb, VT, amask, AO);
    aosum_kernel<<<1408, 256, 0, stream>>>(AO, AOs);

    // --- combine: hmid = hidden + AOs @ WoT^T + 4*bo   (K=64)
    gemm2<128, 0, 0><<<dim3(8, 44, 1), 256, 0, stream>>>(
        AOs, 64, WoT, 64, hmid, nullptr, nullptr, nullptr, 1024, BT, 64, hidden, bo, 4.f);
    // --- LN2 -> bf16
    ln_kernel<1><<<BT, 256, 0, stream>>>(hmid, ln2_g, ln2_b, xln2);

    // --- G1: x1 = relu(xln2 @ fc1w1T^T), split-K 2
    gemm2<64, 0, 0><<<dim3(8, 44, 2), 256, 0, stream>>>(
        xln2, 1024, fc1w1T, 1024, g1p0, g1p1, nullptr, nullptr, 512, BT, 512,
        nullptr, nullptr, 0.f);
    red_relu_kernel<2><<<2816, 256, 0, stream>>>(g1p0, g1p1, nullptr, nullptr, x1);

    // --- G2/G3 per M-half (2816 rows)
    for (int half = 0; half < 2; ++half) {
        const u16* x1h = x1 + (size_t)half * 2816 * 512;
        u16* x3bh = x3b + (size_t)half * 2816 * 512;
        gemm2<128, 2, 1><<<dim3(32, 22, 1), 256, 0, stream>>>(
            x1h, 512, fc1w2T, 512, x2h, nullptr, nullptr, nullptr, 4096, 2816, 512,
            nullptr, nullptr, 0.f);
        gemm2<64, 0, 0><<<dim3(8, 22, 4), 256, 0, stream>>>(
            x2h, 4096, fc2w1T, 4096, g3p0, g3p1, g3p2, g3p3, 512, 2816, 1024,
            nullptr, nullptr, 0.f);
        red_relu_kernel<4><<<1408, 256, 0, stream>>>(g3p0, g3p1, g3p2, g3p3, x3bh);
    }

    // --- G4: out = hmid + x3b @ fc2w2T^T
    gemm2<64, 0, 0><<<dim3(16, 44, 1), 256, 0, stream>>>(
        x3b, 512, fc2w2T, 512, out, nullptr, nullptr, nullptr, 1024, BT, 512,
        hmid, nullptr, 0.f);
}

// Round 7
// 312.922 us; speedup vs baseline: 8.0072x; 1.0296x over previous
//
#include <hip/hip_runtime.h>
#include <hip/hip_bf16.h>
#include <math.h>

// Problem constants
#define BB 8
#define TT 704
#define DD 1024
#define RR 16
#define KK 4
#define HDH 64
#define BT (BB*TT)   // 5632

typedef unsigned short u16;
typedef __attribute__((ext_vector_type(4))) float f32x4;
typedef __attribute__((ext_vector_type(8))) short bf16x8;
typedef __attribute__((ext_vector_type(4))) unsigned short u16x4;
typedef __attribute__((ext_vector_type(8))) unsigned short u16x8;

__device__ __forceinline__ u16 f2bf(float f) {
    union { float f; unsigned int u; } cv; cv.f = f;
    unsigned int u = cv.u;
    unsigned int r = (u + 0x7fffu + ((u >> 16) & 1u)) >> 16;
    return (u16)r;
}

__device__ __forceinline__ float bf2f(u16 v) {
    union { unsigned int u; float f; } cv; cv.u = ((unsigned int)v) << 16;
    return cv.f;
}

__device__ __forceinline__ void gl2lds(const u16* g, u16* l) {
    __builtin_amdgcn_global_load_lds(
        (const __attribute__((address_space(1))) void*)g,
        (__attribute__((address_space(3))) void*)l, 16, 0, 0);
}

template<int N> __device__ __forceinline__ void waitv() {
    if constexpr (N == 0) asm volatile("s_waitcnt vmcnt(0)" ::: "memory");
    else if constexpr (N == 2) asm volatile("s_waitcnt vmcnt(2)" ::: "memory");
    else if constexpr (N == 3) asm volatile("s_waitcnt vmcnt(3)" ::: "memory");
    else asm volatile("s_waitcnt vmcnt(4)" ::: "memory");
}

// ---------------------------------------------------------------- LayerNorm
template<int OBF16>
__global__ __launch_bounds__(256)
void ln_kernel(const float* __restrict__ x, const float* __restrict__ g,
               const float* __restrict__ be, void* __restrict__ yv)
{
    const int row = blockIdx.x;
    const int tid = threadIdx.x;
    __shared__ float sbuf[4];
    const size_t off = (size_t)row * DD + tid * 4;
    float4 v = *(const float4*)(x + off);
    float s = v.x + v.y + v.z + v.w;
#pragma unroll
    for (int o = 32; o; o >>= 1) s += __shfl_xor(s, o);
    if ((tid & 63) == 0) sbuf[tid >> 6] = s;
    __syncthreads();
    float mean = (sbuf[0] + sbuf[1] + sbuf[2] + sbuf[3]) * (1.f / 1024.f);
    float dx = v.x - mean, dy = v.y - mean, dz = v.z - mean, dw = v.w - mean;
    float q = dx*dx + dy*dy + dz*dz + dw*dw;
    __syncthreads();
#pragma unroll
    for (int o = 32; o; o >>= 1) q += __shfl_xor(q, o);
    if ((tid & 63) == 0) sbuf[tid >> 6] = q;
    __syncthreads();
    float var = (sbuf[0] + sbuf[1] + sbuf[2] + sbuf[3]) * (1.f / 1024.f);
    float rstd = rsqrtf(var + 1e-5f);
    float4 gg = *(const float4*)(g + tid * 4);
    float4 bb4 = *(const float4*)(be + tid * 4);
    float o0 = dx * rstd * gg.x + bb4.x;
    float o1 = dy * rstd * gg.y + bb4.y;
    float o2 = dz * rstd * gg.z + bb4.z;
    float o3 = dw * rstd * gg.w + bb4.w;
    if (OBF16) {
        u16x4 o4 = {f2bf(o0), f2bf(o1), f2bf(o2), f2bf(o3)};
        *(u16x4*)((u16*)yv + off) = o4;
    } else {
        float4 o4 = {o0, o1, o2, o3};
        *(float4*)((float*)yv + off) = o4;
    }
}

// -------------------------------------------------- entity pooling (2-phase)
__global__ __launch_bounds__(256)
void pool_partial_kernel(const float* __restrict__ h, float* __restrict__ partial)
{
    const int chunk = blockIdx.x, b = blockIdx.y;   // 11 chunks of 64 tokens
    const int d = threadIdx.x * 4;
    const float* p = h + ((size_t)b * TT + chunk * 64) * DD + d;
    float4 s = {0.f, 0.f, 0.f, 0.f};
    for (int t = 0; t < 64; ++t) {
        float4 v = *(const float4*)(p + (size_t)t * DD);
        s.x += v.x; s.y += v.y; s.z += v.z; s.w += v.w;
    }
    *(float4*)(partial + ((size_t)(b * 11 + chunk)) * 1024 + d) = s;
}

__global__ __launch_bounds__(256)
void pool_finish_kernel(const float* __restrict__ partial, const float* __restrict__ W_ent,
                        const float* __restrict__ b_ent, float* __restrict__ entities)
{
    const int b = blockIdx.x / 3, e = blockIdx.x % 3;
    const int c0 = (e == 0) ? 0 : (e == 1) ? 2 : 3;
    const int c1 = (e == 0) ? 2 : (e == 1) ? 3 : 11;
    const float invlen = (e == 0) ? (1.f/128.f) : (e == 1) ? (1.f/64.f) : (1.f/512.f);
    __shared__ float pooled[1024];
    __shared__ float part[8][32];
    const int tid = threadIdx.x;
    {
        const int d = tid * 4;
        float4 s = {0.f, 0.f, 0.f, 0.f};
        for (int c = c0; c < c1; ++c) {
            float4 v = *(const float4*)(partial + ((size_t)(b * 11 + c)) * 1024 + d);
            s.x += v.x; s.y += v.y; s.z += v.z; s.w += v.w;
        }
        pooled[d+0] = s.x * invlen; pooled[d+1] = s.y * invlen;
        pooled[d+2] = s.z * invlen; pooled[d+3] = s.w * invlen;
    }
    __syncthreads();
    const int g = tid >> 5, j = tid & 31;
    float s = 0.f;
    for (int d = g * 128; d < g * 128 + 128; ++d) s = fmaf(pooled[d], W_ent[d * 32 + j], s);
    part[g][j] = s;
    __syncthreads();
    if (tid < 32) {
        float s2 = b_ent[tid];
        for (int g2 = 0; g2 < 8; ++g2) s2 += part[g2][tid];
        entities[blockIdx.x * 32 + tid] = s2;
    }
}

// ------------------------- rule/entity selection (LDS-staged, wave-parallel)
__global__ __launch_bounds__(256)
void select_kernel(const float* __restrict__ entities, const float* __restrict__ rules,
                   const float* __restrict__ Wq_er, const float* __restrict__ Wk_er,
                   const float* __restrict__ Wq_es, const float* __restrict__ Wk_es,
                   int* __restrict__ slot_rule, float* __restrict__ gate)
{
    __shared__ float rules_s[4096];   // [k][r][64]
    __shared__ float Wq_er_s[2048];   // [64][32]
    __shared__ float Wq_es_s[4096];   // [k][64][16]
    __shared__ float Wk_er_s[1024];   // [32][32]
    __shared__ float Wk_es_s[512];    // [32][16]
    __shared__ float ent_s[768];      // [b][e][32]
    __shared__ float q_er_s[2048];    // [k][r][32]
    __shared__ float k_er_s[768];
    __shared__ float k_es_s[384];
    __shared__ float qes_s[32][16];
    __shared__ int   rsel_s[32];
    __shared__ int   sel_e[32];
    const int tid = threadIdx.x;
    // stage all inputs coalesced
    for (int i = tid; i < 1024; i += 256) *(float4*)&rules_s[i*4] = *(const float4*)&rules[i*4];
    for (int i = tid; i < 512;  i += 256) *(float4*)&Wq_er_s[i*4] = *(const float4*)&Wq_er[i*4];
    for (int i = tid; i < 1024; i += 256) *(float4*)&Wq_es_s[i*4] = *(const float4*)&Wq_es[i*4];
    if (tid < 256) *(float4*)&Wk_er_s[tid*4] = *(const float4*)&Wk_er[tid*4];
    if (tid < 128) *(float4*)&Wk_es_s[tid*4] = *(const float4*)&Wk_es[tid*4];
    if (tid < 192) *(float4*)&ent_s[tid*4] = *(const float4*)&entities[tid*4];
    __syncthreads();
    // projections (all from LDS; fmaf order identical to serial reference)
    for (int idx = tid; idx < 2048; idx += 256) {
        int k = idx >> 9, rem = idx & 511, r = rem >> 5, d = rem & 31;
        float s = 0.f;
        for (int hh = 0; hh < 64; ++hh)
            s = fmaf(rules_s[(k * 16 + r) * 64 + hh], Wq_er_s[hh * 32 + d], s);
        q_er_s[idx] = s;
    }
    for (int idx = tid; idx < 768; idx += 256) {
        int be = idx >> 5, d = idx & 31;
        float s = 0.f;
        for (int ss = 0; ss < 32; ++ss)
            s = fmaf(ent_s[be * 32 + ss], Wk_er_s[ss * 32 + d], s);
        k_er_s[idx] = s;
    }
    for (int idx = tid; idx < 384; idx += 256) {
        int be = idx >> 4, i = idx & 15;
        float s = 0.f;
        for (int ss = 0; ss < 32; ++ss)
            s = fmaf(ent_s[be * 32 + ss], Wk_es_s[ss * 16 + i], s);
        k_es_s[idx] = s;
    }
    __syncthreads();
    // argmax over 48 (r,e) per (b,k) pair: 8 lanes/pair, 6 candidates each
    {
        const int pair = tid >> 3, slice = tid & 7;
        const int b = pair >> 2, k = pair & 3;
        float best = -1e30f; int bj = 48;
        for (int j = slice * 6; j < slice * 6 + 6; ++j) {
            const int r = j / 3, e = j - 3 * r;
            const float* qp = &q_er_s[(k * 16 + r) * 32];
            const float* kp = &k_er_s[(b * 3 + e) * 32];
            float s = 0.f;
            for (int d = 0; d < 32; ++d) s = fmaf(qp[d], kp[d], s);
            s *= 0.17677669529663687f;   // 1/sqrt(32)
            if (s > best) { best = s; bj = j; }
        }
#pragma unroll
        for (int off = 1; off < 8; off <<= 1) {
            float os = __shfl_xor(best, off);
            int oj = __shfl_xor(bj, off);
            if (os > best || (os == best && oj < bj)) { best = os; bj = oj; }
        }
        if (slice == 0) { rsel_s[pair] = bj / 3; slot_rule[pair] = bj / 3; }
    }
    __syncthreads();
    // qes: 2 columns per lane
    {
        const int pair = tid >> 3, slice = tid & 7;
        const int k = pair & 3, rstar = rsel_s[pair];
#pragma unroll
        for (int ii = 0; ii < 2; ++ii) {
            const int i = slice * 2 + ii;
            float s = 0.f;
            for (int hh = 0; hh < 64; ++hh)
                s = fmaf(rules_s[(k * 16 + rstar) * 64 + hh], Wq_es_s[(k * 64 + hh) * 16 + i], s);
            qes_s[pair][i] = s;
        }
    }
    __syncthreads();
    if ((tid & 7) == 0) {
        const int pair = tid >> 3, b = pair >> 2;
        float best2 = -1e30f; int ei = 0;
        for (int e = 0; e < 3; ++e) {
            float s = 0.f;
            for (int i = 0; i < 16; ++i) s = fmaf(qes_s[pair][i], k_es_s[(b * 3 + e) * 16 + i], s);
            s *= 0.25f;   // 1/sqrt(16)
            if (s > best2) { best2 = s; ei = e; }
        }
        sel_e[pair] = ei;
    }
    __syncthreads();
    if (tid < 24) {
        const int b = tid / 3, e = tid % 3;
        float g = 0.f;
        for (int k = 0; k < 4; ++k) g += (sel_e[b * 4 + k] == e) ? 1.f : 0.f;
        gate[b * 3 + e] = g;
    }
}

// ---------------------------------------------- gated hidden -> bf16 staging
__global__ __launch_bounds__(256)
void hg_kernel(const float* __restrict__ h, const float* __restrict__ gate,
               u16* __restrict__ hgb)
{
    const int row = blockIdx.x;   // b*T + t
    const int b = row / TT, t = row - b * TT;
    const float g = gate[b * 3 + ((t < 128) ? 0 : (t < 192) ? 1 : 2)];
    const size_t off = (size_t)row * DD + threadIdx.x * 4;
    float4 v = *(const float4*)(h + off);
    u16x4 o = {f2bf(v.x * g), f2bf(v.y * g), f2bf(v.z * g), f2bf(v.w * g)};
    *(u16x4*)(hgb + off) = o;
}

// ----------------------------- batched fp32 [R][C] -> bf16 [C][R] transposes
__device__ __forceinline__ void transpose_tile(const float* __restrict__ in,
                                               u16* __restrict__ out,
                                               int R, int C, int tr, int tc)
{
    __shared__ float tile[32][33];
    const int tx = threadIdx.x & 31, ty = threadIdx.x >> 5;
    const int c0 = tc * 32, r0 = tr * 32;
#pragma unroll
    for (int j = 0; j < 4; ++j)
        tile[ty + j * 8][tx] = in[(size_t)(r0 + ty + j * 8) * C + c0 + tx];
    __syncthreads();
#pragma unroll
    for (int j = 0; j < 4; ++j)
        out[(size_t)(c0 + ty + j * 8) * R + r0 + tx] = f2bf(tile[tx][ty + j * 8]);
}

__global__ __launch_bounds__(256)
void transpose_batch1_kernel(const float* __restrict__ Wq, const float* __restrict__ Wk,
                             const float* __restrict__ Wv, const float* __restrict__ Wo,
                             const float* __restrict__ fc1w1, const float* __restrict__ fc2w2,
                             u16* __restrict__ WqkvT, u16* __restrict__ WoT,
                             u16* __restrict__ fc1w1T, u16* __restrict__ fc2w2T)
{
    const int bid = blockIdx.x;
    if (bid < 3072) {
        const int m = bid >> 10, t = bid & 1023;
        const float* in = (m == 0) ? Wq : (m == 1) ? Wk : Wv;
        transpose_tile(in, WqkvT + (size_t)m * 1024 * 1024, 1024, 1024, t >> 5, t & 31);
    } else if (bid < 3136) {
        const int t = bid - 3072;
        transpose_tile(Wo, WoT, 64, 1024, t >> 5, t & 31);
    } else if (bid < 3648) {
        const int t = bid - 3136;
        transpose_tile(fc1w1, fc1w1T, 1024, 512, t >> 4, t & 15);
    } else {
        const int t = bid - 3648;
        transpose_tile(fc2w2, fc2w2T, 512, 1024, t >> 5, t & 31);
    }
}

__global__ __launch_bounds__(256)
void transpose_batch2_kernel(const float* __restrict__ fc1w2, const float* __restrict__ fc2w1,
                             u16* __restrict__ fc1w2T, u16* __restrict__ fc2w1T)
{
    const int bid = blockIdx.x;
    if (bid < 2048) transpose_tile(fc1w2, fc1w2T, 512, 4096, bid >> 7, bid & 127);
    else { const int t = bid - 2048; transpose_tile(fc2w1, fc2w1T, 4096, 512, t >> 4, t & 15); }
}

// ------------------------------- pipelined MFMA bf16 GEMM, 128xBN tile, 3-buf
// C[z] = act(A[M, z*Ksub : (z+1)*Ksub] @ Bt[N, same]^T) (+bias*bscale) (+resid)
template<int BN, int ACT, int OBF16>   // ACT: 0 none, 1 relu, 2 gelu(exact)
__global__ __launch_bounds__(256)
void gemm2(const u16* __restrict__ A, int lda, const u16* __restrict__ Bt, int ldb,
           void* C0, void* C1, void* C2, void* C3, int ldc, int M, int Ksub,
           const float* __restrict__ resid, const float* __restrict__ bias, float bscale)
{
    constexpr int MI = (BN == 128) ? 4 : 2;     // 16-row frags per wave
    constexpr int NLOAD = 2 + ((BN == 128) ? 2 : 1);
    __shared__ u16 As[3][128 * 32];
    __shared__ u16 Bs[3][BN * 32];
    const int tid = threadIdx.x;
    const int wid = tid >> 6, lane = tid & 63;
    const int z = blockIdx.z;
    const int row0 = blockIdx.y * 128, col0 = blockIdx.x * BN;
    const size_t koff = (size_t)z * Ksub;
    const int srA = wid * 32 + (lane >> 2);
    const int sc = (lane & 3) * 8;
    const u16* ag = A + (size_t)(row0 + srA) * lda + koff + sc;
    const int srB = (BN == 128) ? (wid * 32 + (lane >> 2)) : (wid * 16 + (lane >> 2));
    const u16* bg = Bt + (size_t)(col0 + srB) * ldb + koff + sc;
    const int nt = Ksub >> 5;

    auto STAGE = [&](int buf, int t) {
        const u16* a = ag + t * 32;
        const u16* b = bg + t * 32;
        gl2lds(a, &As[buf][wid * 1024]);
        gl2lds(a + (size_t)16 * lda, &As[buf][wid * 1024 + 512]);
        if constexpr (BN == 128) {
            gl2lds(b, &Bs[buf][wid * 1024]);
            gl2lds(b + (size_t)16 * ldb, &Bs[buf][wid * 1024 + 512]);
        } else {
            gl2lds(b, &Bs[buf][wid * 512]);
        }
    };

    f32x4 acc[MI][4];
#pragma unroll
    for (int i = 0; i < MI; ++i)
#pragma unroll
        for (int j = 0; j < 4; ++j) acc[i][j] = (f32x4){0.f, 0.f, 0.f, 0.f};

    const int fr = lane & 15, kb8 = (lane >> 4) * 8;
    const int wrbase = (BN == 128) ? (wid >> 1) * 64 : wid * 32;
    const int wcbase = (BN == 128) ? (wid & 1) * 64 : 0;
    const int paoff = (wrbase + fr) * 32 + kb8;
    const int pboff = (wcbase + fr) * 32 + kb8;

    STAGE(0, 0);
    if (nt > 1) STAGE(1, 1);
    for (int t = 0; t < nt; ++t) {
        if (t + 1 < nt) waitv<NLOAD>(); else waitv<0>();
        __builtin_amdgcn_s_barrier();
        asm volatile("" ::: "memory");
        const int buf = t % 3;
#pragma unroll
        for (int mi = 0; mi < MI; ++mi) {
            bf16x8 af = *(const bf16x8*)&As[buf][paoff + mi * 512];
#pragma unroll
            for (int ni = 0; ni < 4; ++ni) {
                bf16x8 bfv = *(const bf16x8*)&Bs[buf][pboff + ni * 512];
                acc[mi][ni] = __builtin_amdgcn_mfma_f32_16x16x32_bf16(af, bfv, acc[mi][ni], 0, 0, 0);
            }
        }
        if (t + 2 < nt) STAGE((t + 2) % 3, t + 2);
    }

    void* Cp = (z == 0) ? C0 : (z == 1) ? C1 : (z == 2) ? C2 : C3;
    const int fq4 = (lane >> 4) * 4;
#pragma unroll
    for (int mi = 0; mi < MI; ++mi) {
#pragma unroll
        for (int j = 0; j < 4; ++j) {
            const int row = row0 + wrbase + mi * 16 + fq4 + j;
#pragma unroll
            for (int ni = 0; ni < 4; ++ni) {
                const int col = col0 + wcbase + ni * 16 + fr;
                float v = acc[mi][ni][j];
                if (bias) v += bscale * bias[col];
                if (ACT == 1) v = fmaxf(v, 0.f);
                else if (ACT == 2) v = 0.5f * v * (1.f + erff(v * 0.70710678118654752f));
                const size_t off = (size_t)row * ldc + col;
                if (OBF16) {
                    ((u16*)Cp)[off] = f2bf(v);
                } else {
                    if (resid) v += resid[off];
                    ((float*)Cp)[off] = v;
                }
            }
        }
    }
}

// ------------------------------------------- split-K reduce: relu + bf16 out
template<int NP>
__global__ __launch_bounds__(256)
void red_relu_kernel(const float* __restrict__ p0, const float* __restrict__ p1,
                     const float* __restrict__ p2, const float* __restrict__ p3,
                     u16* __restrict__ out)
{
    const int i = (blockIdx.x * 256 + threadIdx.x) * 4;
    float4 a = *(const float4*)(p0 + i);
    float4 b = *(const float4*)(p1 + i);
    a.x += b.x; a.y += b.y; a.z += b.z; a.w += b.w;
    if (NP == 4) {
        float4 c = *(const float4*)(p2 + i);
        float4 d = *(const float4*)(p3 + i);
        a.x += c.x + d.x; a.y += c.y + d.y; a.z += c.z + d.z; a.w += c.w + d.w;
    }
    u16x4 o = {f2bf(fmaxf(a.x, 0.f)), f2bf(fmaxf(a.y, 0.f)),
               f2bf(fmaxf(a.z, 0.f)), f2bf(fmaxf(a.w, 0.f))};
    *(u16x4*)(out + i) = o;
}

// ---------------- fused QKV projection: one block computes Q,K and V^T tiles
// grid (11, 32): A tile [64 x 1024] staged once; 12 MFMAs / K-step / wave.
__global__ __launch_bounds__(256)
void qkv3_mfma_kernel(const u16* __restrict__ hgb, const u16* __restrict__ WqkvT,
                      const float* __restrict__ bq, const float* __restrict__ bk,
                      const float* __restrict__ bv, const int* __restrict__ slot_rule,
                      u16* __restrict__ Qb, u16* __restrict__ Kb, u16* __restrict__ VT)
{
    const int mt = blockIdx.x, z = blockIdx.y;   // z = b*4+slot
    const int b = z >> 2;
    const int r = slot_rule[z];
    __shared__ u16 As[3][64 * 32];
    __shared__ u16 Bs[3][3][64 * 32];
    const int tid = threadIdx.x;
    const int w = tid >> 6, lane = tid & 63;
    const u16* ag = hgb + ((size_t)b * TT + mt * 64 + (tid >> 2)) * DD + (tid & 3) * 8;
    const u16* bg0 = WqkvT + (size_t)0 * DD * DD + (size_t)(r * 64 + (tid >> 2)) * DD + (tid & 3) * 8;
    const u16* bg1 = WqkvT + (size_t)1 * DD * DD + (size_t)(r * 64 + (tid >> 2)) * DD + (tid & 3) * 8;
    const u16* bg2 = WqkvT + (size_t)2 * DD * DD + (size_t)(r * 64 + (tid >> 2)) * DD + (tid & 3) * 8;
    auto STAGE = [&](int buf, int t) {
        gl2lds(ag  + t * 32, &As[buf][w * 512]);
        gl2lds(bg0 + t * 32, &Bs[buf][0][w * 512]);
        gl2lds(bg1 + t * 32, &Bs[buf][1][w * 512]);
        gl2lds(bg2 + t * 32, &Bs[buf][2][w * 512]);
    };
    f32x4 accq[4], acck[4], accv[4];
#pragma unroll
    for (int i = 0; i < 4; ++i) {
        accq[i] = (f32x4){0.f, 0.f, 0.f, 0.f};
        acck[i] = (f32x4){0.f, 0.f, 0.f, 0.f};
        accv[i] = (f32x4){0.f, 0.f, 0.f, 0.f};
    }
    const int fr = lane & 15, kb8 = (lane >> 4) * 8;
    const int paoff = (w * 16 + fr) * 32 + kb8;
    const int nt = 32;
    STAGE(0, 0);
    STAGE(1, 1);
    for (int t = 0; t < nt; ++t) {
        if (t + 1 < nt) waitv<4>(); else waitv<0>();
        __builtin_amdgcn_s_barrier();
        asm volatile("" ::: "memory");
        const int buf = t % 3;
        bf16x8 af = *(const bf16x8*)&As[buf][paoff];
#pragma unroll
        for (int ni = 0; ni < 4; ++ni) {
            const int boff = (ni * 16 + fr) * 32 + kb8;
            bf16x8 bq8 = *(const bf16x8*)&Bs[buf][0][boff];
            bf16x8 bk8 = *(const bf16x8*)&Bs[buf][1][boff];
            bf16x8 bv8 = *(const bf16x8*)&Bs[buf][2][boff];
            accq[ni] = __builtin_amdgcn_mfma_f32_16x16x32_bf16(af, bq8, accq[ni], 0, 0, 0);
            acck[ni] = __builtin_amdgcn_mfma_f32_16x16x32_bf16(af, bk8, acck[ni], 0, 0, 0);
            // swapped operands: D rows walk W-cols -> writes V^T directly
            accv[ni] = __builtin_amdgcn_mfma_f32_16x16x32_bf16(bv8, af, accv[ni], 0, 0, 0);
        }
        if (t + 2 < nt) STAGE((t + 2) % 3, t + 2);
    }
    const size_t bs = (size_t)z * TT;
    const int fq4 = (lane >> 4) * 4;
#pragma unroll
    for (int ni = 0; ni < 4; ++ni)
#pragma unroll
        for (int j = 0; j < 4; ++j) {
            // Q, K: row = token, col = head dim
            const int row = mt * 64 + w * 16 + fq4 + j;
            const int col = ni * 16 + fr;
            Qb[(bs + row) * 64 + col] = f2bf((accq[ni][j] + bq[r * 64 + col]) * 0.125f);
            Kb[(bs + row) * 64 + col] = f2bf(acck[ni][j] + bk[r * 64 + col]);
            // V^T: row walks W-cols (d), col walks tokens
            const int d = ni * 16 + fq4 + j;
            const int tt2 = mt * 64 + w * 16 + fr;
            VT[((size_t)z * 64 + d) * TT + tt2] = f2bf(accv[ni][j] + bv[r * 64 + d]);
        }
}

// ----------------------------------------- MFMA bf16 flash attention / slot
__global__ __launch_bounds__(256)
void attn_mfma_kernel(const u16* __restrict__ Qb, const u16* __restrict__ Kb,
                      const u16* __restrict__ VT, const float* __restrict__ amask,
                      u16* __restrict__ AO)
{
    const int qt = blockIdx.x, slot = blockIdx.y, b = blockIdx.z;
    const int z = b * 4 + slot;
    const size_t bs = (size_t)z * TT;
    const int tid = threadIdx.x;
    const int w = tid >> 6, lane = tid & 63;
    const int fr = lane & 15, g = lane >> 4;
    const int q0 = qt * 64 + w * 16;

    __shared__ u16 Ks[64 * 72];    // [key][d], stride 72
    __shared__ u16 VTs[64 * 72];   // [d][key]
    __shared__ u16 Ps[4][16 * 72]; // per-wave P tile [q][key]

    bf16x8 qa[2];
    qa[0] = *(const bf16x8*)(Qb + (bs + q0 + fr) * 64 + g * 8);
    qa[1] = *(const bf16x8*)(Qb + (bs + q0 + fr) * 64 + 32 + g * 8);

    float m_run[4], l_run[4];
    f32x4 oacc[4];
#pragma unroll
    for (int j = 0; j < 4; ++j) { m_run[j] = -1e30f; l_run[j] = 0.f; }
#pragma unroll
    for (int ni = 0; ni < 4; ++ni) oacc[ni] = (f32x4){0.f, 0.f, 0.f, 0.f};

    const float* mrow = amask + ((size_t)b * TT + q0 + g * 4) * TT;

    for (int kc = 0; kc < 11; ++kc) {
        const int kv0 = kc * 64;
        __syncthreads();
#pragma unroll
        for (int it = 0; it < 2; ++it) {
            const int idx = tid + it * 256;
            const int row = idx >> 3, ch = (idx & 7) * 8;
            *(u16x8*)&Ks[row * 72 + ch]  = *(const u16x8*)(Kb + (bs + kv0 + row) * 64 + ch);
            *(u16x8*)&VTs[row * 72 + ch] = *(const u16x8*)(VT + ((size_t)z * 64 + row) * TT + kv0 + ch);
        }
        __syncthreads();
        // S = Q K^T
        f32x4 sacc[4];
#pragma unroll
        for (int ni = 0; ni < 4; ++ni) sacc[ni] = (f32x4){0.f, 0.f, 0.f, 0.f};
#pragma unroll
        for (int c = 0; c < 2; ++c)
#pragma unroll
            for (int ni = 0; ni < 4; ++ni) {
                bf16x8 bf = *(const bf16x8*)&Ks[(ni * 16 + fr) * 72 + c * 32 + g * 8];
                sacc[ni] = __builtin_amdgcn_mfma_f32_16x16x32_bf16(qa[c], bf, sacc[ni], 0, 0, 0);
            }
        // + mask, row max
        float mloc[4] = {-1e30f, -1e30f, -1e30f, -1e30f};
#pragma unroll
        for (int ni = 0; ni < 4; ++ni)
#pragma unroll
            for (int j = 0; j < 4; ++j) {
                float s = sacc[ni][j] + mrow[(size_t)j * TT + kv0 + ni * 16 + fr];
                sacc[ni][j] = s;
                mloc[j] = fmaxf(mloc[j], s);
            }
#pragma unroll
        for (int o = 1; o < 16; o <<= 1)
#pragma unroll
            for (int j = 0; j < 4; ++j) mloc[j] = fmaxf(mloc[j], __shfl_xor(mloc[j], o));
        float fac[4], lsum[4];
#pragma unroll
        for (int j = 0; j < 4; ++j) {
            const float mn = fmaxf(m_run[j], mloc[j]);
            fac[j] = __expf(m_run[j] - mn);
            m_run[j] = mn;
            lsum[j] = 0.f;
        }
#pragma unroll
        for (int ni = 0; ni < 4; ++ni)
#pragma unroll
            for (int j = 0; j < 4; ++j) {
                const float p = __expf(sacc[ni][j] - m_run[j]);
                lsum[j] += p;
                Ps[w][(g * 4 + j) * 72 + ni * 16 + fr] = f2bf(p);
            }
#pragma unroll
        for (int o = 1; o < 16; o <<= 1)
#pragma unroll
            for (int j = 0; j < 4; ++j) lsum[j] += __shfl_xor(lsum[j], o);
#pragma unroll
        for (int j = 0; j < 4; ++j) l_run[j] = l_run[j] * fac[j] + lsum[j];
#pragma unroll
        for (int ni = 0; ni < 4; ++ni)
#pragma unroll
            for (int j = 0; j < 4; ++j) oacc[ni][j] *= fac[j];
        // O += P V
#pragma unroll
        for (int c = 0; c < 2; ++c) {
            bf16x8 paf = *(const bf16x8*)&Ps[w][fr * 72 + c * 32 + g * 8];
#pragma unroll
            for (int ni = 0; ni < 4; ++ni) {
                bf16x8 vf = *(const bf16x8*)&VTs[(ni * 16 + fr) * 72 + c * 32 + g * 8];
                oacc[ni] = __builtin_amdgcn_mfma_f32_16x16x32_bf16(paf, vf, oacc[ni], 0, 0, 0);
            }
        }
    }
#pragma unroll
    for (int j = 0; j < 4; ++j) {
        const float inv = 1.f / l_run[j];
        const int t = q0 + g * 4 + j;
#pragma unroll
        for (int ni = 0; ni < 4; ++ni)
            AO[(bs + t) * 64 + ni * 16 + fr] = f2bf(oacc[ni][j] * inv);
    }
}

// ------------------------------------------------ sum AO over slots -> bf16
__global__ __launch_bounds__(256)
void aosum_kernel(const u16* __restrict__ AO, u16* __restrict__ AOs)
{
    const int i = blockIdx.x * 256 + threadIdx.x;   // over BT*64
    const int bt = i >> 6;
    const int b = bt / TT, t = bt - b * TT;
    const int c = i & 63;
    float s = 0.f;
#pragma unroll
    for (int slot = 0; slot < 4; ++slot)
        s += bf2f(AO[(((size_t)(b * 4 + slot)) * TT + t) * 64 + c]);
    AOs[i] = f2bf(s);
}

// ---------------------------------------------------------------- launcher
extern "C" void kernel_launch(void* const* d_in, const int* in_sizes, int n_in,
                              void* d_out, int out_size, void* d_ws, size_t ws_size,
                              hipStream_t stream)
{
    const float* hidden = (const float*)d_in[0];
    const float* amask  = (const float*)d_in[1];
    const float* rules  = (const float*)d_in[2];
    const float* W_ent  = (const float*)d_in[3];
    const float* b_ent  = (const float*)d_in[4];
    const float* Wq_er  = (const float*)d_in[5];
    const float* Wk_er  = (const float*)d_in[6];
    const float* Wq_es  = (const float*)d_in[7];
    const float* Wk_es  = (const float*)d_in[8];
    const float* Wq     = (const float*)d_in[9];
    const float* bq     = (const float*)d_in[10];
    const float* Wk     = (const float*)d_in[11];
    const float* bk     = (const float*)d_in[12];
    const float* Wv     = (const float*)d_in[13];
    const float* bv     = (const float*)d_in[14];
    const float* Wo     = (const float*)d_in[15];
    const float* bo     = (const float*)d_in[16];
    const float* ln1_g  = (const float*)d_in[17];
    const float* ln1_b  = (const float*)d_in[18];
    const float* ln2_g  = (const float*)d_in[19];
    const float* ln2_b  = (const float*)d_in[20];
    const float* fc1_w1 = (const float*)d_in[21];
    const float* fc1_w2 = (const float*)d_in[22];
    const float* fc2_w1 = (const float*)d_in[23];
    const float* fc2_w2 = (const float*)d_in[24];

    char* ws = (char*)d_ws;
    // -------- workspace map (bytes); total 92,081,408 <= proven 92,278,016
    float* h      = (float*)(ws + 0);              // 23,068,672 [ln1..hg]
    u16*   x1     = (u16*)(ws + 0);                //  5,767,168 [G1..G2b]
    u16*   x3b    = (u16*)(ws + 5767168);          //  5,767,168 [G3red..G4]
    float* g3p1   = (float*)(ws + 11534336);       //  5,767,168 [G3..G3red]
    float* g3p2   = (float*)(ws + 17301504);       //  5,767,168 [G3..G3red]
    float* hmid   = (float*)(ws + 23068672);       // 23,068,672 [combine..G4]
    u16*   hgb    = (u16*)(ws + 46137344);         // 11,534,336 [hg..qkv]
    u16*   xln2   = (u16*)(ws + 46137344);         //   (reuse)  [ln2..G1]
    u16*   x2h    = (u16*)(ws + 46137344);         // 23,068,672 [G2x..G3x]
    u16*   Qb     = (u16*)(ws + 57671680);         //  2,883,584 [qkv..attn]
    u16*   Kb     = (u16*)(ws + 60555264);         //  2,883,584
    u16*   VT     = (u16*)(ws + 66322432);         //  2,883,584
    u16*   AO     = (u16*)(ws + 69206016);         //  2,883,584 [attn..aosum]
    float* part   = (float*)(ws + 69206016);       //    360,448 (dead before AO)
    float* g3p0   = (float*)(ws + 69206016);       //  5,767,168 [G3..G3red]
    float* ent    = (float*)(ws + 74973184);       //      3,072
    float* gate   = (float*)(ws + 74976256);       //        128
    int*   srule  = (int*)(ws + 74976384);         //        128
    u16*   AOs    = (u16*)(ws + 74976512);         //    720,896  -> ends 75,697,408
    u16*   WqkvT  = (u16*)(ws + 75697408);         //  6,291,456 [..qkv]
    u16*   fc1w2T = (u16*)(ws + 75697408);         //  4,194,304 (after qkv)
    u16*   fc2w1T = (u16*)(ws + 79891712);         //  4,194,304 (after qkv)
    u16*   WoT    = (u16*)(ws + 84086016);         //    131,072
    u16*   fc1w1T = (u16*)(ws + 84217088);         //  1,048,576
    u16*   fc2w2T = (u16*)(ws + 85265664);         //  1,048,576  -> ends 86,314,240
    float* g3p3   = (float*)(ws + 86314240);       //  5,767,168  -> ends 92,081,408
    float* out    = (float*)d_out;

    // --- LN1 + selection path (fp32)
    ln_kernel<0><<<BT, 256, 0, stream>>>(hidden, ln1_g, ln1_b, h);
    pool_partial_kernel<<<dim3(11, 8), 256, 0, stream>>>(h, part);
    pool_finish_kernel<<<24, 256, 0, stream>>>(part, W_ent, b_ent, ent);
    select_kernel<<<1, 256, 0, stream>>>(ent, rules, Wq_er, Wk_er, Wq_es, Wk_es, srule, gate);
    hg_kernel<<<BT, 256, 0, stream>>>(h, gate, hgb);

    // --- weight prep (phase 1: batched; needed before/at qkv)
    transpose_batch1_kernel<<<4160, 256, 0, stream>>>(Wq, Wk, Wv, Wo, fc1_w1, fc2_w2,
                                                      WqkvT, WoT, fc1w1T, fc2w2T);

    // --- fused QKV (MFMA; writes Q, K, V^T) + attention (MFMA)
    qkv3_mfma_kernel<<<dim3(11, 32), 256, 0, stream>>>(hgb, WqkvT, bq, bk, bv, srule,
                                                       Qb, Kb, VT);
    // weight prep phase 2 (aliases WqkvT region, so must come after qkv)
    transpose_batch2_kernel<<<4096, 256, 0, stream>>>(fc1_w2, fc2_w1, fc1w2T, fc2w1T);

    attn_mfma_kernel<<<dim3(11, 4, 8), 256, 0, stream>>>(Qb, Kb, VT, amask, AO);
    aosum_kernel<<<1408, 256, 0, stream>>>(AO, AOs);

    // --- combine: hmid = hidden + AOs @ WoT^T + 4*bo   (K=64)
    gemm2<128, 0, 0><<<dim3(8, 44, 1), 256, 0, stream>>>(
        AOs, 64, WoT, 64, hmid, nullptr, nullptr, nullptr, 1024, BT, 64, hidden, bo, 4.f);
    // --- LN2 -> bf16
    ln_kernel<1><<<BT, 256, 0, stream>>>(hmid, ln2_g, ln2_b, xln2);

    // --- G1: x1 = relu(xln2 @ fc1w1T^T)  (unsplit, fused relu->bf16)
    gemm2<64, 1, 1><<<dim3(8, 44, 1), 256, 0, stream>>>(
        xln2, 1024, fc1w1T, 1024, x1, nullptr, nullptr, nullptr, 512, BT, 1024,
        nullptr, nullptr, 0.f);

    // --- G2/G3 per M-half (2816 rows)
    for (int half = 0; half < 2; ++half) {
        const u16* x1h = x1 + (size_t)half * 2816 * 512;
        u16* x3bh = x3b + (size_t)half * 2816 * 512;
        gemm2<128, 2, 1><<<dim3(32, 22, 1), 256, 0, stream>>>(
            x1h, 512, fc1w2T, 512, x2h, nullptr, nullptr, nullptr, 4096, 2816, 512,
            nullptr, nullptr, 0.f);
        gemm2<64, 0, 0><<<dim3(8, 22, 4), 256, 0, stream>>>(
            x2h, 4096, fc2w1T, 4096, g3p0, g3p1, g3p2, g3p3, 512, 2816, 1024,
            nullptr, nullptr, 0.f);
        red_relu_kernel<4><<<1408, 256, 0, stream>>>(g3p0, g3p1, g3p2, g3p3, x3bh);
    }

    // --- G4: out = hmid + x3b @ fc2w2T^T
    gemm2<64, 0, 0><<<dim3(16, 44, 1), 256, 0, stream>>>(
        x3b, 512, fc2w2T, 512, out, nullptr, nullptr, nullptr, 1024, BT, 512,
        hmid, nullptr, 0.f);
}

// Round 8
// 290.165 us; speedup vs baseline: 8.6352x; 1.0784x over previous
//
#include <hip/hip_runtime.h>
#include <hip/hip_bf16.h>
#include <math.h>

// Problem constants
#define BB 8
#define TT 704
#define DD 1024
#define RR 16
#define KK 4
#define HDH 64
#define BT (BB*TT)   // 5632

typedef unsigned short u16;
typedef __attribute__((ext_vector_type(4))) float f32x4;
typedef __attribute__((ext_vector_type(8))) short bf16x8;
typedef __attribute__((ext_vector_type(4))) unsigned short u16x4;
typedef __attribute__((ext_vector_type(8))) unsigned short u16x8;

__device__ __forceinline__ u16 f2bf(float f) {
    union { float f; unsigned int u; } cv; cv.f = f;
    unsigned int u = cv.u;
    unsigned int r = (u + 0x7fffu + ((u >> 16) & 1u)) >> 16;
    return (u16)r;
}

__device__ __forceinline__ float bf2f(u16 v) {
    union { unsigned int u; float f; } cv; cv.u = ((unsigned int)v) << 16;
    return cv.f;
}

__device__ __forceinline__ void gl2lds(const u16* g, u16* l) {
    __builtin_amdgcn_global_load_lds(
        (const __attribute__((address_space(1))) void*)g,
        (__attribute__((address_space(3))) void*)l, 16, 0, 0);
}

template<int N> __device__ __forceinline__ void waitv() {
    if constexpr (N == 0) asm volatile("s_waitcnt vmcnt(0)" ::: "memory");
    else if constexpr (N == 2) asm volatile("s_waitcnt vmcnt(2)" ::: "memory");
    else if constexpr (N == 3) asm volatile("s_waitcnt vmcnt(3)" ::: "memory");
    else asm volatile("s_waitcnt vmcnt(4)" ::: "memory");
}

// ---------------------------------------------------------------- LayerNorm
template<int OBF16, int IBF16>
__global__ __launch_bounds__(256)
void ln_kernel(const void* __restrict__ xv, const float* __restrict__ g,
               const float* __restrict__ be, void* __restrict__ yv)
{
    const int row = blockIdx.x;
    const int tid = threadIdx.x;
    __shared__ float sbuf[4];
    const size_t off = (size_t)row * DD + tid * 4;
    float4 v;
    if (IBF16) {
        u16x4 xb = *(const u16x4*)((const u16*)xv + off);
        v.x = bf2f(xb[0]); v.y = bf2f(xb[1]); v.z = bf2f(xb[2]); v.w = bf2f(xb[3]);
    } else {
        v = *(const float4*)((const float*)xv + off);
    }
    float s = v.x + v.y + v.z + v.w;
#pragma unroll
    for (int o = 32; o; o >>= 1) s += __shfl_xor(s, o);
    if ((tid & 63) == 0) sbuf[tid >> 6] = s;
    __syncthreads();
    float mean = (sbuf[0] + sbuf[1] + sbuf[2] + sbuf[3]) * (1.f / 1024.f);
    float dx = v.x - mean, dy = v.y - mean, dz = v.z - mean, dw = v.w - mean;
    float q = dx*dx + dy*dy + dz*dz + dw*dw;
    __syncthreads();
#pragma unroll
    for (int o = 32; o; o >>= 1) q += __shfl_xor(q, o);
    if ((tid & 63) == 0) sbuf[tid >> 6] = q;
    __syncthreads();
    float var = (sbuf[0] + sbuf[1] + sbuf[2] + sbuf[3]) * (1.f / 1024.f);
    float rstd = rsqrtf(var + 1e-5f);
    float4 gg = *(const float4*)(g + tid * 4);
    float4 bb4 = *(const float4*)(be + tid * 4);
    float o0 = dx * rstd * gg.x + bb4.x;
    float o1 = dy * rstd * gg.y + bb4.y;
    float o2 = dz * rstd * gg.z + bb4.z;
    float o3 = dw * rstd * gg.w + bb4.w;
    if (OBF16) {
        u16x4 o4 = {f2bf(o0), f2bf(o1), f2bf(o2), f2bf(o3)};
        *(u16x4*)((u16*)yv + off) = o4;
    } else {
        float4 o4 = {o0, o1, o2, o3};
        *(float4*)((float*)yv + off) = o4;
    }
}

// -------------------------------------------------- entity pooling (2-phase)
__global__ __launch_bounds__(256)
void pool_partial_kernel(const float* __restrict__ h, float* __restrict__ partial)
{
    const int chunk = blockIdx.x, b = blockIdx.y;   // 11 chunks of 64 tokens
    const int d = threadIdx.x * 4;
    const float* p = h + ((size_t)b * TT + chunk * 64) * DD + d;
    float4 s = {0.f, 0.f, 0.f, 0.f};
    for (int t = 0; t < 64; ++t) {
        float4 v = *(const float4*)(p + (size_t)t * DD);
        s.x += v.x; s.y += v.y; s.z += v.z; s.w += v.w;
    }
    *(float4*)(partial + ((size_t)(b * 11 + chunk)) * 1024 + d) = s;
}

__global__ __launch_bounds__(256)
void pool_finish_kernel(const float* __restrict__ partial, const float* __restrict__ W_ent,
                        const float* __restrict__ b_ent, float* __restrict__ entities)
{
    const int b = blockIdx.x / 3, e = blockIdx.x % 3;
    const int c0 = (e == 0) ? 0 : (e == 1) ? 2 : 3;
    const int c1 = (e == 0) ? 2 : (e == 1) ? 3 : 11;
    const float invlen = (e == 0) ? (1.f/128.f) : (e == 1) ? (1.f/64.f) : (1.f/512.f);
    __shared__ float pooled[1024];
    __shared__ float part[8][32];
    const int tid = threadIdx.x;
    {
        const int d = tid * 4;
        float4 s = {0.f, 0.f, 0.f, 0.f};
        for (int c = c0; c < c1; ++c) {
            float4 v = *(const float4*)(partial + ((size_t)(b * 11 + c)) * 1024 + d);
            s.x += v.x; s.y += v.y; s.z += v.z; s.w += v.w;
        }
        pooled[d+0] = s.x * invlen; pooled[d+1] = s.y * invlen;
        pooled[d+2] = s.z * invlen; pooled[d+3] = s.w * invlen;
    }
    __syncthreads();
    const int g = tid >> 5, j = tid & 31;
    float s = 0.f;
    for (int d = g * 128; d < g * 128 + 128; ++d) s = fmaf(pooled[d], W_ent[d * 32 + j], s);
    part[g][j] = s;
    __syncthreads();
    if (tid < 32) {
        float s2 = b_ent[tid];
        for (int g2 = 0; g2 < 8; ++g2) s2 += part[g2][tid];
        entities[blockIdx.x * 32 + tid] = s2;
    }
}

// ------------------------- rule/entity selection (LDS-staged, wave-parallel)
__global__ __launch_bounds__(256)
void select_kernel(const float* __restrict__ entities, const float* __restrict__ rules,
                   const float* __restrict__ Wq_er, const float* __restrict__ Wk_er,
                   const float* __restrict__ Wq_es, const float* __restrict__ Wk_es,
                   int* __restrict__ slot_rule, float* __restrict__ gate)
{
    __shared__ float rules_s[4096];   // [k][r][64]
    __shared__ float Wq_er_s[2048];   // [64][32]
    __shared__ float Wq_es_s[4096];   // [k][64][16]
    __shared__ float Wk_er_s[1024];   // [32][32]
    __shared__ float Wk_es_s[512];    // [32][16]
    __shared__ float ent_s[768];      // [b][e][32]
    __shared__ float q_er_s[2048];    // [k][r][32]
    __shared__ float k_er_s[768];
    __shared__ float k_es_s[384];
    __shared__ float qes_s[32][16];
    __shared__ int   rsel_s[32];
    __shared__ int   sel_e[32];
    const int tid = threadIdx.x;
    for (int i = tid; i < 1024; i += 256) *(float4*)&rules_s[i*4] = *(const float4*)&rules[i*4];
    for (int i = tid; i < 512;  i += 256) *(float4*)&Wq_er_s[i*4] = *(const float4*)&Wq_er[i*4];
    for (int i = tid; i < 1024; i += 256) *(float4*)&Wq_es_s[i*4] = *(const float4*)&Wq_es[i*4];
    if (tid < 256) *(float4*)&Wk_er_s[tid*4] = *(const float4*)&Wk_er[tid*4];
    if (tid < 128) *(float4*)&Wk_es_s[tid*4] = *(const float4*)&Wk_es[tid*4];
    if (tid < 192) *(float4*)&ent_s[tid*4] = *(const float4*)&entities[tid*4];
    __syncthreads();
    for (int idx = tid; idx < 2048; idx += 256) {
        int k = idx >> 9, rem = idx & 511, r = rem >> 5, d = rem & 31;
        float s = 0.f;
        for (int hh = 0; hh < 64; ++hh)
            s = fmaf(rules_s[(k * 16 + r) * 64 + hh], Wq_er_s[hh * 32 + d], s);
        q_er_s[idx] = s;
    }
    for (int idx = tid; idx < 768; idx += 256) {
        int be = idx >> 5, d = idx & 31;
        float s = 0.f;
        for (int ss = 0; ss < 32; ++ss)
            s = fmaf(ent_s[be * 32 + ss], Wk_er_s[ss * 32 + d], s);
        k_er_s[idx] = s;
    }
    for (int idx = tid; idx < 384; idx += 256) {
        int be = idx >> 4, i = idx & 15;
        float s = 0.f;
        for (int ss = 0; ss < 32; ++ss)
            s = fmaf(ent_s[be * 32 + ss], Wk_es_s[ss * 16 + i], s);
        k_es_s[idx] = s;
    }
    __syncthreads();
    {
        const int pair = tid >> 3, slice = tid & 7;
        const int b = pair >> 2, k = pair & 3;
        float best = -1e30f; int bj = 48;
        for (int j = slice * 6; j < slice * 6 + 6; ++j) {
            const int r = j / 3, e = j - 3 * r;
            const float* qp = &q_er_s[(k * 16 + r) * 32];
            const float* kp = &k_er_s[(b * 3 + e) * 32];
            float s = 0.f;
            for (int d = 0; d < 32; ++d) s = fmaf(qp[d], kp[d], s);
            s *= 0.17677669529663687f;   // 1/sqrt(32)
            if (s > best) { best = s; bj = j; }
        }
#pragma unroll
        for (int off = 1; off < 8; off <<= 1) {
            float os = __shfl_xor(best, off);
            int oj = __shfl_xor(bj, off);
            if (os > best || (os == best && oj < bj)) { best = os; bj = oj; }
        }
        if (slice == 0) { rsel_s[pair] = bj / 3; slot_rule[pair] = bj / 3; }
    }
    __syncthreads();
    {
        const int pair = tid >> 3, slice = tid & 7;
        const int k = pair & 3, rstar = rsel_s[pair];
#pragma unroll
        for (int ii = 0; ii < 2; ++ii) {
            const int i = slice * 2 + ii;
            float s = 0.f;
            for (int hh = 0; hh < 64; ++hh)
                s = fmaf(rules_s[(k * 16 + rstar) * 64 + hh], Wq_es_s[(k * 64 + hh) * 16 + i], s);
            qes_s[pair][i] = s;
        }
    }
    __syncthreads();
    if ((tid & 7) == 0) {
        const int pair = tid >> 3, b = pair >> 2;
        float best2 = -1e30f; int ei = 0;
        for (int e = 0; e < 3; ++e) {
            float s = 0.f;
            for (int i = 0; i < 16; ++i) s = fmaf(qes_s[pair][i], k_es_s[(b * 3 + e) * 16 + i], s);
            s *= 0.25f;   // 1/sqrt(16)
            if (s > best2) { best2 = s; ei = e; }
        }
        sel_e[pair] = ei;
    }
    __syncthreads();
    if (tid < 24) {
        const int b = tid / 3, e = tid % 3;
        float g = 0.f;
        for (int k = 0; k < 4; ++k) g += (sel_e[b * 4 + k] == e) ? 1.f : 0.f;
        gate[b * 3 + e] = g;
    }
}

// ---------------------------------------------- gated hidden -> bf16 staging
__global__ __launch_bounds__(256)
void hg_kernel(const float* __restrict__ h, const float* __restrict__ gate,
               u16* __restrict__ hgb)
{
    const int row = blockIdx.x;   // b*T + t
    const int b = row / TT, t = row - b * TT;
    const float g = gate[b * 3 + ((t < 128) ? 0 : (t < 192) ? 1 : 2)];
    const size_t off = (size_t)row * DD + threadIdx.x * 4;
    float4 v = *(const float4*)(h + off);
    u16x4 o = {f2bf(v.x * g), f2bf(v.y * g), f2bf(v.z * g), f2bf(v.w * g)};
    *(u16x4*)(hgb + off) = o;
}

// ----------------------------- batched fp32 [R][C] -> bf16 [C][R] transposes
__device__ __forceinline__ void transpose_tile(const float* __restrict__ in,
                                               u16* __restrict__ out,
                                               int R, int C, int tr, int tc)
{
    __shared__ float tile[32][33];
    const int tx = threadIdx.x & 31, ty = threadIdx.x >> 5;
    const int c0 = tc * 32, r0 = tr * 32;
#pragma unroll
    for (int j = 0; j < 4; ++j)
        tile[ty + j * 8][tx] = in[(size_t)(r0 + ty + j * 8) * C + c0 + tx];
    __syncthreads();
#pragma unroll
    for (int j = 0; j < 4; ++j)
        out[(size_t)(c0 + ty + j * 8) * R + r0 + tx] = f2bf(tile[tx][ty + j * 8]);
}

// Wo [64x1024] -> WoT4 [1024][256] = WoT replicated 4x along columns
__device__ __forceinline__ void transpose_tile_rep4(const float* __restrict__ in,
                                                    u16* __restrict__ out,
                                                    int tr, int tc)
{
    __shared__ float tile[32][33];
    const int tx = threadIdx.x & 31, ty = threadIdx.x >> 5;
    const int c0 = tc * 32, r0 = tr * 32;   // in is 64 x 1024
#pragma unroll
    for (int j = 0; j < 4; ++j)
        tile[ty + j * 8][tx] = in[(size_t)(r0 + ty + j * 8) * 1024 + c0 + tx];
    __syncthreads();
#pragma unroll
    for (int j = 0; j < 4; ++j) {
        const u16 v = f2bf(tile[tx][ty + j * 8]);
        u16* o = out + (size_t)(c0 + ty + j * 8) * 256 + r0 + tx;
#pragma unroll
        for (int rep = 0; rep < 4; ++rep) o[rep * 64] = v;
    }
}

__global__ __launch_bounds__(256)
void transpose_batch1_kernel(const float* __restrict__ Wq, const float* __restrict__ Wk,
                             const float* __restrict__ Wv, const float* __restrict__ Wo,
                             const float* __restrict__ fc1w1, const float* __restrict__ fc2w2,
                             u16* __restrict__ WqkvT, u16* __restrict__ WoT4,
                             u16* __restrict__ fc1w1T, u16* __restrict__ fc2w2T)
{
    const int bid = blockIdx.x;
    if (bid < 3072) {
        const int m = bid >> 10, t = bid & 1023;
        const float* in = (m == 0) ? Wq : (m == 1) ? Wk : Wv;
        transpose_tile(in, WqkvT + (size_t)m * 1024 * 1024, 1024, 1024, t >> 5, t & 31);
    } else if (bid < 3136) {
        const int t = bid - 3072;
        transpose_tile_rep4(Wo, WoT4, t >> 5, t & 31);
    } else if (bid < 3648) {
        const int t = bid - 3136;
        transpose_tile(fc1w1, fc1w1T, 1024, 512, t >> 4, t & 15);
    } else {
        const int t = bid - 3648;
        transpose_tile(fc2w2, fc2w2T, 512, 1024, t >> 5, t & 31);
    }
}

__global__ __launch_bounds__(256)
void transpose_batch2_kernel(const float* __restrict__ fc1w2, const float* __restrict__ fc2w1,
                             u16* __restrict__ fc1w2T, u16* __restrict__ fc2w1T)
{
    const int bid = blockIdx.x;
    if (bid < 2048) transpose_tile(fc1w2, fc1w2T, 512, 4096, bid >> 7, bid & 127);
    else { const int t = bid - 2048; transpose_tile(fc2w1, fc2w1T, 4096, 512, t >> 4, t & 15); }
}

// ------------------------------- pipelined MFMA bf16 GEMM, 128xBN tile, 3-buf
template<int BN, int ACT, int OBF16, int RESB>   // ACT: 0 none, 1 relu, 2 gelu
__global__ __launch_bounds__(256)
void gemm2(const u16* __restrict__ A, int lda, const u16* __restrict__ Bt, int ldb,
           void* C0, void* C1, void* C2, void* C3, int ldc, int M, int Ksub,
           const void* __restrict__ resid, const float* __restrict__ bias, float bscale)
{
    constexpr int MI = (BN == 128) ? 4 : 2;     // 16-row frags per wave
    constexpr int NLOAD = 2 + ((BN == 128) ? 2 : 1);
    __shared__ u16 As[3][128 * 32];
    __shared__ u16 Bs[3][BN * 32];
    const int tid = threadIdx.x;
    const int wid = tid >> 6, lane = tid & 63;
    const int z = blockIdx.z;
    const int row0 = blockIdx.y * 128, col0 = blockIdx.x * BN;
    const size_t koff = (size_t)z * Ksub;
    const int srA = wid * 32 + (lane >> 2);
    const int sc = (lane & 3) * 8;
    const u16* ag = A + (size_t)(row0 + srA) * lda + koff + sc;
    const int srB = (BN == 128) ? (wid * 32 + (lane >> 2)) : (wid * 16 + (lane >> 2));
    const u16* bg = Bt + (size_t)(col0 + srB) * ldb + koff + sc;
    const int nt = Ksub >> 5;

    auto STAGE = [&](int buf, int t) {
        const u16* a = ag + t * 32;
        const u16* b = bg + t * 32;
        gl2lds(a, &As[buf][wid * 1024]);
        gl2lds(a + (size_t)16 * lda, &As[buf][wid * 1024 + 512]);
        if constexpr (BN == 128) {
            gl2lds(b, &Bs[buf][wid * 1024]);
            gl2lds(b + (size_t)16 * ldb, &Bs[buf][wid * 1024 + 512]);
        } else {
            gl2lds(b, &Bs[buf][wid * 512]);
        }
    };

    f32x4 acc[MI][4];
#pragma unroll
    for (int i = 0; i < MI; ++i)
#pragma unroll
        for (int j = 0; j < 4; ++j) acc[i][j] = (f32x4){0.f, 0.f, 0.f, 0.f};

    const int fr = lane & 15, kb8 = (lane >> 4) * 8;
    const int wrbase = (BN == 128) ? (wid >> 1) * 64 : wid * 32;
    const int wcbase = (BN == 128) ? (wid & 1) * 64 : 0;
    const int paoff = (wrbase + fr) * 32 + kb8;
    const int pboff = (wcbase + fr) * 32 + kb8;

    STAGE(0, 0);
    if (nt > 1) STAGE(1, 1);
    for (int t = 0; t < nt; ++t) {
        if (t + 1 < nt) waitv<NLOAD>(); else waitv<0>();
        __builtin_amdgcn_s_barrier();
        asm volatile("" ::: "memory");
        const int buf = t % 3;
#pragma unroll
        for (int mi = 0; mi < MI; ++mi) {
            bf16x8 af = *(const bf16x8*)&As[buf][paoff + mi * 512];
#pragma unroll
            for (int ni = 0; ni < 4; ++ni) {
                bf16x8 bfv = *(const bf16x8*)&Bs[buf][pboff + ni * 512];
                acc[mi][ni] = __builtin_amdgcn_mfma_f32_16x16x32_bf16(af, bfv, acc[mi][ni], 0, 0, 0);
            }
        }
        if (t + 2 < nt) STAGE((t + 2) % 3, t + 2);
    }

    void* Cp = (z == 0) ? C0 : (z == 1) ? C1 : (z == 2) ? C2 : C3;
    const int fq4 = (lane >> 4) * 4;
#pragma unroll
    for (int mi = 0; mi < MI; ++mi) {
#pragma unroll
        for (int j = 0; j < 4; ++j) {
            const int row = row0 + wrbase + mi * 16 + fq4 + j;
#pragma unroll
            for (int ni = 0; ni < 4; ++ni) {
                const int col = col0 + wcbase + ni * 16 + fr;
                float v = acc[mi][ni][j];
                if (bias) v += bscale * bias[col];
                if (ACT == 1) v = fmaxf(v, 0.f);
                else if (ACT == 2) v = 0.5f * v * (1.f + erff(v * 0.70710678118654752f));
                const size_t off = (size_t)row * ldc + col;
                if (OBF16) {
                    ((u16*)Cp)[off] = f2bf(v);
                } else {
                    if (resid) v += RESB ? bf2f(((const u16*)resid)[off])
                                         : ((const float*)resid)[off];
                    ((float*)Cp)[off] = v;
                }
            }
        }
    }
}

// ------------------------------------------- split-K reduce: relu + bf16 out
template<int NP>
__global__ __launch_bounds__(256)
void red_relu_kernel(const float* __restrict__ p0, const float* __restrict__ p1,
                     const float* __restrict__ p2, const float* __restrict__ p3,
                     u16* __restrict__ out)
{
    const int i = (blockIdx.x * 256 + threadIdx.x) * 4;
    float4 a = *(const float4*)(p0 + i);
    float4 b = *(const float4*)(p1 + i);
    a.x += b.x; a.y += b.y; a.z += b.z; a.w += b.w;
    if (NP == 4) {
        float4 c = *(const float4*)(p2 + i);
        float4 d = *(const float4*)(p3 + i);
        a.x += c.x + d.x; a.y += c.y + d.y; a.z += c.z + d.z; a.w += c.w + d.w;
    }
    u16x4 o = {f2bf(fmaxf(a.x, 0.f)), f2bf(fmaxf(a.y, 0.f)),
               f2bf(fmaxf(a.z, 0.f)), f2bf(fmaxf(a.w, 0.f))};
    *(u16x4*)(out + i) = o;
}

// -------- combine: hmid(bf16) = hidden + sum_slot AO_z @ Wo + 4*bo  (K=256)
// A' [5632 x 256]: A'[row, k] = AO[(b(row)*4 + k>>6)*TT + t(row)][k&63]
__global__ __launch_bounds__(256)
void combine_mfma_kernel(const u16* __restrict__ AO, const u16* __restrict__ WoT4,
                         const float* __restrict__ hidden, const float* __restrict__ bo,
                         u16* __restrict__ hmid)
{
    __shared__ u16 As[3][128 * 32];
    __shared__ u16 Bs[3][128 * 32];
    const int tid = threadIdx.x;
    const int wid = tid >> 6, lane = tid & 63;
    const int row0 = blockIdx.y * 128, col0 = blockIdx.x * 128;
    const int srA = wid * 32 + (lane >> 2);
    const int sc = (lane & 3) * 8;
    // per-lane AO plane bases for rows srA and srA+16 (may cross b boundary)
    const int arow0 = row0 + srA, arow1 = arow0 + 16;
    const int ab0 = arow0 / TT, at0 = arow0 - ab0 * TT;
    const int ab1 = arow1 / TT, at1 = arow1 - ab1 * TT;
    const u16* abase0 = AO + ((size_t)(ab0 * 4) * TT + at0) * 64 + sc;
    const u16* abase1 = AO + ((size_t)(ab1 * 4) * TT + at1) * 64 + sc;
    const u16* bg = WoT4 + (size_t)(col0 + srA) * 256 + sc;
    const int nt = 8;   // K=256, BK=32

    auto STAGE = [&](int buf, int t) {
        const int k0 = t * 32;
        const size_t delta = (size_t)(k0 >> 6) * (TT * 64) + (k0 & 63);
        gl2lds(abase0 + delta, &As[buf][wid * 1024]);
        gl2lds(abase1 + delta, &As[buf][wid * 1024 + 512]);
        gl2lds(bg + k0, &Bs[buf][wid * 1024]);
        gl2lds(bg + k0 + (size_t)16 * 256, &Bs[buf][wid * 1024 + 512]);
    };

    f32x4 acc[4][4];
#pragma unroll
    for (int i = 0; i < 4; ++i)
#pragma unroll
        for (int j = 0; j < 4; ++j) acc[i][j] = (f32x4){0.f, 0.f, 0.f, 0.f};
    const int fr = lane & 15, kb8 = (lane >> 4) * 8;
    const int wrbase = (wid >> 1) * 64, wcbase = (wid & 1) * 64;
    const int paoff = (wrbase + fr) * 32 + kb8;
    const int pboff = (wcbase + fr) * 32 + kb8;

    STAGE(0, 0);
    STAGE(1, 1);
    for (int t = 0; t < nt; ++t) {
        if (t + 1 < nt) waitv<4>(); else waitv<0>();
        __builtin_amdgcn_s_barrier();
        asm volatile("" ::: "memory");
        const int buf = t % 3;
#pragma unroll
        for (int mi = 0; mi < 4; ++mi) {
            bf16x8 af = *(const bf16x8*)&As[buf][paoff + mi * 512];
#pragma unroll
            for (int ni = 0; ni < 4; ++ni) {
                bf16x8 bfv = *(const bf16x8*)&Bs[buf][pboff + ni * 512];
                acc[mi][ni] = __builtin_amdgcn_mfma_f32_16x16x32_bf16(af, bfv, acc[mi][ni], 0, 0, 0);
            }
        }
        if (t + 2 < nt) STAGE((t + 2) % 3, t + 2);
    }

    const int fq4 = (lane >> 4) * 4;
#pragma unroll
    for (int mi = 0; mi < 4; ++mi)
#pragma unroll
        for (int j = 0; j < 4; ++j) {
            const int row = row0 + wrbase + mi * 16 + fq4 + j;
#pragma unroll
            for (int ni = 0; ni < 4; ++ni) {
                const int col = col0 + wcbase + ni * 16 + fr;
                const size_t off = (size_t)row * DD + col;
                float v = acc[mi][ni][j] + 4.f * bo[col] + hidden[off];
                hmid[off] = f2bf(v);
            }
        }
}

// ---------------- fused QKV projection: one block computes Q,K and V^T tiles
// grid (32 z, 11 mt): A tile staged once; slots of same b adjacent for L2.
__global__ __launch_bounds__(256)
void qkv3_mfma_kernel(const u16* __restrict__ hgb, const u16* __restrict__ WqkvT,
                      const float* __restrict__ bq, const float* __restrict__ bk,
                      const float* __restrict__ bv, const int* __restrict__ slot_rule,
                      u16* __restrict__ Qb, u16* __restrict__ Kb, u16* __restrict__ VT)
{
    const int z = blockIdx.x, mt = blockIdx.y;   // z = b*4+slot
    const int b = z >> 2;
    const int r = slot_rule[z];
    __shared__ u16 As[3][64 * 32];
    __shared__ u16 Bs[3][3][64 * 32];
    const int tid = threadIdx.x;
    const int w = tid >> 6, lane = tid & 63;
    const u16* ag = hgb + ((size_t)b * TT + mt * 64 + (tid >> 2)) * DD + (tid & 3) * 8;
    const u16* bg0 = WqkvT + (size_t)0 * DD * DD + (size_t)(r * 64 + (tid >> 2)) * DD + (tid & 3) * 8;
    const u16* bg1 = WqkvT + (size_t)1 * DD * DD + (size_t)(r * 64 + (tid >> 2)) * DD + (tid & 3) * 8;
    const u16* bg2 = WqkvT + (size_t)2 * DD * DD + (size_t)(r * 64 + (tid >> 2)) * DD + (tid & 3) * 8;
    auto STAGE = [&](int buf, int t) {
        gl2lds(ag  + t * 32, &As[buf][w * 512]);
        gl2lds(bg0 + t * 32, &Bs[buf][0][w * 512]);
        gl2lds(bg1 + t * 32, &Bs[buf][1][w * 512]);
        gl2lds(bg2 + t * 32, &Bs[buf][2][w * 512]);
    };
    f32x4 accq[4], acck[4], accv[4];
#pragma unroll
    for (int i = 0; i < 4; ++i) {
        accq[i] = (f32x4){0.f, 0.f, 0.f, 0.f};
        acck[i] = (f32x4){0.f, 0.f, 0.f, 0.f};
        accv[i] = (f32x4){0.f, 0.f, 0.f, 0.f};
    }
    const int fr = lane & 15, kb8 = (lane >> 4) * 8;
    const int paoff = (w * 16 + fr) * 32 + kb8;
    const int nt = 32;
    STAGE(0, 0);
    STAGE(1, 1);
    for (int t = 0; t < nt; ++t) {
        if (t + 1 < nt) waitv<4>(); else waitv<0>();
        __builtin_amdgcn_s_barrier();
        asm volatile("" ::: "memory");
        const int buf = t % 3;
        bf16x8 af = *(const bf16x8*)&As[buf][paoff];
#pragma unroll
        for (int ni = 0; ni < 4; ++ni) {
            const int boff = (ni * 16 + fr) * 32 + kb8;
            bf16x8 bq8 = *(const bf16x8*)&Bs[buf][0][boff];
            bf16x8 bk8 = *(const bf16x8*)&Bs[buf][1][boff];
            bf16x8 bv8 = *(const bf16x8*)&Bs[buf][2][boff];
            accq[ni] = __builtin_amdgcn_mfma_f32_16x16x32_bf16(af, bq8, accq[ni], 0, 0, 0);
            acck[ni] = __builtin_amdgcn_mfma_f32_16x16x32_bf16(af, bk8, acck[ni], 0, 0, 0);
            accv[ni] = __builtin_amdgcn_mfma_f32_16x16x32_bf16(bv8, af, accv[ni], 0, 0, 0);
        }
        if (t + 2 < nt) STAGE((t + 2) % 3, t + 2);
    }
    const size_t bs = (size_t)z * TT;
    const int fq4 = (lane >> 4) * 4;
#pragma unroll
    for (int ni = 0; ni < 4; ++ni)
#pragma unroll
        for (int j = 0; j < 4; ++j) {
            const int row = mt * 64 + w * 16 + fq4 + j;
            const int col = ni * 16 + fr;
            Qb[(bs + row) * 64 + col] = f2bf((accq[ni][j] + bq[r * 64 + col]) * 0.125f);
            Kb[(bs + row) * 64 + col] = f2bf(acck[ni][j] + bk[r * 64 + col]);
            const int d = ni * 16 + fq4 + j;
            const int tt2 = mt * 64 + w * 16 + fr;
            VT[((size_t)z * 64 + d) * TT + tt2] = f2bf(accv[ni][j] + bv[r * 64 + d]);
        }
}

// ----------------------------------------- MFMA bf16 flash attention / slot
// grid (4 slot, 11 qt, 8 b): slots adjacent -> mask tile L2 reuse
__global__ __launch_bounds__(256)
void attn_mfma_kernel(const u16* __restrict__ Qb, const u16* __restrict__ Kb,
                      const u16* __restrict__ VT, const float* __restrict__ amask,
                      u16* __restrict__ AO)
{
    const int slot = blockIdx.x, qt = blockIdx.y, b = blockIdx.z;
    const int z = b * 4 + slot;
    const size_t bs = (size_t)z * TT;
    const int tid = threadIdx.x;
    const int w = tid >> 6, lane = tid & 63;
    const int fr = lane & 15, g = lane >> 4;
    const int q0 = qt * 64 + w * 16;

    __shared__ u16 Ks[64 * 72];    // [key][d], stride 72
    __shared__ u16 VTs[64 * 72];   // [d][key]
    __shared__ u16 Ps[4][16 * 72]; // per-wave P tile [q][key]

    bf16x8 qa[2];
    qa[0] = *(const bf16x8*)(Qb + (bs + q0 + fr) * 64 + g * 8);
    qa[1] = *(const bf16x8*)(Qb + (bs + q0 + fr) * 64 + 32 + g * 8);

    float m_run[4], l_run[4];
    f32x4 oacc[4];
#pragma unroll
    for (int j = 0; j < 4; ++j) { m_run[j] = -1e30f; l_run[j] = 0.f; }
#pragma unroll
    for (int ni = 0; ni < 4; ++ni) oacc[ni] = (f32x4){0.f, 0.f, 0.f, 0.f};

    const float* mrow = amask + ((size_t)b * TT + q0 + g * 4) * TT;

    for (int kc = 0; kc < 11; ++kc) {
        const int kv0 = kc * 64;
        __syncthreads();
#pragma unroll
        for (int it = 0; it < 2; ++it) {
            const int idx = tid + it * 256;
            const int row = idx >> 3, ch = (idx & 7) * 8;
            *(u16x8*)&Ks[row * 72 + ch]  = *(const u16x8*)(Kb + (bs + kv0 + row) * 64 + ch);
            *(u16x8*)&VTs[row * 72 + ch] = *(const u16x8*)(VT + ((size_t)z * 64 + row) * TT + kv0 + ch);
        }
        __syncthreads();
        f32x4 sacc[4];
#pragma unroll
        for (int ni = 0; ni < 4; ++ni) sacc[ni] = (f32x4){0.f, 0.f, 0.f, 0.f};
#pragma unroll
        for (int c = 0; c < 2; ++c)
#pragma unroll
            for (int ni = 0; ni < 4; ++ni) {
                bf16x8 bf = *(const bf16x8*)&Ks[(ni * 16 + fr) * 72 + c * 32 + g * 8];
                sacc[ni] = __builtin_amdgcn_mfma_f32_16x16x32_bf16(qa[c], bf, sacc[ni], 0, 0, 0);
            }
        float mloc[4] = {-1e30f, -1e30f, -1e30f, -1e30f};
#pragma unroll
        for (int ni = 0; ni < 4; ++ni)
#pragma unroll
            for (int j = 0; j < 4; ++j) {
                float s = sacc[ni][j] + mrow[(size_t)j * TT + kv0 + ni * 16 + fr];
                sacc[ni][j] = s;
                mloc[j] = fmaxf(mloc[j], s);
            }
#pragma unroll
        for (int o = 1; o < 16; o <<= 1)
#pragma unroll
            for (int j = 0; j < 4; ++j) mloc[j] = fmaxf(mloc[j], __shfl_xor(mloc[j], o));
        float fac[4], lsum[4];
#pragma unroll
        for (int j = 0; j < 4; ++j) {
            const float mn = fmaxf(m_run[j], mloc[j]);
            fac[j] = __expf(m_run[j] - mn);
            m_run[j] = mn;
            lsum[j] = 0.f;
        }
#pragma unroll
        for (int ni = 0; ni < 4; ++ni)
#pragma unroll
            for (int j = 0; j < 4; ++j) {
                const float p = __expf(sacc[ni][j] - m_run[j]);
                lsum[j] += p;
                Ps[w][(g * 4 + j) * 72 + ni * 16 + fr] = f2bf(p);
            }
#pragma unroll
        for (int o = 1; o < 16; o <<= 1)
#pragma unroll
            for (int j = 0; j < 4; ++j) lsum[j] += __shfl_xor(lsum[j], o);
#pragma unroll
        for (int j = 0; j < 4; ++j) l_run[j] = l_run[j] * fac[j] + lsum[j];
#pragma unroll
        for (int ni = 0; ni < 4; ++ni)
#pragma unroll
            for (int j = 0; j < 4; ++j) oacc[ni][j] *= fac[j];
#pragma unroll
        for (int c = 0; c < 2; ++c) {
            bf16x8 paf = *(const bf16x8*)&Ps[w][fr * 72 + c * 32 + g * 8];
#pragma unroll
            for (int ni = 0; ni < 4; ++ni) {
                bf16x8 vf = *(const bf16x8*)&VTs[(ni * 16 + fr) * 72 + c * 32 + g * 8];
                oacc[ni] = __builtin_amdgcn_mfma_f32_16x16x32_bf16(paf, vf, oacc[ni], 0, 0, 0);
            }
        }
    }
#pragma unroll
    for (int j = 0; j < 4; ++j) {
        const float inv = 1.f / l_run[j];
        const int t = q0 + g * 4 + j;
#pragma unroll
        for (int ni = 0; ni < 4; ++ni)
            AO[(bs + t) * 64 + ni * 16 + fr] = f2bf(oacc[ni][j] * inv);
    }
}

// ---------------------------------------------------------------- launcher
extern "C" void kernel_launch(void* const* d_in, const int* in_sizes, int n_in,
                              void* d_out, int out_size, void* d_ws, size_t ws_size,
                              hipStream_t stream)
{
    const float* hidden = (const float*)d_in[0];
    const float* amask  = (const float*)d_in[1];
    const float* rules  = (const float*)d_in[2];
    const float* W_ent  = (const float*)d_in[3];
    const float* b_ent  = (const float*)d_in[4];
    const float* Wq_er  = (const float*)d_in[5];
    const float* Wk_er  = (const float*)d_in[6];
    const float* Wq_es  = (const float*)d_in[7];
    const float* Wk_es  = (const float*)d_in[8];
    const float* Wq     = (const float*)d_in[9];
    const float* bq     = (const float*)d_in[10];
    const float* Wk     = (const float*)d_in[11];
    const float* bk     = (const float*)d_in[12];
    const float* Wv     = (const float*)d_in[13];
    const float* bv     = (const float*)d_in[14];
    const float* Wo     = (const float*)d_in[15];
    const float* bo     = (const float*)d_in[16];
    const float* ln1_g  = (const float*)d_in[17];
    const float* ln1_b  = (const float*)d_in[18];
    const float* ln2_g  = (const float*)d_in[19];
    const float* ln2_b  = (const float*)d_in[20];
    const float* fc1_w1 = (const float*)d_in[21];
    const float* fc1_w2 = (const float*)d_in[22];
    const float* fc2_w1 = (const float*)d_in[23];
    const float* fc2_w2 = (const float*)d_in[24];

    char* ws = (char*)d_ws;
    // -------- workspace map (bytes)
    float* h      = (float*)(ws + 0);              // 23,068,672 [ln1..hg]
    u16*   x1     = (u16*)(ws + 0);                //  5,767,168 [G1..G2b]
    u16*   x3b    = (u16*)(ws + 5767168);          //  5,767,168 [G3red..G4]
    float* g3p1   = (float*)(ws + 11534336);       //  5,767,168 [G3..G3red]
    float* g3p2   = (float*)(ws + 17301504);       //  5,767,168 [G3..G3red]
    u16*   hmid   = (u16*)(ws + 23068672);         // 11,534,336 bf16 [combine..G4]
    float* g3p3   = (float*)(ws + 34603008);       //  5,767,168 [G3..G3red] (after hmid)
    u16*   hgb    = (u16*)(ws + 46137344);         // 11,534,336 [hg..qkv]
    u16*   xln2   = (u16*)(ws + 46137344);         //   (reuse)  [ln2..G1]
    u16*   x2h    = (u16*)(ws + 46137344);         // 23,068,672 [G2x..G3x]
    u16*   Qb     = (u16*)(ws + 57671680);         //  2,883,584 [qkv..attn]
    u16*   Kb     = (u16*)(ws + 60555264);         //  2,883,584
    u16*   VT     = (u16*)(ws + 66322432);         //  2,883,584
    u16*   AO     = (u16*)(ws + 69206016);         //  2,883,584 [attn..combine]
    float* part   = (float*)(ws + 69206016);       //    360,448 (dead before AO)
    float* g3p0   = (float*)(ws + 74973184);       //  5,767,168 [G3..G3red]
    float* ent    = (float*)(ws + 80740352);       //      3,072
    float* gate   = (float*)(ws + 80743424);       //        128
    int*   srule  = (int*)(ws + 80743552);         //        128
    u16*   WqkvT  = (u16*)(ws + 80743680);         //  6,291,456 [..qkv] -> ends 87,035,136
    u16*   fc1w2T = (u16*)(ws + 80743680);         //  4,194,304 (after qkv)
    u16*   fc2w1T = (u16*)(ws + 84937984);         //  4,194,304 (after qkv) -> ends 89,132,288
    u16*   WoT4   = (u16*)(ws + 89132288);         //    524,288 -> ends 89,656,576
    u16*   fc1w1T = (u16*)(ws + 89656576);         //  1,048,576 -> ends 90,705,152
    u16*   fc2w2T = (u16*)(ws + 90705152);         //  1,048,576 -> ends 91,753,728
    float* out    = (float*)d_out;

    // --- LN1 + selection path (fp32)
    ln_kernel<0, 0><<<BT, 256, 0, stream>>>(hidden, ln1_g, ln1_b, h);
    pool_partial_kernel<<<dim3(11, 8), 256, 0, stream>>>(h, part);
    pool_finish_kernel<<<24, 256, 0, stream>>>(part, W_ent, b_ent, ent);
    select_kernel<<<1, 256, 0, stream>>>(ent, rules, Wq_er, Wk_er, Wq_es, Wk_es, srule, gate);
    hg_kernel<<<BT, 256, 0, stream>>>(h, gate, hgb);

    // --- weight prep (phase 1: batched; needed before/at qkv)
    transpose_batch1_kernel<<<4160, 256, 0, stream>>>(Wq, Wk, Wv, Wo, fc1_w1, fc2_w2,
                                                      WqkvT, WoT4, fc1w1T, fc2w2T);

    // --- fused QKV (MFMA; writes Q, K, V^T); z-major grid for A-tile L2 reuse
    qkv3_mfma_kernel<<<dim3(32, 11), 256, 0, stream>>>(hgb, WqkvT, bq, bk, bv, srule,
                                                       Qb, Kb, VT);
    // weight prep phase 2 (aliases WqkvT region, so must come after qkv)
    transpose_batch2_kernel<<<4096, 256, 0, stream>>>(fc1_w2, fc2_w1, fc1w2T, fc2w1T);

    // --- attention (MFMA); slot-major grid for mask-tile L2 reuse
    attn_mfma_kernel<<<dim3(4, 11, 8), 256, 0, stream>>>(Qb, Kb, VT, amask, AO);

    // --- combine: hmid(bf16) = hidden + sum_slot AO @ Wo + 4*bo (K=256 GEMM)
    combine_mfma_kernel<<<dim3(8, 44), 256, 0, stream>>>(AO, WoT4, hidden, bo, hmid);

    // --- LN2 (bf16 in -> bf16 out)
    ln_kernel<1, 1><<<BT, 256, 0, stream>>>(hmid, ln2_g, ln2_b, xln2);

    // --- G1: x1 = relu(xln2 @ fc1w1T^T)  (fused relu->bf16)
    gemm2<64, 1, 1, 0><<<dim3(8, 44, 1), 256, 0, stream>>>(
        xln2, 1024, fc1w1T, 1024, x1, nullptr, nullptr, nullptr, 512, BT, 1024,
        nullptr, nullptr, 0.f);

    // --- G2/G3 per M-half (2816 rows)
    for (int half = 0; half < 2; ++half) {
        const u16* x1h = x1 + (size_t)half * 2816 * 512;
        u16* x3bh = x3b + (size_t)half * 2816 * 512;
        gemm2<128, 2, 1, 0><<<dim3(32, 22, 1), 256, 0, stream>>>(
            x1h, 512, fc1w2T, 512, x2h, nullptr, nullptr, nullptr, 4096, 2816, 512,
            nullptr, nullptr, 0.f);
        gemm2<64, 0, 0, 0><<<dim3(8, 22, 4), 256, 0, stream>>>(
            x2h, 4096, fc2w1T, 4096, g3p0, g3p1, g3p2, g3p3, 512, 2816, 1024,
            nullptr, nullptr, 0.f);
        red_relu_kernel<4><<<1408, 256, 0, stream>>>(g3p0, g3p1, g3p2, g3p3, x3bh);
    }

    // --- G4: out = hmid(bf16) + x3b @ fc2w2T^T
    gemm2<64, 0, 0, 1><<<dim3(16, 44, 1), 256, 0, stream>>>(
        x3b, 512, fc2w2T, 512, out, nullptr, nullptr, nullptr, 1024, BT, 512,
        hmid, nullptr, 0.f);
}

// Round 9
// 269.976 us; speedup vs baseline: 9.2809x; 1.0748x over previous
//
#include <hip/hip_runtime.h>
#include <hip/hip_bf16.h>
#include <math.h>

// Problem constants
#define BB 8
#define TT 704
#define DD 1024
#define RR 16
#define KK 4
#define HDH 64
#define BT (BB*TT)   // 5632

typedef unsigned short u16;
typedef __attribute__((ext_vector_type(4))) float f32x4;
typedef __attribute__((ext_vector_type(8))) short bf16x8;
typedef __attribute__((ext_vector_type(4))) unsigned short u16x4;
typedef __attribute__((ext_vector_type(8))) unsigned short u16x8;

__device__ __forceinline__ u16 f2bf(float f) {
    union { float f; unsigned int u; } cv; cv.f = f;
    unsigned int u = cv.u;
    unsigned int r = (u + 0x7fffu + ((u >> 16) & 1u)) >> 16;
    return (u16)r;
}

__device__ __forceinline__ float bf2f(u16 v) {
    union { unsigned int u; float f; } cv; cv.u = ((unsigned int)v) << 16;
    return cv.f;
}

__device__ __forceinline__ void gl2lds(const u16* g, u16* l) {
    __builtin_amdgcn_global_load_lds(
        (const __attribute__((address_space(1))) void*)g,
        (__attribute__((address_space(3))) void*)l, 16, 0, 0);
}

template<int N> __device__ __forceinline__ void waitv() {
    if constexpr (N == 0) asm volatile("s_waitcnt vmcnt(0)" ::: "memory");
    else if constexpr (N == 2) asm volatile("s_waitcnt vmcnt(2)" ::: "memory");
    else if constexpr (N == 3) asm volatile("s_waitcnt vmcnt(3)" ::: "memory");
    else asm volatile("s_waitcnt vmcnt(4)" ::: "memory");
}

// XCD-chunked swizzle: physical d -> logical bid so that each XCD (d%8) gets
// a CONTIGUOUS chunk of logical block ids (L2 locality). Requires nwg%8==0.
__device__ __forceinline__ int xcd_swz(int d, int nwg) {
    return (d & 7) * (nwg >> 3) + (d >> 3);
}

// ---------------------------------------------------------- LayerNorm (LN2)
template<int OBF16, int IBF16>
__global__ __launch_bounds__(256)
void ln_kernel(const void* __restrict__ xv, const float* __restrict__ g,
               const float* __restrict__ be, void* __restrict__ yv)
{
    const int row = blockIdx.x;
    const int tid = threadIdx.x;
    __shared__ float sbuf[4];
    const size_t off = (size_t)row * DD + tid * 4;
    float4 v;
    if (IBF16) {
        u16x4 xb = *(const u16x4*)((const u16*)xv + off);
        v.x = bf2f(xb[0]); v.y = bf2f(xb[1]); v.z = bf2f(xb[2]); v.w = bf2f(xb[3]);
    } else {
        v = *(const float4*)((const float*)xv + off);
    }
    float s = v.x + v.y + v.z + v.w;
#pragma unroll
    for (int o = 32; o; o >>= 1) s += __shfl_xor(s, o);
    if ((tid & 63) == 0) sbuf[tid >> 6] = s;
    __syncthreads();
    float mean = (sbuf[0] + sbuf[1] + sbuf[2] + sbuf[3]) * (1.f / 1024.f);
    float dx = v.x - mean, dy = v.y - mean, dz = v.z - mean, dw = v.w - mean;
    float q = dx*dx + dy*dy + dz*dz + dw*dw;
    __syncthreads();
#pragma unroll
    for (int o = 32; o; o >>= 1) q += __shfl_xor(q, o);
    if ((tid & 63) == 0) sbuf[tid >> 6] = q;
    __syncthreads();
    float var = (sbuf[0] + sbuf[1] + sbuf[2] + sbuf[3]) * (1.f / 1024.f);
    float rstd = rsqrtf(var + 1e-5f);
    float4 gg = *(const float4*)(g + tid * 4);
    float4 bb4 = *(const float4*)(be + tid * 4);
    float o0 = dx * rstd * gg.x + bb4.x;
    float o1 = dy * rstd * gg.y + bb4.y;
    float o2 = dz * rstd * gg.z + bb4.z;
    float o3 = dw * rstd * gg.w + bb4.w;
    if (OBF16) {
        u16x4 o4 = {f2bf(o0), f2bf(o1), f2bf(o2), f2bf(o3)};
        *(u16x4*)((u16*)yv + off) = o4;
    } else {
        float4 o4 = {o0, o1, o2, o3};
        *(float4*)((float*)yv + off) = o4;
    }
}

// ------------------------------- LN1: writes fp32 (pool path) + bf16 (GEMMs)
__global__ __launch_bounds__(256)
void ln1_dual_kernel(const float* __restrict__ x, const float* __restrict__ g,
                     const float* __restrict__ be, float* __restrict__ y,
                     u16* __restrict__ yb)
{
    const int row = blockIdx.x;
    const int tid = threadIdx.x;
    __shared__ float sbuf[4];
    const size_t off = (size_t)row * DD + tid * 4;
    float4 v = *(const float4*)(x + off);
    float s = v.x + v.y + v.z + v.w;
#pragma unroll
    for (int o = 32; o; o >>= 1) s += __shfl_xor(s, o);
    if ((tid & 63) == 0) sbuf[tid >> 6] = s;
    __syncthreads();
    float mean = (sbuf[0] + sbuf[1] + sbuf[2] + sbuf[3]) * (1.f / 1024.f);
    float dx = v.x - mean, dy = v.y - mean, dz = v.z - mean, dw = v.w - mean;
    float q = dx*dx + dy*dy + dz*dz + dw*dw;
    __syncthreads();
#pragma unroll
    for (int o = 32; o; o >>= 1) q += __shfl_xor(q, o);
    if ((tid & 63) == 0) sbuf[tid >> 6] = q;
    __syncthreads();
    float var = (sbuf[0] + sbuf[1] + sbuf[2] + sbuf[3]) * (1.f / 1024.f);
    float rstd = rsqrtf(var + 1e-5f);
    float4 gg = *(const float4*)(g + tid * 4);
    float4 bb4 = *(const float4*)(be + tid * 4);
    float o0 = dx * rstd * gg.x + bb4.x;
    float o1 = dy * rstd * gg.y + bb4.y;
    float o2 = dz * rstd * gg.z + bb4.z;
    float o3 = dw * rstd * gg.w + bb4.w;
    float4 o4 = {o0, o1, o2, o3};
    *(float4*)(y + off) = o4;
    u16x4 ob = {f2bf(o0), f2bf(o1), f2bf(o2), f2bf(o3)};
    *(u16x4*)(yb + off) = ob;
}

// -------------------------------------------------- entity pooling (2-phase)
__global__ __launch_bounds__(256)
void pool_partial_kernel(const float* __restrict__ h, float* __restrict__ partial)
{
    const int chunk = blockIdx.x, b = blockIdx.y;   // 11 chunks of 64 tokens
    const int d = threadIdx.x * 4;
    const float* p = h + ((size_t)b * TT + chunk * 64) * DD + d;
    float4 s = {0.f, 0.f, 0.f, 0.f};
    for (int t = 0; t < 64; ++t) {
        float4 v = *(const float4*)(p + (size_t)t * DD);
        s.x += v.x; s.y += v.y; s.z += v.z; s.w += v.w;
    }
    *(float4*)(partial + ((size_t)(b * 11 + chunk)) * 1024 + d) = s;
}

__global__ __launch_bounds__(256)
void pool_finish_kernel(const float* __restrict__ partial, const float* __restrict__ W_ent,
                        const float* __restrict__ b_ent, float* __restrict__ entities)
{
    const int b = blockIdx.x / 3, e = blockIdx.x % 3;
    const int c0 = (e == 0) ? 0 : (e == 1) ? 2 : 3;
    const int c1 = (e == 0) ? 2 : (e == 1) ? 3 : 11;
    const float invlen = (e == 0) ? (1.f/128.f) : (e == 1) ? (1.f/64.f) : (1.f/512.f);
    __shared__ float pooled[1024];
    __shared__ float part[8][32];
    const int tid = threadIdx.x;
    {
        const int d = tid * 4;
        float4 s = {0.f, 0.f, 0.f, 0.f};
        for (int c = c0; c < c1; ++c) {
            float4 v = *(const float4*)(partial + ((size_t)(b * 11 + c)) * 1024 + d);
            s.x += v.x; s.y += v.y; s.z += v.z; s.w += v.w;
        }
        pooled[d+0] = s.x * invlen; pooled[d+1] = s.y * invlen;
        pooled[d+2] = s.z * invlen; pooled[d+3] = s.w * invlen;
    }
    __syncthreads();
    const int g = tid >> 5, j = tid & 31;
    float s = 0.f;
    for (int d = g * 128; d < g * 128 + 128; ++d) s = fmaf(pooled[d], W_ent[d * 32 + j], s);
    part[g][j] = s;
    __syncthreads();
    if (tid < 32) {
        float s2 = b_ent[tid];
        for (int g2 = 0; g2 < 8; ++g2) s2 += part[g2][tid];
        entities[blockIdx.x * 32 + tid] = s2;
    }
}

// ------------------------- rule/entity selection (LDS-staged, wave-parallel)
__global__ __launch_bounds__(256)
void select_kernel(const float* __restrict__ entities, const float* __restrict__ rules,
                   const float* __restrict__ Wq_er, const float* __restrict__ Wk_er,
                   const float* __restrict__ Wq_es, const float* __restrict__ Wk_es,
                   int* __restrict__ slot_rule, float* __restrict__ gate)
{
    __shared__ float rules_s[4096];   // [k][r][64]
    __shared__ float Wq_er_s[2048];   // [64][32]
    __shared__ float Wq_es_s[4096];   // [k][64][16]
    __shared__ float Wk_er_s[1024];   // [32][32]
    __shared__ float Wk_es_s[512];    // [32][16]
    __shared__ float ent_s[768];      // [b][e][32]
    __shared__ float q_er_s[2048];    // [k][r][32]
    __shared__ float k_er_s[768];
    __shared__ float k_es_s[384];
    __shared__ float qes_s[32][16];
    __shared__ int   rsel_s[32];
    __shared__ int   sel_e[32];
    const int tid = threadIdx.x;
    for (int i = tid; i < 1024; i += 256) *(float4*)&rules_s[i*4] = *(const float4*)&rules[i*4];
    for (int i = tid; i < 512;  i += 256) *(float4*)&Wq_er_s[i*4] = *(const float4*)&Wq_er[i*4];
    for (int i = tid; i < 1024; i += 256) *(float4*)&Wq_es_s[i*4] = *(const float4*)&Wq_es[i*4];
    if (tid < 256) *(float4*)&Wk_er_s[tid*4] = *(const float4*)&Wk_er[tid*4];
    if (tid < 128) *(float4*)&Wk_es_s[tid*4] = *(const float4*)&Wk_es[tid*4];
    if (tid < 192) *(float4*)&ent_s[tid*4] = *(const float4*)&entities[tid*4];
    __syncthreads();
    for (int idx = tid; idx < 2048; idx += 256) {
        int k = idx >> 9, rem = idx & 511, r = rem >> 5, d = rem & 31;
        float s = 0.f;
        for (int hh = 0; hh < 64; ++hh)
            s = fmaf(rules_s[(k * 16 + r) * 64 + hh], Wq_er_s[hh * 32 + d], s);
        q_er_s[idx] = s;
    }
    for (int idx = tid; idx < 768; idx += 256) {
        int be = idx >> 5, d = idx & 31;
        float s = 0.f;
        for (int ss = 0; ss < 32; ++ss)
            s = fmaf(ent_s[be * 32 + ss], Wk_er_s[ss * 32 + d], s);
        k_er_s[idx] = s;
    }
    for (int idx = tid; idx < 384; idx += 256) {
        int be = idx >> 4, i = idx & 15;
        float s = 0.f;
        for (int ss = 0; ss < 32; ++ss)
            s = fmaf(ent_s[be * 32 + ss], Wk_es_s[ss * 16 + i], s);
        k_es_s[idx] = s;
    }
    __syncthreads();
    {
        const int pair = tid >> 3, slice = tid & 7;
        const int b = pair >> 2, k = pair & 3;
        float best = -1e30f; int bj = 48;
        for (int j = slice * 6; j < slice * 6 + 6; ++j) {
            const int r = j / 3, e = j - 3 * r;
            const float* qp = &q_er_s[(k * 16 + r) * 32];
            const float* kp = &k_er_s[(b * 3 + e) * 32];
            float s = 0.f;
            for (int d = 0; d < 32; ++d) s = fmaf(qp[d], kp[d], s);
            s *= 0.17677669529663687f;   // 1/sqrt(32)
            if (s > best) { best = s; bj = j; }
        }
#pragma unroll
        for (int off = 1; off < 8; off <<= 1) {
            float os = __shfl_xor(best, off);
            int oj = __shfl_xor(bj, off);
            if (os > best || (os == best && oj < bj)) { best = os; bj = oj; }
        }
        if (slice == 0) { rsel_s[pair] = bj / 3; slot_rule[pair] = bj / 3; }
    }
    __syncthreads();
    {
        const int pair = tid >> 3, slice = tid & 7;
        const int k = pair & 3, rstar = rsel_s[pair];
#pragma unroll
        for (int ii = 0; ii < 2; ++ii) {
            const int i = slice * 2 + ii;
            float s = 0.f;
            for (int hh = 0; hh < 64; ++hh)
                s = fmaf(rules_s[(k * 16 + rstar) * 64 + hh], Wq_es_s[(k * 64 + hh) * 16 + i], s);
            qes_s[pair][i] = s;
        }
    }
    __syncthreads();
    if ((tid & 7) == 0) {
        const int pair = tid >> 3, b = pair >> 2;
        float best2 = -1e30f; int ei = 0;
        for (int e = 0; e < 3; ++e) {
            float s = 0.f;
            for (int i = 0; i < 16; ++i) s = fmaf(qes_s[pair][i], k_es_s[(b * 3 + e) * 16 + i], s);
            s *= 0.25f;   // 1/sqrt(16)
            if (s > best2) { best2 = s; ei = e; }
        }
        sel_e[pair] = ei;
    }
    __syncthreads();
    if (tid < 24) {
        const int b = tid / 3, e = tid % 3;
        float g = 0.f;
        for (int k = 0; k < 4; ++k) g += (sel_e[b * 4 + k] == e) ? 1.f : 0.f;
        gate[b * 3 + e] = g;
    }
}

// ----------------------------- batched fp32 [R][C] -> bf16 [C][R] transposes
__device__ __forceinline__ void transpose_tile(const float* __restrict__ in,
                                               u16* __restrict__ out,
                                               int R, int C, int tr, int tc)
{
    __shared__ float tile[32][33];
    const int tx = threadIdx.x & 31, ty = threadIdx.x >> 5;
    const int c0 = tc * 32, r0 = tr * 32;
#pragma unroll
    for (int j = 0; j < 4; ++j)
        tile[ty + j * 8][tx] = in[(size_t)(r0 + ty + j * 8) * C + c0 + tx];
    __syncthreads();
#pragma unroll
    for (int j = 0; j < 4; ++j)
        out[(size_t)(c0 + ty + j * 8) * R + r0 + tx] = f2bf(tile[tx][ty + j * 8]);
}

// Wo [64x1024] -> WoT4 [1024][256] = WoT replicated 4x along columns
__device__ __forceinline__ void transpose_tile_rep4(const float* __restrict__ in,
                                                    u16* __restrict__ out,
                                                    int tr, int tc)
{
    __shared__ float tile[32][33];
    const int tx = threadIdx.x & 31, ty = threadIdx.x >> 5;
    const int c0 = tc * 32, r0 = tr * 32;   // in is 64 x 1024
#pragma unroll
    for (int j = 0; j < 4; ++j)
        tile[ty + j * 8][tx] = in[(size_t)(r0 + ty + j * 8) * 1024 + c0 + tx];
    __syncthreads();
#pragma unroll
    for (int j = 0; j < 4; ++j) {
        const u16 v = f2bf(tile[tx][ty + j * 8]);
        u16* o = out + (size_t)(c0 + ty + j * 8) * 256 + r0 + tx;
#pragma unroll
        for (int rep = 0; rep < 4; ++rep) o[rep * 64] = v;
    }
}

__global__ __launch_bounds__(256)
void transpose_batch1_kernel(const float* __restrict__ Wq, const float* __restrict__ Wk,
                             const float* __restrict__ Wv, const float* __restrict__ Wo,
                             const float* __restrict__ fc1w1, const float* __restrict__ fc2w2,
                             u16* __restrict__ WqkvT, u16* __restrict__ WoT4,
                             u16* __restrict__ fc1w1T, u16* __restrict__ fc2w2T)
{
    const int bid = blockIdx.x;
    if (bid < 3072) {
        const int m = bid >> 10, t = bid & 1023;
        const float* in = (m == 0) ? Wq : (m == 1) ? Wk : Wv;
        transpose_tile(in, WqkvT + (size_t)m * 1024 * 1024, 1024, 1024, t >> 5, t & 31);
    } else if (bid < 3136) {
        const int t = bid - 3072;
        transpose_tile_rep4(Wo, WoT4, t >> 5, t & 31);
    } else if (bid < 3648) {
        const int t = bid - 3136;
        transpose_tile(fc1w1, fc1w1T, 1024, 512, t >> 4, t & 15);
    } else {
        const int t = bid - 3648;
        transpose_tile(fc2w2, fc2w2T, 512, 1024, t >> 5, t & 31);
    }
}

__global__ __launch_bounds__(256)
void transpose_batch2_kernel(const float* __restrict__ fc1w2, const float* __restrict__ fc2w1,
                             u16* __restrict__ fc1w2T, u16* __restrict__ fc2w1T)
{
    const int bid = blockIdx.x;
    if (bid < 2048) transpose_tile(fc1w2, fc1w2T, 512, 4096, bid >> 7, bid & 127);
    else { const int t = bid - 2048; transpose_tile(fc2w1, fc2w1T, 4096, 512, t >> 4, t & 15); }
}

// --------------- pipelined MFMA bf16 GEMM, 128xBN tile, 3-buf, 1D swz grid
// launched with nwg = gx*gy*gz blocks; logical bid: col fastest, then row, z.
template<int BN, int ACT, int OBF16, int RESB, int SWZ>
__global__ __launch_bounds__(256)
void gemm2(const u16* __restrict__ A, int lda, const u16* __restrict__ Bt, int ldb,
           void* C0, void* C1, int ldc, int M, int Ksub,
           const void* __restrict__ resid, const float* __restrict__ bias, float bscale,
           int gx, int gy)
{
    constexpr int MI = (BN == 128) ? 4 : 2;     // 16-row frags per wave
    constexpr int NLOAD = 2 + ((BN == 128) ? 2 : 1);
    __shared__ u16 As[3][128 * 32];
    __shared__ u16 Bs[3][BN * 32];
    const int tid = threadIdx.x;
    const int wid = tid >> 6, lane = tid & 63;
    const int bid = SWZ ? xcd_swz(blockIdx.x, gridDim.x) : (int)blockIdx.x;
    const int col = bid % gx;
    const int rem = bid / gx;
    const int row = rem % gy;
    const int z = rem / gy;
    const int row0 = row * 128, col0 = col * BN;
    const size_t koff = (size_t)z * Ksub;
    const int srA = wid * 32 + (lane >> 2);
    const int sc = (lane & 3) * 8;
    const u16* ag = A + (size_t)(row0 + srA) * lda + koff + sc;
    const int srB = (BN == 128) ? (wid * 32 + (lane >> 2)) : (wid * 16 + (lane >> 2));
    const u16* bg = Bt + (size_t)(col0 + srB) * ldb + koff + sc;
    const int nt = Ksub >> 5;

    auto STAGE = [&](int buf, int t) {
        const u16* a = ag + t * 32;
        const u16* b = bg + t * 32;
        gl2lds(a, &As[buf][wid * 1024]);
        gl2lds(a + (size_t)16 * lda, &As[buf][wid * 1024 + 512]);
        if constexpr (BN == 128) {
            gl2lds(b, &Bs[buf][wid * 1024]);
            gl2lds(b + (size_t)16 * ldb, &Bs[buf][wid * 1024 + 512]);
        } else {
            gl2lds(b, &Bs[buf][wid * 512]);
        }
    };

    f32x4 acc[MI][4];
#pragma unroll
    for (int i = 0; i < MI; ++i)
#pragma unroll
        for (int j = 0; j < 4; ++j) acc[i][j] = (f32x4){0.f, 0.f, 0.f, 0.f};

    const int fr = lane & 15, kb8 = (lane >> 4) * 8;
    const int wrbase = (BN == 128) ? (wid >> 1) * 64 : wid * 32;
    const int wcbase = (BN == 128) ? (wid & 1) * 64 : 0;
    const int paoff = (wrbase + fr) * 32 + kb8;
    const int pboff = (wcbase + fr) * 32 + kb8;

    STAGE(0, 0);
    if (nt > 1) STAGE(1, 1);
    for (int t = 0; t < nt; ++t) {
        if (t + 1 < nt) waitv<NLOAD>(); else waitv<0>();
        __builtin_amdgcn_s_barrier();
        asm volatile("" ::: "memory");
        const int buf = t % 3;
#pragma unroll
        for (int mi = 0; mi < MI; ++mi) {
            bf16x8 af = *(const bf16x8*)&As[buf][paoff + mi * 512];
#pragma unroll
            for (int ni = 0; ni < 4; ++ni) {
                bf16x8 bfv = *(const bf16x8*)&Bs[buf][pboff + ni * 512];
                acc[mi][ni] = __builtin_amdgcn_mfma_f32_16x16x32_bf16(af, bfv, acc[mi][ni], 0, 0, 0);
            }
        }
        if (t + 2 < nt) STAGE((t + 2) % 3, t + 2);
    }

    void* Cp = (z == 0) ? C0 : C1;
    const int fq4 = (lane >> 4) * 4;
#pragma unroll
    for (int mi = 0; mi < MI; ++mi) {
#pragma unroll
        for (int j = 0; j < 4; ++j) {
            const int rw = row0 + wrbase + mi * 16 + fq4 + j;
#pragma unroll
            for (int ni = 0; ni < 4; ++ni) {
                const int cl = col0 + wcbase + ni * 16 + fr;
                float v = acc[mi][ni][j];
                if (bias) v += bscale * bias[cl];
                if (ACT == 1) v = fmaxf(v, 0.f);
                else if (ACT == 2) v = 0.5f * v * (1.f + erff(v * 0.70710678118654752f));
                const size_t off = (size_t)rw * ldc + cl;
                if (OBF16) {
                    ((u16*)Cp)[off] = f2bf(v);
                } else {
                    if (resid) v += RESB ? bf2f(((const u16*)resid)[off])
                                         : ((const float*)resid)[off];
                    ((float*)Cp)[off] = v;
                }
            }
        }
    }
}

// ------------------------------------------- split-K reduce: relu + bf16 out
template<int NP>
__global__ __launch_bounds__(256)
void red_relu_kernel(const float* __restrict__ p0, const float* __restrict__ p1,
                     const float* __restrict__ p2, const float* __restrict__ p3,
                     u16* __restrict__ out)
{
    const int i = (blockIdx.x * 256 + threadIdx.x) * 4;
    float4 a = *(const float4*)(p0 + i);
    float4 b = *(const float4*)(p1 + i);
    a.x += b.x; a.y += b.y; a.z += b.z; a.w += b.w;
    if (NP == 4) {
        float4 c = *(const float4*)(p2 + i);
        float4 d = *(const float4*)(p3 + i);
        a.x += c.x + d.x; a.y += c.y + d.y; a.z += c.z + d.z; a.w += c.w + d.w;
    }
    u16x4 o = {f2bf(fmaxf(a.x, 0.f)), f2bf(fmaxf(a.y, 0.f)),
               f2bf(fmaxf(a.z, 0.f)), f2bf(fmaxf(a.w, 0.f))};
    *(u16x4*)(out + i) = o;
}

// -------- combine: hmid(bf16) = hidden + sum_slot AO_z @ Wo + 4*bo  (K=256)
__global__ __launch_bounds__(256)
void combine_mfma_kernel(const u16* __restrict__ AO, const u16* __restrict__ WoT4,
                         const float* __restrict__ hidden, const float* __restrict__ bo,
                         u16* __restrict__ hmid)
{
    __shared__ u16 As[3][128 * 32];
    __shared__ u16 Bs[3][128 * 32];
    const int tid = threadIdx.x;
    const int wid = tid >> 6, lane = tid & 63;
    const int bid = xcd_swz(blockIdx.x, gridDim.x);   // nwg = 352
    const int row0 = (bid >> 3) * 128, col0 = (bid & 7) * 128;
    const int srA = wid * 32 + (lane >> 2);
    const int sc = (lane & 3) * 8;
    const int arow0 = row0 + srA, arow1 = arow0 + 16;
    const int ab0 = arow0 / TT, at0 = arow0 - ab0 * TT;
    const int ab1 = arow1 / TT, at1 = arow1 - ab1 * TT;
    const u16* abase0 = AO + ((size_t)(ab0 * 4) * TT + at0) * 64 + sc;
    const u16* abase1 = AO + ((size_t)(ab1 * 4) * TT + at1) * 64 + sc;
    const u16* bg = WoT4 + (size_t)(col0 + srA) * 256 + sc;
    const int nt = 8;   // K=256, BK=32

    auto STAGE = [&](int buf, int t) {
        const int k0 = t * 32;
        const size_t delta = (size_t)(k0 >> 6) * (TT * 64) + (k0 & 63);
        gl2lds(abase0 + delta, &As[buf][wid * 1024]);
        gl2lds(abase1 + delta, &As[buf][wid * 1024 + 512]);
        gl2lds(bg + k0, &Bs[buf][wid * 1024]);
        gl2lds(bg + k0 + (size_t)16 * 256, &Bs[buf][wid * 1024 + 512]);
    };

    f32x4 acc[4][4];
#pragma unroll
    for (int i = 0; i < 4; ++i)
#pragma unroll
        for (int j = 0; j < 4; ++j) acc[i][j] = (f32x4){0.f, 0.f, 0.f, 0.f};
    const int fr = lane & 15, kb8 = (lane >> 4) * 8;
    const int wrbase = (wid >> 1) * 64, wcbase = (wid & 1) * 64;
    const int paoff = (wrbase + fr) * 32 + kb8;
    const int pboff = (wcbase + fr) * 32 + kb8;

    STAGE(0, 0);
    STAGE(1, 1);
    for (int t = 0; t < nt; ++t) {
        if (t + 1 < nt) waitv<4>(); else waitv<0>();
        __builtin_amdgcn_s_barrier();
        asm volatile("" ::: "memory");
        const int buf = t % 3;
#pragma unroll
        for (int mi = 0; mi < 4; ++mi) {
            bf16x8 af = *(const bf16x8*)&As[buf][paoff + mi * 512];
#pragma unroll
            for (int ni = 0; ni < 4; ++ni) {
                bf16x8 bfv = *(const bf16x8*)&Bs[buf][pboff + ni * 512];
                acc[mi][ni] = __builtin_amdgcn_mfma_f32_16x16x32_bf16(af, bfv, acc[mi][ni], 0, 0, 0);
            }
        }
        if (t + 2 < nt) STAGE((t + 2) % 3, t + 2);
    }

    const int fq4 = (lane >> 4) * 4;
#pragma unroll
    for (int mi = 0; mi < 4; ++mi)
#pragma unroll
        for (int j = 0; j < 4; ++j) {
            const int rw = row0 + wrbase + mi * 16 + fq4 + j;
#pragma unroll
            for (int ni = 0; ni < 4; ++ni) {
                const int cl = col0 + wcbase + ni * 16 + fr;
                const size_t off = (size_t)rw * DD + cl;
                float v = acc[mi][ni][j] + 4.f * bo[cl] + hidden[off];
                hmid[off] = f2bf(v);
            }
        }
}

// ---------------- fused QKV projection: one block computes Q,K and V^T tiles
// 1D grid nwg=352, logical bid = ((b*11+mt)*4+slot); gate applied in epilogue
// (exact: gate is integer-valued and constant per 64-token tile).
__global__ __launch_bounds__(256)
void qkv3_mfma_kernel(const u16* __restrict__ hb, const u16* __restrict__ WqkvT,
                      const float* __restrict__ bq, const float* __restrict__ bk,
                      const float* __restrict__ bv, const int* __restrict__ slot_rule,
                      const float* __restrict__ gatep,
                      u16* __restrict__ Qb, u16* __restrict__ Kb, u16* __restrict__ VT)
{
    const int bid = xcd_swz(blockIdx.x, gridDim.x);
    const int slot = bid & 3;
    const int mt = (bid >> 2) % 11;
    const int b = (bid >> 2) / 11;
    const int z = b * 4 + slot;
    const int r = slot_rule[z];
    const float gv = gatep[b * 3 + ((mt < 2) ? 0 : (mt < 3) ? 1 : 2)];
    __shared__ u16 As[3][64 * 32];
    __shared__ u16 Bs[3][3][64 * 32];
    const int tid = threadIdx.x;
    const int w = tid >> 6, lane = tid & 63;
    const u16* ag = hb + ((size_t)b * TT + mt * 64 + (tid >> 2)) * DD + (tid & 3) * 8;
    const u16* bg0 = WqkvT + (size_t)0 * DD * DD + (size_t)(r * 64 + (tid >> 2)) * DD + (tid & 3) * 8;
    const u16* bg1 = WqkvT + (size_t)1 * DD * DD + (size_t)(r * 64 + (tid >> 2)) * DD + (tid & 3) * 8;
    const u16* bg2 = WqkvT + (size_t)2 * DD * DD + (size_t)(r * 64 + (tid >> 2)) * DD + (tid & 3) * 8;
    auto STAGE = [&](int buf, int t) {
        gl2lds(ag  + t * 32, &As[buf][w * 512]);
        gl2lds(bg0 + t * 32, &Bs[buf][0][w * 512]);
        gl2lds(bg1 + t * 32, &Bs[buf][1][w * 512]);
        gl2lds(bg2 + t * 32, &Bs[buf][2][w * 512]);
    };
    f32x4 accq[4], acck[4], accv[4];
#pragma unroll
    for (int i = 0; i < 4; ++i) {
        accq[i] = (f32x4){0.f, 0.f, 0.f, 0.f};
        acck[i] = (f32x4){0.f, 0.f, 0.f, 0.f};
        accv[i] = (f32x4){0.f, 0.f, 0.f, 0.f};
    }
    const int fr = lane & 15, kb8 = (lane >> 4) * 8;
    const int paoff = (w * 16 + fr) * 32 + kb8;
    const int nt = 32;
    STAGE(0, 0);
    STAGE(1, 1);
    for (int t = 0; t < nt; ++t) {
        if (t + 1 < nt) waitv<4>(); else waitv<0>();
        __builtin_amdgcn_s_barrier();
        asm volatile("" ::: "memory");
        const int buf = t % 3;
        bf16x8 af = *(const bf16x8*)&As[buf][paoff];
#pragma unroll
        for (int ni = 0; ni < 4; ++ni) {
            const int boff = (ni * 16 + fr) * 32 + kb8;
            bf16x8 bq8 = *(const bf16x8*)&Bs[buf][0][boff];
            bf16x8 bk8 = *(const bf16x8*)&Bs[buf][1][boff];
            bf16x8 bv8 = *(const bf16x8*)&Bs[buf][2][boff];
            accq[ni] = __builtin_amdgcn_mfma_f32_16x16x32_bf16(af, bq8, accq[ni], 0, 0, 0);
            acck[ni] = __builtin_amdgcn_mfma_f32_16x16x32_bf16(af, bk8, acck[ni], 0, 0, 0);
            accv[ni] = __builtin_amdgcn_mfma_f32_16x16x32_bf16(bv8, af, accv[ni], 0, 0, 0);
        }
        if (t + 2 < nt) STAGE((t + 2) % 3, t + 2);
    }
    const size_t bs = (size_t)z * TT;
    const int fq4 = (lane >> 4) * 4;
#pragma unroll
    for (int ni = 0; ni < 4; ++ni)
#pragma unroll
        for (int j = 0; j < 4; ++j) {
            const int row = mt * 64 + w * 16 + fq4 + j;
            const int col = ni * 16 + fr;
            Qb[(bs + row) * 64 + col] = f2bf((gv * accq[ni][j] + bq[r * 64 + col]) * 0.125f);
            Kb[(bs + row) * 64 + col] = f2bf(gv * acck[ni][j] + bk[r * 64 + col]);
            const int d = ni * 16 + fq4 + j;
            const int tt2 = mt * 64 + w * 16 + fr;
            VT[((size_t)z * 64 + d) * TT + tt2] = f2bf(gv * accv[ni][j] + bv[r * 64 + d]);
        }
}

// ----------------------------------------- MFMA bf16 flash attention / slot
// 1D grid nwg=352, logical bid = ((b*11+qt)*4+slot): each XCD owns one b.
__global__ __launch_bounds__(256)
void attn_mfma_kernel(const u16* __restrict__ Qb, const u16* __restrict__ Kb,
                      const u16* __restrict__ VT, const float* __restrict__ amask,
                      u16* __restrict__ AO)
{
    const int bid = xcd_swz(blockIdx.x, gridDim.x);
    const int slot = bid & 3;
    const int qt = (bid >> 2) % 11;
    const int b = (bid >> 2) / 11;
    const int z = b * 4 + slot;
    const size_t bs = (size_t)z * TT;
    const int tid = threadIdx.x;
    const int w = tid >> 6, lane = tid & 63;
    const int fr = lane & 15, g = lane >> 4;
    const int q0 = qt * 64 + w * 16;

    __shared__ u16 Ks[64 * 72];    // [key][d], stride 72
    __shared__ u16 VTs[64 * 72];   // [d][key]
    __shared__ u16 Ps[4][16 * 72]; // per-wave P tile [q][key]

    bf16x8 qa[2];
    qa[0] = *(const bf16x8*)(Qb + (bs + q0 + fr) * 64 + g * 8);
    qa[1] = *(const bf16x8*)(Qb + (bs + q0 + fr) * 64 + 32 + g * 8);

    float m_run[4], l_run[4];
    f32x4 oacc[4];
#pragma unroll
    for (int j = 0; j < 4; ++j) { m_run[j] = -1e30f; l_run[j] = 0.f; }
#pragma unroll
    for (int ni = 0; ni < 4; ++ni) oacc[ni] = (f32x4){0.f, 0.f, 0.f, 0.f};

    const float* mrow = amask + ((size_t)b * TT + q0 + g * 4) * TT;

    for (int kc = 0; kc < 11; ++kc) {
        const int kv0 = kc * 64;
        __syncthreads();
#pragma unroll
        for (int it = 0; it < 2; ++it) {
            const int idx = tid + it * 256;
            const int row = idx >> 3, ch = (idx & 7) * 8;
            *(u16x8*)&Ks[row * 72 + ch]  = *(const u16x8*)(Kb + (bs + kv0 + row) * 64 + ch);
            *(u16x8*)&VTs[row * 72 + ch] = *(const u16x8*)(VT + ((size_t)z * 64 + row) * TT + kv0 + ch);
        }
        __syncthreads();
        f32x4 sacc[4];
#pragma unroll
        for (int ni = 0; ni < 4; ++ni) sacc[ni] = (f32x4){0.f, 0.f, 0.f, 0.f};
#pragma unroll
        for (int c = 0; c < 2; ++c)
#pragma unroll
            for (int ni = 0; ni < 4; ++ni) {
                bf16x8 bf = *(const bf16x8*)&Ks[(ni * 16 + fr) * 72 + c * 32 + g * 8];
                sacc[ni] = __builtin_amdgcn_mfma_f32_16x16x32_bf16(qa[c], bf, sacc[ni], 0, 0, 0);
            }
        float mloc[4] = {-1e30f, -1e30f, -1e30f, -1e30f};
#pragma unroll
        for (int ni = 0; ni < 4; ++ni)
#pragma unroll
            for (int j = 0; j < 4; ++j) {
                float s = sacc[ni][j] + mrow[(size_t)j * TT + kv0 + ni * 16 + fr];
                sacc[ni][j] = s;
                mloc[j] = fmaxf(mloc[j], s);
            }
#pragma unroll
        for (int o = 1; o < 16; o <<= 1)
#pragma unroll
            for (int j = 0; j < 4; ++j) mloc[j] = fmaxf(mloc[j], __shfl_xor(mloc[j], o));
        float fac[4], lsum[4];
#pragma unroll
        for (int j = 0; j < 4; ++j) {
            const float mn = fmaxf(m_run[j], mloc[j]);
            fac[j] = __expf(m_run[j] - mn);
            m_run[j] = mn;
            lsum[j] = 0.f;
        }
#pragma unroll
        for (int ni = 0; ni < 4; ++ni)
#pragma unroll
            for (int j = 0; j < 4; ++j) {
                const float p = __expf(sacc[ni][j] - m_run[j]);
                lsum[j] += p;
                Ps[w][(g * 4 + j) * 72 + ni * 16 + fr] = f2bf(p);
            }
#pragma unroll
        for (int o = 1; o < 16; o <<= 1)
#pragma unroll
            for (int j = 0; j < 4; ++j) lsum[j] += __shfl_xor(lsum[j], o);
#pragma unroll
        for (int j = 0; j < 4; ++j) l_run[j] = l_run[j] * fac[j] + lsum[j];
#pragma unroll
        for (int ni = 0; ni < 4; ++ni)
#pragma unroll
            for (int j = 0; j < 4; ++j) oacc[ni][j] *= fac[j];
#pragma unroll
        for (int c = 0; c < 2; ++c) {
            bf16x8 paf = *(const bf16x8*)&Ps[w][fr * 72 + c * 32 + g * 8];
#pragma unroll
            for (int ni = 0; ni < 4; ++ni) {
                bf16x8 vf = *(const bf16x8*)&VTs[(ni * 16 + fr) * 72 + c * 32 + g * 8];
                oacc[ni] = __builtin_amdgcn_mfma_f32_16x16x32_bf16(paf, vf, oacc[ni], 0, 0, 0);
            }
        }
    }
#pragma unroll
    for (int j = 0; j < 4; ++j) {
        const float inv = 1.f / l_run[j];
        const int t = q0 + g * 4 + j;
#pragma unroll
        for (int ni = 0; ni < 4; ++ni)
            AO[(bs + t) * 64 + ni * 16 + fr] = f2bf(oacc[ni][j] * inv);
    }
}

// ---------------------------------------------------------------- launcher
extern "C" void kernel_launch(void* const* d_in, const int* in_sizes, int n_in,
                              void* d_out, int out_size, void* d_ws, size_t ws_size,
                              hipStream_t stream)
{
    const float* hidden = (const float*)d_in[0];
    const float* amask  = (const float*)d_in[1];
    const float* rules  = (const float*)d_in[2];
    const float* W_ent  = (const float*)d_in[3];
    const float* b_ent  = (const float*)d_in[4];
    const float* Wq_er  = (const float*)d_in[5];
    const float* Wk_er  = (const float*)d_in[6];
    const float* Wq_es  = (const float*)d_in[7];
    const float* Wk_es  = (const float*)d_in[8];
    const float* Wq     = (const float*)d_in[9];
    const float* bq     = (const float*)d_in[10];
    const float* Wk     = (const float*)d_in[11];
    const float* bk     = (const float*)d_in[12];
    const float* Wv     = (const float*)d_in[13];
    const float* bv     = (const float*)d_in[14];
    const float* Wo     = (const float*)d_in[15];
    const float* bo     = (const float*)d_in[16];
    const float* ln1_g  = (const float*)d_in[17];
    const float* ln1_b  = (const float*)d_in[18];
    const float* ln2_g  = (const float*)d_in[19];
    const float* ln2_b  = (const float*)d_in[20];
    const float* fc1_w1 = (const float*)d_in[21];
    const float* fc1_w2 = (const float*)d_in[22];
    const float* fc2_w1 = (const float*)d_in[23];
    const float* fc2_w2 = (const float*)d_in[24];

    char* ws = (char*)d_ws;
    // -------- workspace map (bytes)
    float* h      = (float*)(ws + 0);              // 23,068,672 [ln1..pool]
    u16*   x1     = (u16*)(ws + 0);                //  5,767,168 [G1..G2]
    u16*   x3b    = (u16*)(ws + 5767168);          //  5,767,168 [G3red..G4]
    float* g3p1   = (float*)(ws + 11534336);       //  5,767,168 [G3..G3red]
    u16*   hmid   = (u16*)(ws + 23068672);         // 11,534,336 bf16 [combine..G4]
    u16*   hb     = (u16*)(ws + 46137344);         // 11,534,336 bf16 LN1 out [ln1..qkv]
    u16*   xln2   = (u16*)(ws + 46137344);         //   (reuse)  [ln2..G1]
    u16*   x2h    = (u16*)(ws + 46137344);         // 23,068,672 [G2..G3]
    u16*   Qb     = (u16*)(ws + 57671680);         //  2,883,584 [qkv..attn]
    u16*   Kb     = (u16*)(ws + 60555264);         //  2,883,584
    u16*   VT     = (u16*)(ws + 66322432);         //  2,883,584
    u16*   AO     = (u16*)(ws + 69206016);         //  2,883,584 [attn..combine]
    float* part   = (float*)(ws + 69206016);       //    360,448 (dead before AO)
    float* g3p0   = (float*)(ws + 74973184);       //  5,767,168 [G3..G3red]
    float* ent    = (float*)(ws + 80740352);       //      3,072
    float* gate   = (float*)(ws + 80743424);       //        128
    int*   srule  = (int*)(ws + 80743552);         //        128
    u16*   WqkvT  = (u16*)(ws + 80743680);         //  6,291,456 [..qkv]
    u16*   fc1w2T = (u16*)(ws + 80743680);         //  4,194,304 (after qkv)
    u16*   fc2w1T = (u16*)(ws + 84937984);         //  4,194,304 (after qkv)
    u16*   WoT4   = (u16*)(ws + 89132288);         //    524,288
    u16*   fc1w1T = (u16*)(ws + 89656576);         //  1,048,576
    u16*   fc2w2T = (u16*)(ws + 90705152);         //  1,048,576  -> ends 91,753,728
    float* out    = (float*)d_out;

    // --- LN1 (dual fp32+bf16 out) + selection path
    ln1_dual_kernel<<<BT, 256, 0, stream>>>(hidden, ln1_g, ln1_b, h, hb);
    pool_partial_kernel<<<dim3(11, 8), 256, 0, stream>>>(h, part);
    pool_finish_kernel<<<24, 256, 0, stream>>>(part, W_ent, b_ent, ent);
    select_kernel<<<1, 256, 0, stream>>>(ent, rules, Wq_er, Wk_er, Wq_es, Wk_es, srule, gate);

    // --- weight prep (phase 1: batched; needed before/at qkv)
    transpose_batch1_kernel<<<4160, 256, 0, stream>>>(Wq, Wk, Wv, Wo, fc1_w1, fc2_w2,
                                                      WqkvT, WoT4, fc1w1T, fc2w2T);

    // --- fused QKV (MFMA; gate applied in epilogue; writes Q, K, V^T)
    qkv3_mfma_kernel<<<352, 256, 0, stream>>>(hb, WqkvT, bq, bk, bv, srule, gate,
                                              Qb, Kb, VT);
    // weight prep phase 2 (aliases WqkvT region, so must come after qkv)
    transpose_batch2_kernel<<<4096, 256, 0, stream>>>(fc1_w2, fc2_w1, fc1w2T, fc2w1T);

    // --- attention (MFMA); XCD-swizzled so each XCD owns one batch b
    attn_mfma_kernel<<<352, 256, 0, stream>>>(Qb, Kb, VT, amask, AO);

    // --- combine: hmid(bf16) = hidden + sum_slot AO @ Wo + 4*bo (K=256 GEMM)
    combine_mfma_kernel<<<352, 256, 0, stream>>>(AO, WoT4, hidden, bo, hmid);

    // --- LN2 (bf16 in -> bf16 out)
    ln_kernel<1, 1><<<BT, 256, 0, stream>>>(hmid, ln2_g, ln2_b, xln2);

    // --- G1: x1 = relu(xln2 @ fc1w1T^T)  (fused relu->bf16), swizzled
    gemm2<64, 1, 1, 0, 1><<<352, 256, 0, stream>>>(
        xln2, 1024, fc1w1T, 1024, x1, nullptr, 512, BT, 1024,
        nullptr, nullptr, 0.f, 8, 44);

    // --- G2/G3 per M-half (2816 rows)
    for (int half = 0; half < 2; ++half) {
        const u16* x1h = x1 + (size_t)half * 2816 * 512;
        u16* x3bh = x3b + (size_t)half * 2816 * 512;
        // G2: x2h = gelu(x1h @ fc1w2T^T); natural order pins B cols per XCD
        gemm2<128, 2, 1, 0, 0><<<704, 256, 0, stream>>>(
            x1h, 512, fc1w2T, 512, x2h, nullptr, 4096, 2816, 512,
            nullptr, nullptr, 0.f, 32, 22);
        // G3: split-K 2 fp32 partials, swizzled (A = x2h is the big operand)
        gemm2<64, 0, 0, 0, 1><<<352, 256, 0, stream>>>(
            x2h, 4096, fc2w1T, 4096, g3p0, g3p1, 512, 2816, 2048,
            nullptr, nullptr, 0.f, 8, 22);
        red_relu_kernel<2><<<1408, 256, 0, stream>>>(g3p0, g3p1, nullptr, nullptr, x3bh);
    }

    // --- G4: out = hmid(bf16) + x3b @ fc2w2T^T, swizzled
    gemm2<64, 0, 0, 1, 1><<<704, 256, 0, stream>>>(
        x3b, 512, fc2w2T, 512, out, nullptr, 1024, BT, 512,
        hmid, nullptr, 0.f, 16, 44);
}